// Round 1
// baseline (2633.006 us; speedup 1.0000x reference)
//
#include <hip/hip_runtime.h>
#include <math.h>

// ---------------- problem constants ----------------
constexpr int cH = 8;          // heads
constexpr int cDP = 128;       // dim_p_embd
constexpr int cM = 64;         // random features
constexpr int cB = 16;         // batch
constexpr int cNCTX = 3200;
constexpr int cNQ = 3072;
constexpr int cSHIFT = 128;    // s = NCTX*2//50
constexpr int ROWS_Q = 2 * cB * cNQ;    // 98304
constexpr int ROWS_KV = cB * cNCTX;     // 51200
constexpr float cRATIO = 0.125f;        // M^-0.5
constexpr float cEPST = 0.125e-4f;      // ratio * EPS
constexpr float cLNEPS = 1e-5f;

__device__ __forceinline__ float wmax64(float v) {
#pragma unroll
  for (int o = 32; o; o >>= 1) v = fmaxf(v, __shfl_xor(v, o));
  return v;
}
__device__ __forceinline__ float wsum64(float v) {
#pragma unroll
  for (int o = 32; o; o >>= 1) v += __shfl_xor(v, o);
  return v;
}
__device__ __forceinline__ float gelu_f(float x) {
  return 0.5f * x * (1.0f + tanhf(0.79788456080286536f * (x + 0.044715f * x * x * x)));
}

// ================= K1: per-row MLP (LN4 -> fc -> gelu -> pr -> +y) =================
// y (98304,128) -> y1 (98304,128). Weights staged in LDS, 16 rows per block-iter.
__global__ __launch_bounds__(512) void k1_mlp(
    const float* __restrict__ y,
    const float* __restrict__ ln4w, const float* __restrict__ ln4b,
    const float* __restrict__ fcw, const float* __restrict__ fcb,
    const float* __restrict__ prw, const float* __restrict__ prb,
    float* __restrict__ y1)
{
  __shared__ float wfc[cDP * cDP];
  __shared__ float wpr[cDP * cDP];
  __shared__ float xb[16][cDP];
  __shared__ float hb[16][cDP];
  __shared__ float redS[8][4], redQ[8][4];

  const int tid = threadIdx.x;
  for (int i = tid; i < cDP * cDP; i += 512) { wfc[i] = fcw[i]; wpr[i] = prw[i]; }
  const int col = tid & 127;
  const int rh = tid >> 7;       // 0..3 -> rows rh*4 .. rh*4+3
  const int wv = tid >> 6;       // wave 0..7
  const int lane = tid & 63;
  const float lw4 = ln4w[col], lb4 = ln4b[col];
  const float fb = fcb[col], pb = prb[col];
  __syncthreads();

  for (int g = blockIdx.x; g < ROWS_Q / 16; g += gridDim.x) {
    const int r0 = g * 16;
    for (int i = tid; i < 16 * cDP; i += 512)
      xb[i >> 7][i & 127] = y[(size_t)(r0 + (i >> 7)) * cDP + (i & 127)];
    __syncthreads();

    float yv[4], mu_[4], rs_[4];
#pragma unroll
    for (int rr = 0; rr < 4; ++rr) {
      float v = xb[rh * 4 + rr][col];
      yv[rr] = v;
      float s = v, q = v * v;
#pragma unroll
      for (int o = 32; o; o >>= 1) { s += __shfl_xor(s, o); q += __shfl_xor(q, o); }
      if (lane == 0) { redS[wv][rr] = s; redQ[wv][rr] = q; }
    }
    __syncthreads();
#pragma unroll
    for (int rr = 0; rr < 4; ++rr) {
      float s = redS[wv][rr] + redS[wv ^ 1][rr];
      float q = redQ[wv][rr] + redQ[wv ^ 1][rr];
      float mu = s * (1.0f / 128.0f);
      mu_[rr] = mu;
      rs_[rr] = rsqrtf(q * (1.0f / 128.0f) - mu * mu + cLNEPS);
    }
#pragma unroll
    for (int rr = 0; rr < 4; ++rr)
      xb[rh * 4 + rr][col] = (yv[rr] - mu_[rr]) * rs_[rr] * lw4 + lb4;
    __syncthreads();

    // GEMM1 + gelu
    float a0 = fb, a1 = fb, a2 = fb, a3 = fb;
    for (int k = 0; k < cDP; k += 4) {
      float4 v0 = *(const float4*)&xb[rh * 4 + 0][k];
      float4 v1 = *(const float4*)&xb[rh * 4 + 1][k];
      float4 v2 = *(const float4*)&xb[rh * 4 + 2][k];
      float4 v3 = *(const float4*)&xb[rh * 4 + 3][k];
      float w0 = wfc[(k + 0) * cDP + col], w1 = wfc[(k + 1) * cDP + col];
      float w2 = wfc[(k + 2) * cDP + col], w3 = wfc[(k + 3) * cDP + col];
      a0 += v0.x * w0 + v0.y * w1 + v0.z * w2 + v0.w * w3;
      a1 += v1.x * w0 + v1.y * w1 + v1.z * w2 + v1.w * w3;
      a2 += v2.x * w0 + v2.y * w1 + v2.z * w2 + v2.w * w3;
      a3 += v3.x * w0 + v3.y * w1 + v3.z * w2 + v3.w * w3;
    }
    hb[rh * 4 + 0][col] = gelu_f(a0);
    hb[rh * 4 + 1][col] = gelu_f(a1);
    hb[rh * 4 + 2][col] = gelu_f(a2);
    hb[rh * 4 + 3][col] = gelu_f(a3);
    __syncthreads();

    // GEMM2 + residual
    float b0 = pb, b1 = pb, b2 = pb, b3 = pb;
    for (int k = 0; k < cDP; k += 4) {
      float4 v0 = *(const float4*)&hb[rh * 4 + 0][k];
      float4 v1 = *(const float4*)&hb[rh * 4 + 1][k];
      float4 v2 = *(const float4*)&hb[rh * 4 + 2][k];
      float4 v3 = *(const float4*)&hb[rh * 4 + 3][k];
      float w0 = wpr[(k + 0) * cDP + col], w1 = wpr[(k + 1) * cDP + col];
      float w2 = wpr[(k + 2) * cDP + col], w3 = wpr[(k + 3) * cDP + col];
      b0 += v0.x * w0 + v0.y * w1 + v0.z * w2 + v0.w * w3;
      b1 += v1.x * w0 + v1.y * w1 + v1.z * w2 + v1.w * w3;
      b2 += v2.x * w0 + v2.y * w1 + v2.z * w2 + v2.w * w3;
      b3 += v3.x * w0 + v3.y * w1 + v3.z * w2 + v3.w * w3;
    }
    y1[(size_t)(r0 + rh * 4 + 0) * cDP + col] = b0 + yv[0];
    y1[(size_t)(r0 + rh * 4 + 1) * cDP + col] = b1 + yv[1];
    y1[(size_t)(r0 + rh * 4 + 2) * cDP + col] = b2 + yv[2];
    y1[(size_t)(r0 + rh * 4 + 3) * cDP + col] = b3 + yv[3];
    __syncthreads();
  }
}

// ================= K2: LN2(x) -> k = ctx@wk.T, v = ctx@wv.T =================
__global__ __launch_bounds__(512) void k2_kv(
    const float* __restrict__ x,
    const float* __restrict__ ln2w, const float* __restrict__ ln2b,
    const float* __restrict__ wkw, const float* __restrict__ wvw,
    float* __restrict__ kbuf, float* __restrict__ vbuf)
{
  __shared__ float wkT[32 * cDP];  // [d][j]
  __shared__ float wvT[32 * cDP];
  __shared__ float xb[16][32];
  const int tid = threadIdx.x;
  for (int i = tid; i < 32 * cDP; i += 512) {
    int j = i >> 5, d = i & 31;
    wkT[d * cDP + j] = wkw[i];
    wvT[d * cDP + j] = wvw[i];
  }
  const int dl = tid & 31, rl = tid >> 5;     // LN mapping: 16 rows x 32 lanes
  const int col = tid & 127, rh = tid >> 7;   // GEMM mapping
  const float l2w = ln2w[dl], l2b = ln2b[dl];
  __syncthreads();

  for (int g = blockIdx.x; g < ROWS_KV / 16; g += gridDim.x) {
    const int r0 = g * 16;
    __syncthreads();
    {
      float v = x[(size_t)(r0 + rl) * 32 + dl];
      float s = v, q = v * v;
#pragma unroll
      for (int o = 16; o; o >>= 1) { s += __shfl_xor(s, o); q += __shfl_xor(q, o); }
      float mu = s * (1.0f / 32.0f);
      float var = q * (1.0f / 32.0f) - mu * mu;
      xb[rl][dl] = (v - mu) * rsqrtf(var + cLNEPS) * l2w + l2b;
    }
    __syncthreads();
    float ak0 = 0, ak1 = 0, ak2 = 0, ak3 = 0, av0 = 0, av1 = 0, av2 = 0, av3 = 0;
    for (int d = 0; d < 32; d += 4) {
      float4 v0 = *(const float4*)&xb[rh * 4 + 0][d];
      float4 v1 = *(const float4*)&xb[rh * 4 + 1][d];
      float4 v2 = *(const float4*)&xb[rh * 4 + 2][d];
      float4 v3 = *(const float4*)&xb[rh * 4 + 3][d];
      float k0 = wkT[(d + 0) * cDP + col], k1 = wkT[(d + 1) * cDP + col];
      float k2 = wkT[(d + 2) * cDP + col], k3 = wkT[(d + 3) * cDP + col];
      float u0 = wvT[(d + 0) * cDP + col], u1 = wvT[(d + 1) * cDP + col];
      float u2 = wvT[(d + 2) * cDP + col], u3 = wvT[(d + 3) * cDP + col];
      ak0 += v0.x * k0 + v0.y * k1 + v0.z * k2 + v0.w * k3;
      ak1 += v1.x * k0 + v1.y * k1 + v1.z * k2 + v1.w * k3;
      ak2 += v2.x * k0 + v2.y * k1 + v2.z * k2 + v2.w * k3;
      ak3 += v3.x * k0 + v3.y * k1 + v3.z * k2 + v3.w * k3;
      av0 += v0.x * u0 + v0.y * u1 + v0.z * u2 + v0.w * u3;
      av1 += v1.x * u0 + v1.y * u1 + v1.z * u2 + v1.w * u3;
      av2 += v2.x * u0 + v2.y * u1 + v2.z * u2 + v2.w * u3;
      av3 += v3.x * u0 + v3.y * u1 + v3.z * u2 + v3.w * u3;
    }
    kbuf[(size_t)(r0 + rh * 4 + 0) * cDP + col] = ak0;
    kbuf[(size_t)(r0 + rh * 4 + 1) * cDP + col] = ak1;
    kbuf[(size_t)(r0 + rh * 4 + 2) * cDP + col] = ak2;
    kbuf[(size_t)(r0 + rh * 4 + 3) * cDP + col] = ak3;
    vbuf[(size_t)(r0 + rh * 4 + 0) * cDP + col] = av0;
    vbuf[(size_t)(r0 + rh * 4 + 1) * cDP + col] = av1;
    vbuf[(size_t)(r0 + rh * 4 + 2) * cDP + col] = av2;
    vbuf[(size_t)(r0 + rh * 4 + 3) * cDP + col] = av3;
  }
}

// ================= K3: LN1(y1) -> q = xq@wq.T -> dash/unnorm/rowmax =================
__global__ __launch_bounds__(512) void k3_q(
    const float* __restrict__ y1,
    const float* __restrict__ ln1w, const float* __restrict__ ln1b,
    const float* __restrict__ wq, const float* __restrict__ proj,
    float* __restrict__ q_un, float* __restrict__ mxq)
{
  __shared__ float wT[cDP * cDP];   // wT[k][j] = wq[j][k]
  __shared__ float xb[16][cDP];
  __shared__ float qb[16][cDP];
  __shared__ float redS[8][4], redQ[8][4];
  const int tid = threadIdx.x;
  for (int i = tid; i < cDP * cDP; i += 512) {
    int j = i >> 7, k = i & 127;
    wT[k * cDP + j] = wq[i];
  }
  const int col = tid & 127, rh = tid >> 7, wv = tid >> 6, lane = tid & 63;
  const int m = tid & 63;
  const int h = tid >> 6;   // head per wave (0..7)
  float pr[16];
#pragma unroll
  for (int d = 0; d < 16; ++d) pr[d] = proj[m * 16 + d];
  const float lw1 = ln1w[col], lb1 = ln1b[col];
  __syncthreads();

  for (int g = blockIdx.x; g < ROWS_Q / 16; g += gridDim.x) {
    const int r0 = g * 16;
    for (int i = tid; i < 16 * cDP; i += 512)
      xb[i >> 7][i & 127] = y1[(size_t)(r0 + (i >> 7)) * cDP + (i & 127)];
    __syncthreads();

    float vv[4], mu_[4], rs_[4];
#pragma unroll
    for (int rr = 0; rr < 4; ++rr) {
      float v = xb[rh * 4 + rr][col];
      vv[rr] = v;
      float s = v, q = v * v;
#pragma unroll
      for (int o = 32; o; o >>= 1) { s += __shfl_xor(s, o); q += __shfl_xor(q, o); }
      if (lane == 0) { redS[wv][rr] = s; redQ[wv][rr] = q; }
    }
    __syncthreads();
#pragma unroll
    for (int rr = 0; rr < 4; ++rr) {
      float s = redS[wv][rr] + redS[wv ^ 1][rr];
      float q = redQ[wv][rr] + redQ[wv ^ 1][rr];
      float mu = s * (1.0f / 128.0f);
      mu_[rr] = mu;
      rs_[rr] = rsqrtf(q * (1.0f / 128.0f) - mu * mu + cLNEPS);
    }
#pragma unroll
    for (int rr = 0; rr < 4; ++rr)
      xb[rh * 4 + rr][col] = (vv[rr] - mu_[rr]) * rs_[rr] * lw1 + lb1;
    __syncthreads();

    float a0 = 0, a1 = 0, a2 = 0, a3 = 0;
    for (int k = 0; k < cDP; k += 4) {
      float4 v0 = *(const float4*)&xb[rh * 4 + 0][k];
      float4 v1 = *(const float4*)&xb[rh * 4 + 1][k];
      float4 v2 = *(const float4*)&xb[rh * 4 + 2][k];
      float4 v3 = *(const float4*)&xb[rh * 4 + 3][k];
      float w0 = wT[(k + 0) * cDP + col], w1 = wT[(k + 1) * cDP + col];
      float w2 = wT[(k + 2) * cDP + col], w3 = wT[(k + 3) * cDP + col];
      a0 += v0.x * w0 + v0.y * w1 + v0.z * w2 + v0.w * w3;
      a1 += v1.x * w0 + v1.y * w1 + v1.z * w2 + v1.w * w3;
      a2 += v2.x * w0 + v2.y * w1 + v2.z * w2 + v2.w * w3;
      a3 += v3.x * w0 + v3.y * w1 + v3.z * w2 + v3.w * w3;
    }
    qb[rh * 4 + 0][col] = a0;
    qb[rh * 4 + 1][col] = a1;
    qb[rh * 4 + 2][col] = a2;
    qb[rh * 4 + 3][col] = a3;
    __syncthreads();

    for (int r = 0; r < 16; ++r) {
      int row = r0 + r;
      int bb = row / cNQ;
      int n = row - bb * cNQ;
      float4 q0 = *(const float4*)&qb[r][h * 16 + 0];
      float4 q1 = *(const float4*)&qb[r][h * 16 + 4];
      float4 q2 = *(const float4*)&qb[r][h * 16 + 8];
      float4 q3 = *(const float4*)&qb[r][h * 16 + 12];
      float dash = q0.x * pr[0] + q0.y * pr[1] + q0.z * pr[2] + q0.w * pr[3]
                 + q1.x * pr[4] + q1.y * pr[5] + q1.z * pr[6] + q1.w * pr[7]
                 + q2.x * pr[8] + q2.y * pr[9] + q2.z * pr[10] + q2.w * pr[11]
                 + q3.x * pr[12] + q3.y * pr[13] + q3.z * pr[14] + q3.w * pr[15];
      dash *= 0.5f;
      float ss = q0.x * q0.x + q0.y * q0.y + q0.z * q0.z + q0.w * q0.w
               + q1.x * q1.x + q1.y * q1.y + q1.z * q1.z + q1.w * q1.w
               + q2.x * q2.x + q2.y * q2.y + q2.z * q2.z + q2.w * q2.w
               + q3.x * q3.x + q3.y * q3.y + q3.z * q3.z + q3.w * q3.w;
      float un = cRATIO * expf(dash - 0.125f * ss);
      size_t base = (size_t)(bb * cH + h) * cNQ + n;
      q_un[base * cM + m] = un;
      float mx = wmax64(dash);
      if (lane == 0) mxq[base] = mx;
    }
    __syncthreads();
  }
}

// ================= K4: k dash/unnorm with temporal-split windowed writes =================
__global__ __launch_bounds__(512) void k4_kun(
    const float* __restrict__ kbuf, const float* __restrict__ proj,
    float* __restrict__ k_un, float* __restrict__ tmax)
{
  __shared__ float kb[16][cDP];
  const int tid = threadIdx.x;
  const int m = tid & 63, h = tid >> 6, lane = tid & 63;
  float pr[16];
#pragma unroll
  for (int d = 0; d < 16; ++d) pr[d] = proj[m * 16 + d];

  for (int g = blockIdx.x; g < ROWS_KV / 16; g += gridDim.x) {
    const int r0 = g * 16;
    __syncthreads();
    for (int i = tid; i < 16 * cDP; i += 512)
      kb[i >> 7][i & 127] = kbuf[(size_t)(r0 + (i >> 7)) * cDP + (i & 127)];
    __syncthreads();
    for (int r = 0; r < 16; ++r) {
      int row = r0 + r;
      int b = row / cNCTX;
      int t = row - b * cNCTX;
      float4 q0 = *(const float4*)&kb[r][h * 16 + 0];
      float4 q1 = *(const float4*)&kb[r][h * 16 + 4];
      float4 q2 = *(const float4*)&kb[r][h * 16 + 8];
      float4 q3 = *(const float4*)&kb[r][h * 16 + 12];
      float dash = q0.x * pr[0] + q0.y * pr[1] + q0.z * pr[2] + q0.w * pr[3]
                 + q1.x * pr[4] + q1.y * pr[5] + q1.z * pr[6] + q1.w * pr[7]
                 + q2.x * pr[8] + q2.y * pr[9] + q2.z * pr[10] + q2.w * pr[11]
                 + q3.x * pr[12] + q3.y * pr[13] + q3.z * pr[14] + q3.w * pr[15];
      dash *= 0.5f;
      float ss = q0.x * q0.x + q0.y * q0.y + q0.z * q0.z + q0.w * q0.w
               + q1.x * q1.x + q1.y * q1.y + q1.z * q1.z + q1.w * q1.w
               + q2.x * q2.x + q2.y * q2.y + q2.z * q2.z + q2.w * q2.w
               + q3.x * q3.x + q3.y * q3.y + q3.z * q3.z + q3.w * q3.w;
      float un = cRATIO * expf(dash - 0.125f * ss);
      if (t < cNQ)
        k_un[((size_t)(b * cH + h) * cNQ + t) * cM + m] = un;
      if (t >= cSHIFT)
        k_un[((size_t)((b + cB) * cH + h) * cNQ + (t - cSHIFT)) * cM + m] = un;
      float mx = wmax64(dash);
      if (lane == 0) tmax[(b * cH + h) * cNCTX + t] = mx;
    }
  }
}

// ================= K4b: windowed max over tokens -> mxk per (bb,h) =================
__global__ __launch_bounds__(256) void k4b_mxk(
    const float* __restrict__ tmax, float* __restrict__ mxk)
{
  const int bh = blockIdx.x;   // 0..127 = b*8+h
  const int tid = threadIdx.x;
  float m0 = -1e30f, m1 = -1e30f;
  for (int t = tid; t < cNCTX; t += 256) {
    float v = tmax[bh * cNCTX + t];
    if (t < cNQ) m0 = fmaxf(m0, v);
    if (t >= cSHIFT) m1 = fmaxf(m1, v);
  }
  __shared__ float s0[256], s1[256];
  s0[tid] = m0; s1[tid] = m1;
  __syncthreads();
  for (int s = 128; s; s >>= 1) {
    if (tid < s) { s0[tid] = fmaxf(s0[tid], s0[tid + s]); s1[tid] = fmaxf(s1[tid], s1[tid + s]); }
    __syncthreads();
  }
  if (tid == 0) { mxk[bh] = s0[0]; mxk[bh + 128] = s1[0]; }
}

// ================= K5a: ctx2[m][e] = sum_n kf*v, ksum[m] = sum_n kf =================
__global__ __launch_bounds__(256) void k5a_ctx(
    const float* __restrict__ k_un, const float* __restrict__ vbuf,
    const float* __restrict__ mxk,
    float* __restrict__ ctx2, float* __restrict__ ksum)
{
  const int bbh = blockIdx.x;       // 0..255
  const int bb = bbh >> 3, h = bbh & 7;
  const int b = bb & 15, toff = (bb >> 4) * cSHIFT;
  const float ek = expf(-mxk[bbh]);
  const int tid = threadIdx.x, m = tid & 63, eq = tid >> 6;
  __shared__ float ub[64][64];
  __shared__ float vb[64][16];
  float c0 = 0, c1 = 0, c2 = 0, c3 = 0, ks = 0;
  for (int n0 = 0; n0 < cNQ; n0 += 64) {
    for (int i = tid; i < 64 * 64; i += 256)
      ub[i >> 6][i & 63] = k_un[((size_t)bbh * cNQ + n0 + (i >> 6)) * cM + (i & 63)];
    for (int i = tid; i < 64 * 16; i += 256)
      vb[i >> 4][i & 15] = vbuf[((size_t)(b * cNCTX) + toff + n0 + (i >> 4)) * cDP + h * 16 + (i & 15)];
    __syncthreads();
#pragma unroll 4
    for (int nn = 0; nn < 64; ++nn) {
      float kf = ub[nn][m] * ek + cEPST;
      ks += kf;
      float4 vv = *(const float4*)&vb[nn][eq * 4];
      c0 += kf * vv.x; c1 += kf * vv.y; c2 += kf * vv.z; c3 += kf * vv.w;
    }
    __syncthreads();
  }
  ctx2[bbh * 1024 + m * 16 + eq * 4 + 0] = c0;
  ctx2[bbh * 1024 + m * 16 + eq * 4 + 1] = c1;
  ctx2[bbh * 1024 + m * 16 + eq * 4 + 2] = c2;
  ctx2[bbh * 1024 + m * 16 + eq * 4 + 3] = c3;
  if (eq == 0) ksum[bbh * cM + m] = ks;
}

// ================= K5b: per-token denom + out = d_inv * qf @ ctx2 =================
__global__ __launch_bounds__(256) void k5b_out(
    const float* __restrict__ q_un, const float* __restrict__ mxq,
    const float* __restrict__ ctx2, const float* __restrict__ ksum,
    float* __restrict__ attn)
{
  const int bb = blockIdx.y;      // 0..31
  const int chunk = blockIdx.x;   // 0..47 -> 64 tokens each
  const int tid = threadIdx.x;
  const int m = tid & 63, lane = tid & 63;
  __shared__ float c2[cH * cM * 16];   // 32 KB
  __shared__ float ksl[cH * cM];       // 2 KB
  __shared__ float qfl[2 * cH * cM];   // 4 KB
  __shared__ float dv[2][cH];
  __shared__ float ev[2][cH];
  for (int i = tid; i < cH * cM * 16; i += 256) c2[i] = ctx2[(size_t)bb * 8192 + i];
  for (int i = tid; i < cH * cM; i += 256) ksl[i] = ksum[bb * 512 + i];
  __syncthreads();

  for (int it = 0; it < 32; ++it) {
    const int n_base = chunk * 64 + it * 2;
    if (tid < 16) {
      int tt = tid >> 3, hh = tid & 7;
      ev[tt][hh] = expf(-mxq[(size_t)(bb * cH + hh) * cNQ + n_base + tt]);
    }
    __syncthreads();
    for (int i = tid; i < 2 * cH * cM; i += 256) {
      int tt = i >> 9, hh = (i >> 6) & 7, mm = i & 63;
      qfl[i] = q_un[((size_t)(bb * cH + hh) * cNQ + n_base + tt) * cM + mm] * ev[tt][hh] + cEPST;
    }
    __syncthreads();
#pragma unroll
    for (int p = 0; p < 4; ++p) {
      int pp = (tid >> 6) * 4 + p;
      int tt = pp >> 3, hh = pp & 7;
      float v = qfl[tt * 512 + hh * 64 + m] * ksl[hh * 64 + m];
      v = wsum64(v);
      if (lane == 0) dv[tt][hh] = 1.0f / v;
    }
    __syncthreads();
    {
      int tt = tid >> 7, hh = (tid >> 4) & 7, e = tid & 15;
      float acc = 0.0f;
#pragma unroll 8
      for (int mm = 0; mm < 64; ++mm)
        acc += qfl[tt * 512 + hh * 64 + mm] * c2[hh * 1024 + mm * 16 + e];
      attn[((size_t)(bb * cNQ) + n_base + tt) * cDP + hh * 16 + e] = acc * dv[tt][hh];
    }
    __syncthreads();
  }
}

// ================= K6: yout = y1 + attn @ wo.T + wo_b =================
__global__ __launch_bounds__(512) void k6_wo(
    const float* __restrict__ attn,
    const float* __restrict__ wo, const float* __restrict__ wob,
    const float* __restrict__ y1, float* __restrict__ yout)
{
  __shared__ float wT[cDP * cDP];
  __shared__ float xb[16][cDP];
  const int tid = threadIdx.x;
  for (int i = tid; i < cDP * cDP; i += 512) {
    int j = i >> 7, k = i & 127;
    wT[k * cDP + j] = wo[i];
  }
  const int col = tid & 127, rh = tid >> 7;
  const float wb = wob[col];
  __syncthreads();

  for (int g = blockIdx.x; g < ROWS_Q / 16; g += gridDim.x) {
    const int r0 = g * 16;
    __syncthreads();
    for (int i = tid; i < 16 * cDP; i += 512)
      xb[i >> 7][i & 127] = attn[(size_t)(r0 + (i >> 7)) * cDP + (i & 127)];
    __syncthreads();
    float a0 = wb, a1 = wb, a2 = wb, a3 = wb;
    for (int k = 0; k < cDP; k += 4) {
      float4 v0 = *(const float4*)&xb[rh * 4 + 0][k];
      float4 v1 = *(const float4*)&xb[rh * 4 + 1][k];
      float4 v2 = *(const float4*)&xb[rh * 4 + 2][k];
      float4 v3 = *(const float4*)&xb[rh * 4 + 3][k];
      float w0 = wT[(k + 0) * cDP + col], w1 = wT[(k + 1) * cDP + col];
      float w2 = wT[(k + 2) * cDP + col], w3 = wT[(k + 3) * cDP + col];
      a0 += v0.x * w0 + v0.y * w1 + v0.z * w2 + v0.w * w3;
      a1 += v1.x * w0 + v1.y * w1 + v1.z * w2 + v1.w * w3;
      a2 += v2.x * w0 + v2.y * w1 + v2.z * w2 + v2.w * w3;
      a3 += v3.x * w0 + v3.y * w1 + v3.z * w2 + v3.w * w3;
    }
    size_t o0 = (size_t)(r0 + rh * 4 + 0) * cDP + col;
    size_t o1 = (size_t)(r0 + rh * 4 + 1) * cDP + col;
    size_t o2 = (size_t)(r0 + rh * 4 + 2) * cDP + col;
    size_t o3 = (size_t)(r0 + rh * 4 + 3) * cDP + col;
    yout[o0] = a0 + y1[o0];
    yout[o1] = a1 + y1[o1];
    yout[o2] = a2 + y1[o2];
    yout[o3] = a3 + y1[o3];
  }
}

// =============================== launch ===============================
extern "C" void kernel_launch(void* const* d_in, const int* in_sizes, int n_in,
                              void* d_out, int out_size, void* d_ws, size_t ws_size,
                              hipStream_t stream) {
  (void)in_sizes; (void)n_in; (void)out_size; (void)ws_size;
  const float* x    = (const float*)d_in[0];
  const float* y    = (const float*)d_in[1];
  const float* proj = (const float*)d_in[2];
  const float* ln1w = (const float*)d_in[3];
  const float* ln1b = (const float*)d_in[4];
  const float* ln2w = (const float*)d_in[5];
  const float* ln2b = (const float*)d_in[6];
  const float* ln4w = (const float*)d_in[7];
  const float* ln4b = (const float*)d_in[8];
  const float* fcw  = (const float*)d_in[9];
  const float* fcb  = (const float*)d_in[10];
  const float* prw  = (const float*)d_in[11];
  const float* prb  = (const float*)d_in[12];
  const float* wq   = (const float*)d_in[13];
  const float* wk   = (const float*)d_in[14];
  const float* wv   = (const float*)d_in[15];
  const float* wo   = (const float*)d_in[16];
  const float* wob  = (const float*)d_in[17];

  float* out  = (float*)d_out;
  float* q_un = out + 12582912;            // (32,8,3072,64)
  float* k_un = out + 62914560;            // (32,8,3072,64)

  float* ws   = (float*)d_ws;              // total 27,164,928 floats = 109 MB
  float* y1   = ws;                        // 12,582,912
  float* kbuf = ws + 12582912;             // 6,553,600
  float* vbuf = ws + 19136512;             // 6,553,600
  float* attn = ws + 12582912;             // aliases kbuf+vbuf (dead after k5a)
  float* mxq  = ws + 25690112;             // 786,432
  float* tmax = ws + 26476544;             // 409,600
  float* mxk  = ws + 26886144;             // 256
  float* ksum = ws + 26886400;             // 16,384
  float* ctx2 = ws + 26902784;             // 262,144

  k1_mlp<<<dim3(256), dim3(512), 0, stream>>>(y, ln4w, ln4b, fcw, fcb, prw, prb, y1);
  k2_kv<<<dim3(400), dim3(512), 0, stream>>>(x, ln2w, ln2b, wk, wv, kbuf, vbuf);
  k3_q<<<dim3(512), dim3(512), 0, stream>>>(y1, ln1w, ln1b, wq, proj, q_un, mxq);
  k4_kun<<<dim3(400), dim3(512), 0, stream>>>(kbuf, proj, k_un, tmax);
  k4b_mxk<<<dim3(128), dim3(256), 0, stream>>>(tmax, mxk);
  k5a_ctx<<<dim3(256), dim3(256), 0, stream>>>(k_un, vbuf, mxk, ctx2, ksum);
  k5b_out<<<dim3(48, 32), dim3(256), 0, stream>>>(q_un, mxq, ctx2, ksum, attn);
  k6_wo<<<dim3(512), dim3(512), 0, stream>>>(attn, wo, wob, y1, out);
}

// Round 4
// 812.759 us; speedup vs baseline: 3.2396x; 3.2396x over previous
//
#include <hip/hip_runtime.h>
#include <math.h>

// ---------------- problem constants ----------------
constexpr int cH = 8;
constexpr int cDP = 128;
constexpr int cM = 64;
constexpr int cB = 16;
constexpr int cNCTX = 3200;
constexpr int cNQ = 3072;
constexpr int cSHIFT = 128;
constexpr int ROWS_Q = 2 * cB * cNQ;    // 98304
constexpr int ROWS_KV = cB * cNCTX;     // 51200
constexpr float cRATIO = 0.125f;
constexpr float cEPST = 0.125e-4f;
constexpr float cLNEPS = 1e-5f;

__device__ __forceinline__ float wmax64(float v) {
#pragma unroll
  for (int o = 32; o; o >>= 1) v = fmaxf(v, __shfl_xor(v, o));
  return v;
}
__device__ __forceinline__ float wsum64(float v) {
#pragma unroll
  for (int o = 32; o; o >>= 1) v += __shfl_xor(v, o);
  return v;
}
__device__ __forceinline__ float gelu_f(float x) {
  return 0.5f * x * (1.0f + tanhf(0.79788456080286536f * (x + 0.044715f * x * x * x)));
}
// fp32 -> bf16 (RTNE), returned in low 16 bits
__device__ __forceinline__ unsigned int bf16r(float f) {
  unsigned int x = __float_as_uint(f);
  return (x + 0x7fffu + ((x >> 16) & 1u)) >> 16;
}
// 8 packed bf16 (uint4) -> 8 floats
__device__ __forceinline__ void cvt8(uint4 u, float f[8]) {
  f[0] = __uint_as_float(u.x << 16);
  f[1] = __uint_as_float(u.x & 0xffff0000u);
  f[2] = __uint_as_float(u.y << 16);
  f[3] = __uint_as_float(u.y & 0xffff0000u);
  f[4] = __uint_as_float(u.z << 16);
  f[5] = __uint_as_float(u.z & 0xffff0000u);
  f[6] = __uint_as_float(u.w << 16);
  f[7] = __uint_as_float(u.w & 0xffff0000u);
}
// swizzled ushort index for element (row, k) in a [*][128] bf16 tile:
// slot = (k>>3) ^ (row&15), giving conflict-free b128 column reads.
__device__ __forceinline__ int swz(int row, int k) {
  return row * 128 + ((((k >> 3) ^ (row & 15)) << 3) | (k & 7));
}

// 4x4 register-tiled 32x128x128 GEMM micro-kernel; rows ry*4.., cols cx+32*cc
__device__ __forceinline__ void gemm_tile(const uint4* __restrict__ a4,
                                          const uint4* __restrict__ w4,
                                          int cx, int ry, float acc[4][4]) {
#pragma unroll 2
  for (int kg = 0; kg < 16; ++kg) {
    uint4 xv[4], wv[4];
#pragma unroll
    for (int rr = 0; rr < 4; ++rr) {
      int r = ry * 4 + rr;
      xv[rr] = a4[r * 16 + (kg ^ (r & 15))];
    }
#pragma unroll
    for (int cc = 0; cc < 4; ++cc) {
      int c = cx + 32 * cc;
      wv[cc] = w4[c * 16 + (kg ^ (c & 15))];
    }
    float xf[4][8];
#pragma unroll
    for (int rr = 0; rr < 4; ++rr) cvt8(xv[rr], xf[rr]);
#pragma unroll
    for (int cc = 0; cc < 4; ++cc) {
      float wf[8];
      cvt8(wv[cc], wf);
#pragma unroll
      for (int rr = 0; rr < 4; ++rr)
#pragma unroll
        for (int i = 0; i < 8; ++i)
          acc[rr][cc] = fmaf(xf[rr][i], wf[i], acc[rr][cc]);
    }
  }
}

// ============ K0: weight prep -> bf16, [n][k] layout, pre-swizzled ============
__global__ __launch_bounds__(256) void k0_prep(
    const float* __restrict__ fcw, const float* __restrict__ prw,
    const float* __restrict__ wq, const float* __restrict__ wo,
    unsigned short* __restrict__ fcT, unsigned short* __restrict__ prT,
    unsigned short* __restrict__ wqT, unsigned short* __restrict__ woT) {
  const int mat = blockIdx.x;
  const float* src = mat == 0 ? fcw : mat == 1 ? prw : mat == 2 ? wq : wo;
  unsigned short* dst = mat == 0 ? fcT : mat == 1 ? prT : mat == 2 ? wqT : woT;
  const bool tr = (mat < 2);   // fc_w/pr_w are [k][n]; wq/wo are [n][k]
  for (int i = threadIdx.x; i < 16384; i += 256) {
    int n = i >> 7, k = i & 127;
    float f = tr ? src[k * 128 + n] : src[i];
    dst[swz(n, k)] = (unsigned short)bf16r(f);
  }
}

// ============ K1: MLP (LN4 -> fc -> gelu -> pr -> +y), 32 rows/iter ============
__global__ __launch_bounds__(256, 2) void k1_mlp(
    const float* __restrict__ y,
    const float* __restrict__ ln4w, const float* __restrict__ ln4b,
    const unsigned short* __restrict__ fcT, const float* __restrict__ fcb,
    const unsigned short* __restrict__ prT, const float* __restrict__ prb,
    float* __restrict__ y1) {
  __shared__ unsigned short wfc[128 * 128];
  __shared__ unsigned short wpr[128 * 128];
  __shared__ unsigned short xb[32 * 128];
  __shared__ unsigned short hb[32 * 128];
  const int tid = threadIdx.x;
  {
    const uint4* s1 = (const uint4*)fcT; uint4* d1 = (uint4*)wfc;
    const uint4* s2 = (const uint4*)prT; uint4* d2 = (uint4*)wpr;
    for (int i = tid; i < 2048; i += 256) { d1[i] = s1[i]; d2[i] = s2[i]; }
  }
  const int lrow = tid >> 3, lsub = tid & 7;
  const int cx = tid & 31, ry = tid >> 5;
  float fbias[4], pbias[4];
#pragma unroll
  for (int cc = 0; cc < 4; ++cc) { fbias[cc] = fcb[cx + 32 * cc]; pbias[cc] = prb[cx + 32 * cc]; }
  uint4* xb4 = (uint4*)xb;
  const uint4* wfc4 = (const uint4*)wfc;
  const uint4* wpr4 = (const uint4*)wpr;
  const uint4* hb4 = (const uint4*)hb;
  __syncthreads();

  for (int g = blockIdx.x; g < ROWS_Q / 32; g += gridDim.x) {
    const int r0 = g * 32;
    {  // ---- LN4: row lrow, cols lsub*16..+15 ----
      const float* yr = y + (size_t)(r0 + lrow) * 128 + lsub * 16;
      float v[16];
      *(float4*)&v[0] = *(const float4*)(yr + 0);
      *(float4*)&v[4] = *(const float4*)(yr + 4);
      *(float4*)&v[8] = *(const float4*)(yr + 8);
      *(float4*)&v[12] = *(const float4*)(yr + 12);
      float s = 0.f, q = 0.f;
#pragma unroll
      for (int j = 0; j < 16; ++j) { s += v[j]; q += v[j] * v[j]; }
#pragma unroll
      for (int o = 1; o <= 4; o <<= 1) { s += __shfl_xor(s, o); q += __shfl_xor(q, o); }
      float mu = s * (1.0f / 128.0f);
      float rs = rsqrtf(q * (1.0f / 128.0f) - mu * mu + cLNEPS);
      float lw[16], lb[16];
      *(float4*)&lw[0] = *(const float4*)(ln4w + lsub * 16 + 0);
      *(float4*)&lw[4] = *(const float4*)(ln4w + lsub * 16 + 4);
      *(float4*)&lw[8] = *(const float4*)(ln4w + lsub * 16 + 8);
      *(float4*)&lw[12] = *(const float4*)(ln4w + lsub * 16 + 12);
      *(float4*)&lb[0] = *(const float4*)(ln4b + lsub * 16 + 0);
      *(float4*)&lb[4] = *(const float4*)(ln4b + lsub * 16 + 4);
      *(float4*)&lb[8] = *(const float4*)(ln4b + lsub * 16 + 8);
      *(float4*)&lb[12] = *(const float4*)(ln4b + lsub * 16 + 12);
      unsigned int us[8];
#pragma unroll
      for (int j = 0; j < 8; ++j) {
        float f0 = (v[2 * j] - mu) * rs * lw[2 * j] + lb[2 * j];
        float f1 = (v[2 * j + 1] - mu) * rs * lw[2 * j + 1] + lb[2 * j + 1];
        us[j] = bf16r(f0) | (bf16r(f1) << 16);
      }
      int s0 = (lsub * 2) ^ (lrow & 15), s1 = (lsub * 2 + 1) ^ (lrow & 15);
      xb4[lrow * 16 + s0] = make_uint4(us[0], us[1], us[2], us[3]);
      xb4[lrow * 16 + s1] = make_uint4(us[4], us[5], us[6], us[7]);
    }
    __syncthreads();
    // ---- GEMM1 + gelu -> hb ----
    float acc[4][4];
#pragma unroll
    for (int rr = 0; rr < 4; ++rr)
#pragma unroll
      for (int cc = 0; cc < 4; ++cc) acc[rr][cc] = fbias[cc];
    gemm_tile(xb4, wfc4, cx, ry, acc);
#pragma unroll
    for (int rr = 0; rr < 4; ++rr)
#pragma unroll
      for (int cc = 0; cc < 4; ++cc) {
        int r = ry * 4 + rr, c = cx + 32 * cc;
        hb[swz(r, c)] = (unsigned short)bf16r(gelu_f(acc[rr][cc]));
      }
    __syncthreads();
    // ---- GEMM2 + residual ----
    float a2[4][4];
#pragma unroll
    for (int rr = 0; rr < 4; ++rr)
#pragma unroll
      for (int cc = 0; cc < 4; ++cc) a2[rr][cc] = pbias[cc];
    gemm_tile(hb4, wpr4, cx, ry, a2);
#pragma unroll
    for (int rr = 0; rr < 4; ++rr)
#pragma unroll
      for (int cc = 0; cc < 4; ++cc) {
        size_t o = (size_t)(r0 + ry * 4 + rr) * 128 + cx + 32 * cc;
        y1[o] = a2[rr][cc] + y[o];
      }
    __syncthreads();
  }
}

// ============ K2: LN2(x) -> k,v projections (fp32, K=32) ============
__global__ __launch_bounds__(512) void k2_kv(
    const float* __restrict__ x,
    const float* __restrict__ ln2w, const float* __restrict__ ln2b,
    const float* __restrict__ wkw, const float* __restrict__ wvw,
    float* __restrict__ kbuf, float* __restrict__ vbuf) {
  __shared__ float wkT[32 * cDP];
  __shared__ float wvT[32 * cDP];
  __shared__ float xbs[16][32];
  const int tid = threadIdx.x;
  for (int i = tid; i < 32 * cDP; i += 512) {
    int j = i >> 5, d = i & 31;
    wkT[d * cDP + j] = wkw[i];
    wvT[d * cDP + j] = wvw[i];
  }
  const int dl = tid & 31, rl = tid >> 5;
  const int col = tid & 127, rh = tid >> 7;
  const float l2w = ln2w[dl], l2b = ln2b[dl];
  __syncthreads();
  for (int g = blockIdx.x; g < ROWS_KV / 16; g += gridDim.x) {
    const int r0 = g * 16;
    __syncthreads();
    {
      float v = x[(size_t)(r0 + rl) * 32 + dl];
      float s = v, q = v * v;
#pragma unroll
      for (int o = 16; o; o >>= 1) { s += __shfl_xor(s, o); q += __shfl_xor(q, o); }
      float mu = s * (1.0f / 32.0f);
      float var = q * (1.0f / 32.0f) - mu * mu;
      xbs[rl][dl] = (v - mu) * rsqrtf(var + cLNEPS) * l2w + l2b;
    }
    __syncthreads();
    float ak0 = 0, ak1 = 0, ak2 = 0, ak3 = 0, av0 = 0, av1 = 0, av2 = 0, av3 = 0;
    for (int d = 0; d < 32; d += 4) {
      float4 v0 = *(const float4*)&xbs[rh * 4 + 0][d];
      float4 v1 = *(const float4*)&xbs[rh * 4 + 1][d];
      float4 v2 = *(const float4*)&xbs[rh * 4 + 2][d];
      float4 v3 = *(const float4*)&xbs[rh * 4 + 3][d];
      float k0 = wkT[(d + 0) * cDP + col], k1 = wkT[(d + 1) * cDP + col];
      float k2 = wkT[(d + 2) * cDP + col], k3 = wkT[(d + 3) * cDP + col];
      float u0 = wvT[(d + 0) * cDP + col], u1 = wvT[(d + 1) * cDP + col];
      float u2 = wvT[(d + 2) * cDP + col], u3 = wvT[(d + 3) * cDP + col];
      ak0 += v0.x * k0 + v0.y * k1 + v0.z * k2 + v0.w * k3;
      ak1 += v1.x * k0 + v1.y * k1 + v1.z * k2 + v1.w * k3;
      ak2 += v2.x * k0 + v2.y * k1 + v2.z * k2 + v2.w * k3;
      ak3 += v3.x * k0 + v3.y * k1 + v3.z * k2 + v3.w * k3;
      av0 += v0.x * u0 + v0.y * u1 + v0.z * u2 + v0.w * u3;
      av1 += v1.x * u0 + v1.y * u1 + v1.z * u2 + v1.w * u3;
      av2 += v2.x * u0 + v2.y * u1 + v2.z * u2 + v2.w * u3;
      av3 += v3.x * u0 + v3.y * u1 + v3.z * u2 + v3.w * u3;
    }
    kbuf[(size_t)(r0 + rh * 4 + 0) * cDP + col] = ak0;
    kbuf[(size_t)(r0 + rh * 4 + 1) * cDP + col] = ak1;
    kbuf[(size_t)(r0 + rh * 4 + 2) * cDP + col] = ak2;
    kbuf[(size_t)(r0 + rh * 4 + 3) * cDP + col] = ak3;
    vbuf[(size_t)(r0 + rh * 4 + 0) * cDP + col] = av0;
    vbuf[(size_t)(r0 + rh * 4 + 1) * cDP + col] = av1;
    vbuf[(size_t)(r0 + rh * 4 + 2) * cDP + col] = av2;
    vbuf[(size_t)(r0 + rh * 4 + 3) * cDP + col] = av3;
  }
}

// ============ K3: LN1 -> q GEMM -> FAVOR features ============
__global__ __launch_bounds__(256, 2) void k3_q(
    const float* __restrict__ y1,
    const float* __restrict__ ln1w, const float* __restrict__ ln1b,
    const unsigned short* __restrict__ wqT, const float* __restrict__ proj,
    float* __restrict__ q_un, float* __restrict__ mxq) {
  __shared__ unsigned short wqs[128 * 128];
  __shared__ unsigned short xb[32 * 128];
  __shared__ float qb[32][132];
  const int tid = threadIdx.x;
  {
    const uint4* s1 = (const uint4*)wqT; uint4* d1 = (uint4*)wqs;
    for (int i = tid; i < 2048; i += 256) d1[i] = s1[i];
  }
  const int lrow = tid >> 3, lsub = tid & 7;
  const int cx = tid & 31, ry = tid >> 5;
  const int lane = tid & 63, wvid = tid >> 6;
  const int m = lane;
  float pr[16];
#pragma unroll
  for (int d = 0; d < 16; ++d) pr[d] = proj[m * 16 + d];
  uint4* xb4 = (uint4*)xb;
  const uint4* wq4 = (const uint4*)wqs;
  __syncthreads();

  for (int g = blockIdx.x; g < ROWS_Q / 32; g += gridDim.x) {
    const int r0 = g * 32;
    {  // LN1
      const float* yr = y1 + (size_t)(r0 + lrow) * 128 + lsub * 16;
      float v[16];
      *(float4*)&v[0] = *(const float4*)(yr + 0);
      *(float4*)&v[4] = *(const float4*)(yr + 4);
      *(float4*)&v[8] = *(const float4*)(yr + 8);
      *(float4*)&v[12] = *(const float4*)(yr + 12);
      float s = 0.f, q = 0.f;
#pragma unroll
      for (int j = 0; j < 16; ++j) { s += v[j]; q += v[j] * v[j]; }
#pragma unroll
      for (int o = 1; o <= 4; o <<= 1) { s += __shfl_xor(s, o); q += __shfl_xor(q, o); }
      float mu = s * (1.0f / 128.0f);
      float rs = rsqrtf(q * (1.0f / 128.0f) - mu * mu + cLNEPS);
      float lw[16], lb[16];
      *(float4*)&lw[0] = *(const float4*)(ln1w + lsub * 16 + 0);
      *(float4*)&lw[4] = *(const float4*)(ln1w + lsub * 16 + 4);
      *(float4*)&lw[8] = *(const float4*)(ln1w + lsub * 16 + 8);
      *(float4*)&lw[12] = *(const float4*)(ln1w + lsub * 16 + 12);
      *(float4*)&lb[0] = *(const float4*)(ln1b + lsub * 16 + 0);
      *(float4*)&lb[4] = *(const float4*)(ln1b + lsub * 16 + 4);
      *(float4*)&lb[8] = *(const float4*)(ln1b + lsub * 16 + 8);
      *(float4*)&lb[12] = *(const float4*)(ln1b + lsub * 16 + 12);
      unsigned int us[8];
#pragma unroll
      for (int j = 0; j < 8; ++j) {
        float f0 = (v[2 * j] - mu) * rs * lw[2 * j] + lb[2 * j];
        float f1 = (v[2 * j + 1] - mu) * rs * lw[2 * j + 1] + lb[2 * j + 1];
        us[j] = bf16r(f0) | (bf16r(f1) << 16);
      }
      int s0 = (lsub * 2) ^ (lrow & 15), s1 = (lsub * 2 + 1) ^ (lrow & 15);
      xb4[lrow * 16 + s0] = make_uint4(us[0], us[1], us[2], us[3]);
      xb4[lrow * 16 + s1] = make_uint4(us[4], us[5], us[6], us[7]);
    }
    __syncthreads();
    float acc[4][4] = {};
    gemm_tile(xb4, wq4, cx, ry, acc);
#pragma unroll
    for (int rr = 0; rr < 4; ++rr)
#pragma unroll
      for (int cc = 0; cc < 4; ++cc) qb[ry * 4 + rr][cx + 32 * cc] = acc[rr][cc];
    __syncthreads();
    // FAVOR features: wave wvid handles heads 2*wvid, 2*wvid+1; lanes = m
    const int bb = r0 / cNQ;
    const int n0 = r0 - bb * cNQ;
    for (int r = 0; r < 32; ++r) {
#pragma unroll
      for (int hh = 0; hh < 2; ++hh) {
        int h = wvid * 2 + hh;
        float4 q0 = *(const float4*)&qb[r][h * 16 + 0];
        float4 q1 = *(const float4*)&qb[r][h * 16 + 4];
        float4 q2 = *(const float4*)&qb[r][h * 16 + 8];
        float4 q3 = *(const float4*)&qb[r][h * 16 + 12];
        float dash = q0.x * pr[0] + q0.y * pr[1] + q0.z * pr[2] + q0.w * pr[3]
                   + q1.x * pr[4] + q1.y * pr[5] + q1.z * pr[6] + q1.w * pr[7]
                   + q2.x * pr[8] + q2.y * pr[9] + q2.z * pr[10] + q2.w * pr[11]
                   + q3.x * pr[12] + q3.y * pr[13] + q3.z * pr[14] + q3.w * pr[15];
        dash *= 0.5f;
        float ss = q0.x * q0.x + q0.y * q0.y + q0.z * q0.z + q0.w * q0.w
                 + q1.x * q1.x + q1.y * q1.y + q1.z * q1.z + q1.w * q1.w
                 + q2.x * q2.x + q2.y * q2.y + q2.z * q2.z + q2.w * q2.w
                 + q3.x * q3.x + q3.y * q3.y + q3.z * q3.z + q3.w * q3.w;
        float un = cRATIO * expf(dash - 0.125f * ss);
        size_t base = (size_t)(bb * cH + h) * cNQ + n0 + r;
        q_un[base * cM + m] = un;
        float mx = wmax64(dash);
        if (lane == 0) mxq[base] = mx;
      }
    }
    __syncthreads();
  }
}

// ============ K4: k features + temporal-split windowed writes ============
__global__ __launch_bounds__(512) void k4_kun(
    const float* __restrict__ kbuf, const float* __restrict__ proj,
    float* __restrict__ k_un, float* __restrict__ tmax) {
  __shared__ float kb[16][cDP];
  const int tid = threadIdx.x;
  const int m = tid & 63, h = tid >> 6, lane = tid & 63;
  float pr[16];
#pragma unroll
  for (int d = 0; d < 16; ++d) pr[d] = proj[m * 16 + d];
  for (int g = blockIdx.x; g < ROWS_KV / 16; g += gridDim.x) {
    const int r0 = g * 16;
    __syncthreads();
    for (int i = tid; i < 16 * cDP; i += 512)
      kb[i >> 7][i & 127] = kbuf[(size_t)(r0 + (i >> 7)) * cDP + (i & 127)];
    __syncthreads();
    for (int r = 0; r < 16; ++r) {
      int row = r0 + r;
      int b = row / cNCTX;
      int t = row - b * cNCTX;
      float4 q0 = *(const float4*)&kb[r][h * 16 + 0];
      float4 q1 = *(const float4*)&kb[r][h * 16 + 4];
      float4 q2 = *(const float4*)&kb[r][h * 16 + 8];
      float4 q3 = *(const float4*)&kb[r][h * 16 + 12];
      float dash = q0.x * pr[0] + q0.y * pr[1] + q0.z * pr[2] + q0.w * pr[3]
                 + q1.x * pr[4] + q1.y * pr[5] + q1.z * pr[6] + q1.w * pr[7]
                 + q2.x * pr[8] + q2.y * pr[9] + q2.z * pr[10] + q2.w * pr[11]
                 + q3.x * pr[12] + q3.y * pr[13] + q3.z * pr[14] + q3.w * pr[15];
      dash *= 0.5f;
      float ss = q0.x * q0.x + q0.y * q0.y + q0.z * q0.z + q0.w * q0.w
               + q1.x * q1.x + q1.y * q1.y + q1.z * q1.z + q1.w * q1.w
               + q2.x * q2.x + q2.y * q2.y + q2.z * q2.z + q2.w * q2.w
               + q3.x * q3.x + q3.y * q3.y + q3.z * q3.z + q3.w * q3.w;
      float un = cRATIO * expf(dash - 0.125f * ss);
      if (t < cNQ)
        k_un[((size_t)(b * cH + h) * cNQ + t) * cM + m] = un;
      if (t >= cSHIFT)
        k_un[((size_t)((b + cB) * cH + h) * cNQ + (t - cSHIFT)) * cM + m] = un;
      float mx = wmax64(dash);
      if (lane == 0) tmax[(b * cH + h) * cNCTX + t] = mx;
    }
  }
}

// ============ K4b: windowed max ============
__global__ __launch_bounds__(256) void k4b_mxk(
    const float* __restrict__ tmax, float* __restrict__ mxk) {
  const int bh = blockIdx.x;
  const int tid = threadIdx.x;
  float m0 = -1e30f, m1 = -1e30f;
  for (int t = tid; t < cNCTX; t += 256) {
    float v = tmax[bh * cNCTX + t];
    if (t < cNQ) m0 = fmaxf(m0, v);
    if (t >= cSHIFT) m1 = fmaxf(m1, v);
  }
  __shared__ float s0[256], s1[256];
  s0[tid] = m0; s1[tid] = m1;
  __syncthreads();
  for (int s = 128; s; s >>= 1) {
    if (tid < s) { s0[tid] = fmaxf(s0[tid], s0[tid + s]); s1[tid] = fmaxf(s1[tid], s1[tid + s]); }
    __syncthreads();
  }
  if (tid == 0) { mxk[bh] = s0[0]; mxk[bh + 128] = s1[0]; }
}

// ============ K5a: partial ctx/ksum over 512-token chunks ============
__global__ __launch_bounds__(256) void k5a_ctx(
    const float* __restrict__ k_un, const float* __restrict__ vbuf,
    const float* __restrict__ mxk,
    float* __restrict__ part_c, float* __restrict__ part_k) {
  const int bbh = blockIdx.x;   // 0..255
  const int ch = blockIdx.y;    // 0..5
  const int bb = bbh >> 3, h = bbh & 7;
  const int b = bb & 15, toff = (bb >> 4) * cSHIFT;
  const float ek = expf(-mxk[bbh]);
  const int tid = threadIdx.x, m = tid & 63, eq = tid >> 6;
  __shared__ float ub[64][64];
  __shared__ float vb[64][16];
  float c0 = 0, c1 = 0, c2 = 0, c3 = 0, ks = 0;
  const int nb = ch * 512;
  for (int n0 = nb; n0 < nb + 512; n0 += 64) {
    for (int i = tid; i < 64 * 64; i += 256)
      ub[i >> 6][i & 63] = k_un[((size_t)bbh * cNQ + n0 + (i >> 6)) * cM + (i & 63)];
    for (int i = tid; i < 64 * 16; i += 256)
      vb[i >> 4][i & 15] = vbuf[((size_t)(b * cNCTX) + toff + n0 + (i >> 4)) * cDP + h * 16 + (i & 15)];
    __syncthreads();
#pragma unroll 4
    for (int nn = 0; nn < 64; ++nn) {
      float kf = ub[nn][m] * ek + cEPST;
      ks += kf;
      float4 vv = *(const float4*)&vb[nn][eq * 4];
      c0 += kf * vv.x; c1 += kf * vv.y; c2 += kf * vv.z; c3 += kf * vv.w;
    }
    __syncthreads();
  }
  size_t po = (size_t)ch * 256 + bbh;
  part_c[po * 1024 + m * 16 + eq * 4 + 0] = c0;
  part_c[po * 1024 + m * 16 + eq * 4 + 1] = c1;
  part_c[po * 1024 + m * 16 + eq * 4 + 2] = c2;
  part_c[po * 1024 + m * 16 + eq * 4 + 3] = c3;
  if (eq == 0) part_k[po * 64 + m] = ks;
}

__global__ __launch_bounds__(256) void k5a2_red(
    const float* __restrict__ part_c, const float* __restrict__ part_k,
    float* __restrict__ ctx2, float* __restrict__ ksum) {
  const int bbh = blockIdx.x;
  const int tid = threadIdx.x;
  for (int i = tid; i < 1024; i += 256) {
    float s = 0;
#pragma unroll
    for (int ch = 0; ch < 6; ++ch) s += part_c[((size_t)ch * 256 + bbh) * 1024 + i];
    ctx2[bbh * 1024 + i] = s;
  }
  if (tid < 64) {
    float s = 0;
#pragma unroll
    for (int ch = 0; ch < 6; ++ch) s += part_k[((size_t)ch * 256 + bbh) * 64 + tid];
    ksum[bbh * cM + tid] = s;
  }
}

// ============ K5b: denom + out = d_inv * qf @ ctx2 ============
__global__ __launch_bounds__(256) void k5b_out(
    const float* __restrict__ q_un, const float* __restrict__ mxq,
    const float* __restrict__ ctx2, const float* __restrict__ ksum,
    float* __restrict__ attn) {
  const int chunk = blockIdx.x;   // 0..11
  const int bbh = blockIdx.y;     // 0..255
  const int bb = bbh >> 3, h = bbh & 7;
  const int tid = threadIdx.x, lane = tid & 63;
  __shared__ float c2[cM * 16];
  __shared__ float ksl[cM];
  __shared__ float qf[16][cM];
  __shared__ float evs[16], dv[16];
  for (int i = tid; i < cM * 16; i += 256) c2[i] = ctx2[(size_t)bbh * 1024 + i];
  if (tid < cM) ksl[tid] = ksum[bbh * cM + tid];
  __syncthreads();
  for (int it = 0; it < 16; ++it) {
    const int t0 = chunk * 256 + it * 16;
    if (tid < 16) evs[tid] = expf(-mxq[(size_t)bbh * cNQ + t0 + tid]);
    __syncthreads();
#pragma unroll
    for (int j = 0; j < 4; ++j) {
      int i = tid + j * 256;
      int tt = i >> 6, mm = i & 63;
      qf[tt][mm] = q_un[((size_t)bbh * cNQ + t0 + tt) * cM + mm] * evs[tt] + cEPST;
    }
    __syncthreads();
#pragma unroll
    for (int p = 0; p < 4; ++p) {
      int tt = (tid >> 6) * 4 + p;
      float v = qf[tt][lane] * ksl[lane];
      v = wsum64(v);
      if (lane == 0) dv[tt] = 1.0f / v;
    }
    __syncthreads();
    {
      int tt = tid >> 4, e = tid & 15;
      float a = 0.f;
#pragma unroll 8
      for (int mm = 0; mm < cM; ++mm) a += qf[tt][mm] * c2[mm * 16 + e];
      attn[((size_t)(bb * cNQ) + t0 + tt) * cDP + h * 16 + e] = a * dv[tt];
    }
    __syncthreads();
  }
}

// ============ K6: yout = y1 + attn @ wo.T + wo_b ============
__global__ __launch_bounds__(256, 2) void k6_wo(
    const float* __restrict__ attn,
    const unsigned short* __restrict__ woT, const float* __restrict__ wob,
    const float* __restrict__ y1, float* __restrict__ yout) {
  __shared__ unsigned short wos[128 * 128];
  __shared__ unsigned short xb[32 * 128];
  const int tid = threadIdx.x;
  {
    const uint4* s1 = (const uint4*)woT; uint4* d1 = (uint4*)wos;
    for (int i = tid; i < 2048; i += 256) d1[i] = s1[i];
  }
  const int lrow = tid >> 3, lsub = tid & 7;
  const int cx = tid & 31, ry = tid >> 5;
  float wbias[4];
#pragma unroll
  for (int cc = 0; cc < 4; ++cc) wbias[cc] = wob[cx + 32 * cc];
  uint4* xb4 = (uint4*)xb;
  const uint4* wo4 = (const uint4*)wos;
  __syncthreads();
  for (int g = blockIdx.x; g < ROWS_Q / 32; g += gridDim.x) {
    const int r0 = g * 32;
    {  // stage attn tile -> bf16 swizzled
      const float* ar = attn + (size_t)(r0 + lrow) * 128 + lsub * 16;
      float v[16];
      *(float4*)&v[0] = *(const float4*)(ar + 0);
      *(float4*)&v[4] = *(const float4*)(ar + 4);
      *(float4*)&v[8] = *(const float4*)(ar + 8);
      *(float4*)&v[12] = *(const float4*)(ar + 12);
      unsigned int us[8];
#pragma unroll
      for (int j = 0; j < 8; ++j)
        us[j] = bf16r(v[2 * j]) | (bf16r(v[2 * j + 1]) << 16);
      int s0 = (lsub * 2) ^ (lrow & 15), s1 = (lsub * 2 + 1) ^ (lrow & 15);
      xb4[lrow * 16 + s0] = make_uint4(us[0], us[1], us[2], us[3]);
      xb4[lrow * 16 + s1] = make_uint4(us[4], us[5], us[6], us[7]);
    }
    __syncthreads();
    float acc[4][4];
#pragma unroll
    for (int rr = 0; rr < 4; ++rr)
#pragma unroll
      for (int cc = 0; cc < 4; ++cc) acc[rr][cc] = wbias[cc];
    gemm_tile(xb4, wo4, cx, ry, acc);
#pragma unroll
    for (int rr = 0; rr < 4; ++rr)
#pragma unroll
      for (int cc = 0; cc < 4; ++cc) {
        size_t o = (size_t)(r0 + ry * 4 + rr) * 128 + cx + 32 * cc;
        yout[o] = acc[rr][cc] + y1[o];
      }
    __syncthreads();
  }
}

// =============================== launch ===============================
extern "C" void kernel_launch(void* const* d_in, const int* in_sizes, int n_in,
                              void* d_out, int out_size, void* d_ws, size_t ws_size,
                              hipStream_t stream) {
  (void)in_sizes; (void)n_in; (void)out_size; (void)ws_size;
  const float* x = (const float*)d_in[0];
  const float* y = (const float*)d_in[1];
  const float* proj = (const float*)d_in[2];
  const float* ln1w = (const float*)d_in[3];
  const float* ln1b = (const float*)d_in[4];
  const float* ln2w = (const float*)d_in[5];
  const float* ln2b = (const float*)d_in[6];
  const float* ln4w = (const float*)d_in[7];
  const float* ln4b = (const float*)d_in[8];
  const float* fcw = (const float*)d_in[9];
  const float* fcb = (const float*)d_in[10];
  const float* prw = (const float*)d_in[11];
  const float* prb = (const float*)d_in[12];
  const float* wq = (const float*)d_in[13];
  const float* wk = (const float*)d_in[14];
  const float* wv = (const float*)d_in[15];
  const float* wo = (const float*)d_in[16];
  const float* wob = (const float*)d_in[17];

  float* out = (float*)d_out;
  float* q_un = out + 12582912;
  float* k_un = out + 62914560;

  float* ws = (float*)d_ws;
  float* y1 = ws;                          // 12,582,912
  float* kbuf = ws + 12582912;             // 6,553,600 (dead after k4)
  float* vbuf = ws + 19136512;             // 6,553,600 (dead after k5a)
  float* part_c = ws + 12582912;           // 1,572,864 (reuses kbuf region)
  float* part_k = ws + 14155776;           // 98,304
  float* attn = ws + 12582912;             // 12,582,912 (after k5a2)
  float* mxq = ws + 25690112;              // 786,432
  float* tmax = ws + 26476544;             // 409,600
  float* mxk = ws + 26886144;              // 256
  float* ksum = ws + 26886400;             // 16,384
  float* ctx2 = ws + 26902784;             // 262,144
  unsigned short* fcT = (unsigned short*)(ws + 27164928);   // 16384 us each
  unsigned short* prT = fcT + 16384;
  unsigned short* wqT = prT + 16384;
  unsigned short* woT = wqT + 16384;       // ends at ws + 27,197,696 floats

  k0_prep<<<dim3(4), dim3(256), 0, stream>>>(fcw, prw, wq, wo, fcT, prT, wqT, woT);
  k1_mlp<<<dim3(512), dim3(256), 0, stream>>>(y, ln4w, ln4b, fcT, fcb, prT, prb, y1);
  k2_kv<<<dim3(400), dim3(512), 0, stream>>>(x, ln2w, ln2b, wk, wv, kbuf, vbuf);
  k3_q<<<dim3(512), dim3(256), 0, stream>>>(y1, ln1w, ln1b, wqT, proj, q_un, mxq);
  k4_kun<<<dim3(400), dim3(512), 0, stream>>>(kbuf, proj, k_un, tmax);
  k4b_mxk<<<dim3(128), dim3(256), 0, stream>>>(tmax, mxk);
  k5a_ctx<<<dim3(256, 6), dim3(256), 0, stream>>>(k_un, vbuf, mxk, part_c, part_k);
  k5a2_red<<<dim3(256), dim3(256), 0, stream>>>(part_c, part_k, ctx2, ksum);
  k5b_out<<<dim3(12, 256), dim3(256), 0, stream>>>(q_un, mxq, ctx2, ksum, attn);
  k6_wo<<<dim3(512), dim3(256), 0, stream>>>(attn, woT, wob, y1, out);
}

// Round 8
// 655.086 us; speedup vs baseline: 4.0193x; 1.2407x over previous
//
#include <hip/hip_runtime.h>
#include <math.h>

// ---------------- problem constants ----------------
constexpr int cH = 8;
constexpr int cDP = 128;
constexpr int cM = 64;
constexpr int cB = 16;
constexpr int cNCTX = 3200;
constexpr int cNQ = 3072;
constexpr int cSHIFT = 128;
constexpr int ROWS_Q = 2 * cB * cNQ;    // 98304
constexpr int ROWS_KV = cB * cNCTX;     // 51200
constexpr float cRATIO = 0.125f;
constexpr float cEPST = 0.125e-4f;
constexpr float cLNEPS = 1e-5f;

typedef float f32x4 __attribute__((ext_vector_type(4)));
typedef short short8 __attribute__((ext_vector_type(8)));

#define MFMA16x16(a, b, c) __builtin_amdgcn_mfma_f32_16x16x32_bf16((a), (b), (c), 0, 0, 0)

__device__ __forceinline__ float wmax64(float v) {
#pragma unroll
  for (int o = 32; o; o >>= 1) v = fmaxf(v, __shfl_xor(v, o));
  return v;
}
__device__ __forceinline__ float wsum64(float v) {
#pragma unroll
  for (int o = 32; o; o >>= 1) v += __shfl_xor(v, o);
  return v;
}
__device__ __forceinline__ float gelu_f(float x) {
  return 0.5f * x * (1.0f + tanhf(0.79788456080286536f * (x + 0.044715f * x * x * x)));
}
// fp32 -> bf16 (RTNE), low 16 bits
__device__ __forceinline__ unsigned int bf16r(float f) {
  unsigned int x = __float_as_uint(f);
  return (x + 0x7fffu + ((x >> 16) & 1u)) >> 16;
}
// 8 packed bf16 (uint4) -> 8 floats
__device__ __forceinline__ void cvt8(uint4 u, float f[8]) {
  f[0] = __uint_as_float(u.x << 16);
  f[1] = __uint_as_float(u.x & 0xffff0000u);
  f[2] = __uint_as_float(u.y << 16);
  f[3] = __uint_as_float(u.y & 0xffff0000u);
  f[4] = __uint_as_float(u.z << 16);
  f[5] = __uint_as_float(u.z & 0xffff0000u);
  f[6] = __uint_as_float(u.w << 16);
  f[7] = __uint_as_float(u.w & 0xffff0000u);
}
// swizzled ushort index for element (row, k) in a [*][128] 16-bit tile
__device__ __forceinline__ int swz(int row, int k) {
  return row * 128 + ((((k >> 3) ^ (row & 15)) << 3) | (k & 7));
}

// 4x4 register-tiled VALU GEMM micro-kernel (k3_q only now)
__device__ __forceinline__ void gemm_tile(const uint4* __restrict__ a4,
                                          const uint4* __restrict__ w4,
                                          int cx, int ry, float acc[4][4]) {
#pragma unroll 2
  for (int kg = 0; kg < 16; ++kg) {
    uint4 xv[4], wv[4];
#pragma unroll
    for (int rr = 0; rr < 4; ++rr) {
      int r = ry * 4 + rr;
      xv[rr] = a4[r * 16 + (kg ^ (r & 15))];
    }
#pragma unroll
    for (int cc = 0; cc < 4; ++cc) {
      int c = cx + 32 * cc;
      wv[cc] = w4[c * 16 + (kg ^ (c & 15))];
    }
    float xf[4][8];
#pragma unroll
    for (int rr = 0; rr < 4; ++rr) cvt8(xv[rr], xf[rr]);
#pragma unroll
    for (int cc = 0; cc < 4; ++cc) {
      float wf[8];
      cvt8(wv[cc], wf);
#pragma unroll
      for (int rr = 0; rr < 4; ++rr)
#pragma unroll
        for (int i = 0; i < 8; ++i)
          acc[rr][cc] = fmaf(xf[rr][i], wf[i], acc[rr][cc]);
    }
  }
}

// ============ K0: weight prep -> bf16, [n][k] layout, pre-swizzled ============
__global__ __launch_bounds__(256) void k0_prep(
    const float* __restrict__ fcw, const float* __restrict__ prw,
    const float* __restrict__ wq, const float* __restrict__ wo,
    unsigned short* __restrict__ fcT, unsigned short* __restrict__ prT,
    unsigned short* __restrict__ wqT, unsigned short* __restrict__ woT) {
  const int mat = blockIdx.x;
  const float* src = mat == 0 ? fcw : mat == 1 ? prw : mat == 2 ? wq : wo;
  unsigned short* dst = mat == 0 ? fcT : mat == 1 ? prT : mat == 2 ? wqT : woT;
  const bool tr = (mat < 2);   // fc_w/pr_w are [k][n]; wq/wo are [n][k]
  for (int i = threadIdx.x; i < 16384; i += 256) {
    int n = i >> 7, k = i & 127;
    float f = tr ? src[k * 128 + n] : src[i];
    dst[swz(n, k)] = (unsigned short)bf16r(f);
  }
}

// ============ K1: MLP (LN4 -> fc -> gelu -> pr -> +y), MFMA version ============
__global__ __launch_bounds__(256, 2) void k1_mlp(
    const float* __restrict__ y,
    const float* __restrict__ ln4w, const float* __restrict__ ln4b,
    const unsigned short* __restrict__ fcT, const float* __restrict__ fcb,
    const unsigned short* __restrict__ prT, const float* __restrict__ prb,
    float* __restrict__ y1) {
  __shared__ unsigned short wfc[16384];
  __shared__ unsigned short wpr[16384];
  __shared__ unsigned short xb[4096];
  __shared__ unsigned short hb[4096];
  const int tid = threadIdx.x;
  {
    const uint4* s1 = (const uint4*)fcT; uint4* d1 = (uint4*)wfc;
    const uint4* s2 = (const uint4*)prT; uint4* d2 = (uint4*)wpr;
    for (int i = tid; i < 2048; i += 256) { d1[i] = s1[i]; d2[i] = s2[i]; }
  }
  const int lane = tid & 63, wv = tid >> 6;
  const int lrow = tid >> 3, lsub = tid & 7;
  const int colbase = wv * 32;
  float fb[2], pb[2];
#pragma unroll
  for (int ct = 0; ct < 2; ++ct) {
    int col = colbase + ct * 16 + (lane & 15);
    fb[ct] = fcb[col];
    pb[ct] = prb[col];
  }
  float lw[16], lb[16];
  *(float4*)&lw[0] = *(const float4*)(ln4w + lsub * 16 + 0);
  *(float4*)&lw[4] = *(const float4*)(ln4w + lsub * 16 + 4);
  *(float4*)&lw[8] = *(const float4*)(ln4w + lsub * 16 + 8);
  *(float4*)&lw[12] = *(const float4*)(ln4w + lsub * 16 + 12);
  *(float4*)&lb[0] = *(const float4*)(ln4b + lsub * 16 + 0);
  *(float4*)&lb[4] = *(const float4*)(ln4b + lsub * 16 + 4);
  *(float4*)&lb[8] = *(const float4*)(ln4b + lsub * 16 + 8);
  *(float4*)&lb[12] = *(const float4*)(ln4b + lsub * 16 + 12);
  uint4* xb4 = (uint4*)xb;
  __syncthreads();

  for (int g = blockIdx.x; g < ROWS_Q / 32; g += gridDim.x) {
    const int r0 = g * 32;
    {  // LN4 -> xb (bf16 swizzled)
      const float* yr = y + (size_t)(r0 + lrow) * 128 + lsub * 16;
      float v[16];
      *(float4*)&v[0] = *(const float4*)(yr + 0);
      *(float4*)&v[4] = *(const float4*)(yr + 4);
      *(float4*)&v[8] = *(const float4*)(yr + 8);
      *(float4*)&v[12] = *(const float4*)(yr + 12);
      float s = 0.f, q = 0.f;
#pragma unroll
      for (int j = 0; j < 16; ++j) { s += v[j]; q += v[j] * v[j]; }
#pragma unroll
      for (int o = 1; o <= 4; o <<= 1) { s += __shfl_xor(s, o); q += __shfl_xor(q, o); }
      float mu = s * (1.0f / 128.0f);
      float rs = rsqrtf(q * (1.0f / 128.0f) - mu * mu + cLNEPS);
      unsigned int us[8];
#pragma unroll
      for (int j = 0; j < 8; ++j) {
        float f0 = (v[2 * j] - mu) * rs * lw[2 * j] + lb[2 * j];
        float f1 = (v[2 * j + 1] - mu) * rs * lw[2 * j + 1] + lb[2 * j + 1];
        us[j] = bf16r(f0) | (bf16r(f1) << 16);
      }
      int s0 = (lsub * 2) ^ (lrow & 15), s1 = (lsub * 2 + 1) ^ (lrow & 15);
      xb4[lrow * 16 + s0] = make_uint4(us[0], us[1], us[2], us[3]);
      xb4[lrow * 16 + s1] = make_uint4(us[4], us[5], us[6], us[7]);
    }
    __syncthreads();
    {  // GEMM1 (MFMA) + gelu -> hb
      f32x4 acc[2][2] = {{{0.f,0.f,0.f,0.f},{0.f,0.f,0.f,0.f}},
                         {{0.f,0.f,0.f,0.f},{0.f,0.f,0.f,0.f}}};
#pragma unroll
      for (int kc = 0; kc < 4; ++kc) {
        short8 af[2], bfv[2];
#pragma unroll
        for (int rt = 0; rt < 2; ++rt) {
          int row = rt * 16 + (lane & 15);
          int slot = ((lane >> 4) + kc * 4) ^ (row & 15);
          af[rt] = *(const short8*)&xb[row * 128 + slot * 8];
        }
#pragma unroll
        for (int ct = 0; ct < 2; ++ct) {
          int col = colbase + ct * 16 + (lane & 15);
          int slot = ((lane >> 4) + kc * 4) ^ (col & 15);
          bfv[ct] = *(const short8*)&wfc[col * 128 + slot * 8];
        }
#pragma unroll
        for (int rt = 0; rt < 2; ++rt)
#pragma unroll
          for (int ct = 0; ct < 2; ++ct)
            acc[rt][ct] = MFMA16x16(af[rt], bfv[ct], acc[rt][ct]);
      }
#pragma unroll
      for (int rt = 0; rt < 2; ++rt)
#pragma unroll
        for (int ct = 0; ct < 2; ++ct) {
          int col = colbase + ct * 16 + (lane & 15);
#pragma unroll
          for (int reg = 0; reg < 4; ++reg) {
            int row = rt * 16 + (lane >> 4) * 4 + reg;
            hb[swz(row, col)] = (unsigned short)bf16r(gelu_f(acc[rt][ct][reg] + fb[ct]));
          }
        }
    }
    __syncthreads();
    {  // GEMM2 (MFMA) + bias + residual -> y1
      f32x4 a2[2][2] = {{{0.f,0.f,0.f,0.f},{0.f,0.f,0.f,0.f}},
                        {{0.f,0.f,0.f,0.f},{0.f,0.f,0.f,0.f}}};
#pragma unroll
      for (int kc = 0; kc < 4; ++kc) {
        short8 af[2], bfv[2];
#pragma unroll
        for (int rt = 0; rt < 2; ++rt) {
          int row = rt * 16 + (lane & 15);
          int slot = ((lane >> 4) + kc * 4) ^ (row & 15);
          af[rt] = *(const short8*)&hb[row * 128 + slot * 8];
        }
#pragma unroll
        for (int ct = 0; ct < 2; ++ct) {
          int col = colbase + ct * 16 + (lane & 15);
          int slot = ((lane >> 4) + kc * 4) ^ (col & 15);
          bfv[ct] = *(const short8*)&wpr[col * 128 + slot * 8];
        }
#pragma unroll
        for (int rt = 0; rt < 2; ++rt)
#pragma unroll
          for (int ct = 0; ct < 2; ++ct)
            a2[rt][ct] = MFMA16x16(af[rt], bfv[ct], a2[rt][ct]);
      }
#pragma unroll
      for (int rt = 0; rt < 2; ++rt)
#pragma unroll
        for (int ct = 0; ct < 2; ++ct) {
          int col = colbase + ct * 16 + (lane & 15);
#pragma unroll
          for (int reg = 0; reg < 4; ++reg) {
            int row = rt * 16 + (lane >> 4) * 4 + reg;
            size_t o = (size_t)(r0 + row) * 128 + col;
            y1[o] = a2[rt][ct][reg] + pb[ct] + y[o];
          }
        }
    }
    __syncthreads();
  }
}

// ============ K2: LN2(x) -> k,v projections (R4 exact) ============
__global__ __launch_bounds__(512) void k2_kv(
    const float* __restrict__ x,
    const float* __restrict__ ln2w, const float* __restrict__ ln2b,
    const float* __restrict__ wkw, const float* __restrict__ wvw,
    float* __restrict__ kbuf, float* __restrict__ vbuf) {
  __shared__ float wkT[32 * cDP];
  __shared__ float wvT[32 * cDP];
  __shared__ float xbs[16][32];
  const int tid = threadIdx.x;
  for (int i = tid; i < 32 * cDP; i += 512) {
    int j = i >> 5, d = i & 31;
    wkT[d * cDP + j] = wkw[i];
    wvT[d * cDP + j] = wvw[i];
  }
  const int dl = tid & 31, rl = tid >> 5;
  const int col = tid & 127, rh = tid >> 7;
  const float l2w = ln2w[dl], l2b = ln2b[dl];
  __syncthreads();
  for (int g = blockIdx.x; g < ROWS_KV / 16; g += gridDim.x) {
    const int r0 = g * 16;
    __syncthreads();
    {
      float v = x[(size_t)(r0 + rl) * 32 + dl];
      float s = v, q = v * v;
#pragma unroll
      for (int o = 16; o; o >>= 1) { s += __shfl_xor(s, o); q += __shfl_xor(q, o); }
      float mu = s * (1.0f / 32.0f);
      float var = q * (1.0f / 32.0f) - mu * mu;
      xbs[rl][dl] = (v - mu) * rsqrtf(var + cLNEPS) * l2w + l2b;
    }
    __syncthreads();
    float ak0 = 0, ak1 = 0, ak2 = 0, ak3 = 0, av0 = 0, av1 = 0, av2 = 0, av3 = 0;
    for (int d = 0; d < 32; d += 4) {
      float4 v0 = *(const float4*)&xbs[rh * 4 + 0][d];
      float4 v1 = *(const float4*)&xbs[rh * 4 + 1][d];
      float4 v2 = *(const float4*)&xbs[rh * 4 + 2][d];
      float4 v3 = *(const float4*)&xbs[rh * 4 + 3][d];
      float k0 = wkT[(d + 0) * cDP + col], k1 = wkT[(d + 1) * cDP + col];
      float k2 = wkT[(d + 2) * cDP + col], k3 = wkT[(d + 3) * cDP + col];
      float u0 = wvT[(d + 0) * cDP + col], u1 = wvT[(d + 1) * cDP + col];
      float u2 = wvT[(d + 2) * cDP + col], u3 = wvT[(d + 3) * cDP + col];
      ak0 += v0.x * k0 + v0.y * k1 + v0.z * k2 + v0.w * k3;
      ak1 += v1.x * k0 + v1.y * k1 + v1.z * k2 + v1.w * k3;
      ak2 += v2.x * k0 + v2.y * k1 + v2.z * k2 + v2.w * k3;
      ak3 += v3.x * k0 + v3.y * k1 + v3.z * k2 + v3.w * k3;
      av0 += v0.x * u0 + v0.y * u1 + v0.z * u2 + v0.w * u3;
      av1 += v1.x * u0 + v1.y * u1 + v1.z * u2 + v1.w * u3;
      av2 += v2.x * u0 + v2.y * u1 + v2.z * u2 + v2.w * u3;
      av3 += v3.x * u0 + v3.y * u1 + v3.z * u2 + v3.w * u3;
    }
    kbuf[(size_t)(r0 + rh * 4 + 0) * cDP + col] = ak0;
    kbuf[(size_t)(r0 + rh * 4 + 1) * cDP + col] = ak1;
    kbuf[(size_t)(r0 + rh * 4 + 2) * cDP + col] = ak2;
    kbuf[(size_t)(r0 + rh * 4 + 3) * cDP + col] = ak3;
    vbuf[(size_t)(r0 + rh * 4 + 0) * cDP + col] = av0;
    vbuf[(size_t)(r0 + rh * 4 + 1) * cDP + col] = av1;
    vbuf[(size_t)(r0 + rh * 4 + 2) * cDP + col] = av2;
    vbuf[(size_t)(r0 + rh * 4 + 3) * cDP + col] = av3;
  }
}

// ============ K3: LN1 -> q GEMM -> FAVOR features (R4 exact) ============
__global__ __launch_bounds__(256, 2) void k3_q(
    const float* __restrict__ y1,
    const float* __restrict__ ln1w, const float* __restrict__ ln1b,
    const unsigned short* __restrict__ wqT, const float* __restrict__ proj,
    float* __restrict__ q_un, float* __restrict__ mxq) {
  __shared__ unsigned short wqs[128 * 128];
  __shared__ unsigned short xb[32 * 128];
  __shared__ float qb[32][132];
  const int tid = threadIdx.x;
  {
    const uint4* s1 = (const uint4*)wqT; uint4* d1 = (uint4*)wqs;
    for (int i = tid; i < 2048; i += 256) d1[i] = s1[i];
  }
  const int lrow = tid >> 3, lsub = tid & 7;
  const int cx = tid & 31, ry = tid >> 5;
  const int lane = tid & 63, wvid = tid >> 6;
  const int m = lane;
  float pr[16];
#pragma unroll
  for (int d = 0; d < 16; ++d) pr[d] = proj[m * 16 + d];
  uint4* xb4 = (uint4*)xb;
  const uint4* wq4 = (const uint4*)wqs;
  __syncthreads();

  for (int g = blockIdx.x; g < ROWS_Q / 32; g += gridDim.x) {
    const int r0 = g * 32;
    {  // LN1
      const float* yr = y1 + (size_t)(r0 + lrow) * 128 + lsub * 16;
      float v[16];
      *(float4*)&v[0] = *(const float4*)(yr + 0);
      *(float4*)&v[4] = *(const float4*)(yr + 4);
      *(float4*)&v[8] = *(const float4*)(yr + 8);
      *(float4*)&v[12] = *(const float4*)(yr + 12);
      float s = 0.f, q = 0.f;
#pragma unroll
      for (int j = 0; j < 16; ++j) { s += v[j]; q += v[j] * v[j]; }
#pragma unroll
      for (int o = 1; o <= 4; o <<= 1) { s += __shfl_xor(s, o); q += __shfl_xor(q, o); }
      float mu = s * (1.0f / 128.0f);
      float rs = rsqrtf(q * (1.0f / 128.0f) - mu * mu + cLNEPS);
      float lw[16], lb[16];
      *(float4*)&lw[0] = *(const float4*)(ln1w + lsub * 16 + 0);
      *(float4*)&lw[4] = *(const float4*)(ln1w + lsub * 16 + 4);
      *(float4*)&lw[8] = *(const float4*)(ln1w + lsub * 16 + 8);
      *(float4*)&lw[12] = *(const float4*)(ln1w + lsub * 16 + 12);
      *(float4*)&lb[0] = *(const float4*)(ln1b + lsub * 16 + 0);
      *(float4*)&lb[4] = *(const float4*)(ln1b + lsub * 16 + 4);
      *(float4*)&lb[8] = *(const float4*)(ln1b + lsub * 16 + 8);
      *(float4*)&lb[12] = *(const float4*)(ln1b + lsub * 16 + 12);
      unsigned int us[8];
#pragma unroll
      for (int j = 0; j < 8; ++j) {
        float f0 = (v[2 * j] - mu) * rs * lw[2 * j] + lb[2 * j];
        float f1 = (v[2 * j + 1] - mu) * rs * lw[2 * j + 1] + lb[2 * j + 1];
        us[j] = bf16r(f0) | (bf16r(f1) << 16);
      }
      int s0 = (lsub * 2) ^ (lrow & 15), s1 = (lsub * 2 + 1) ^ (lrow & 15);
      xb4[lrow * 16 + s0] = make_uint4(us[0], us[1], us[2], us[3]);
      xb4[lrow * 16 + s1] = make_uint4(us[4], us[5], us[6], us[7]);
    }
    __syncthreads();
    float acc[4][4] = {};
    gemm_tile(xb4, wq4, cx, ry, acc);
#pragma unroll
    for (int rr = 0; rr < 4; ++rr)
#pragma unroll
      for (int cc = 0; cc < 4; ++cc) qb[ry * 4 + rr][cx + 32 * cc] = acc[rr][cc];
    __syncthreads();
    const int bb = r0 / cNQ;
    const int n0 = r0 - bb * cNQ;
    for (int r = 0; r < 32; ++r) {
#pragma unroll
      for (int hh = 0; hh < 2; ++hh) {
        int h = wvid * 2 + hh;
        float4 q0 = *(const float4*)&qb[r][h * 16 + 0];
        float4 q1 = *(const float4*)&qb[r][h * 16 + 4];
        float4 q2 = *(const float4*)&qb[r][h * 16 + 8];
        float4 q3 = *(const float4*)&qb[r][h * 16 + 12];
        float dash = q0.x * pr[0] + q0.y * pr[1] + q0.z * pr[2] + q0.w * pr[3]
                   + q1.x * pr[4] + q1.y * pr[5] + q1.z * pr[6] + q1.w * pr[7]
                   + q2.x * pr[8] + q2.y * pr[9] + q2.z * pr[10] + q2.w * pr[11]
                   + q3.x * pr[12] + q3.y * pr[13] + q3.z * pr[14] + q3.w * pr[15];
        dash *= 0.5f;
        float ss = q0.x * q0.x + q0.y * q0.y + q0.z * q0.z + q0.w * q0.w
                 + q1.x * q1.x + q1.y * q1.y + q1.z * q1.z + q1.w * q1.w
                 + q2.x * q2.x + q2.y * q2.y + q2.z * q2.z + q2.w * q2.w
                 + q3.x * q3.x + q3.y * q3.y + q3.z * q3.z + q3.w * q3.w;
        float un = cRATIO * expf(dash - 0.125f * ss);
        size_t base = (size_t)(bb * cH + h) * cNQ + n0 + r;
        q_un[base * cM + m] = un;
        float mx = wmax64(dash);
        if (lane == 0) mxq[base] = mx;
      }
    }
    __syncthreads();
  }
}

// ============ K4: k features + temporal-split windowed writes (R4 exact) ============
__global__ __launch_bounds__(512) void k4_kun(
    const float* __restrict__ kbuf, const float* __restrict__ proj,
    float* __restrict__ k_un, float* __restrict__ tmax) {
  __shared__ float kb[16][cDP];
  const int tid = threadIdx.x;
  const int m = tid & 63, h = tid >> 6, lane = tid & 63;
  float pr[16];
#pragma unroll
  for (int d = 0; d < 16; ++d) pr[d] = proj[m * 16 + d];
  for (int g = blockIdx.x; g < ROWS_KV / 16; g += gridDim.x) {
    const int r0 = g * 16;
    __syncthreads();
    for (int i = tid; i < 16 * cDP; i += 512)
      kb[i >> 7][i & 127] = kbuf[(size_t)(r0 + (i >> 7)) * cDP + (i & 127)];
    __syncthreads();
    for (int r = 0; r < 16; ++r) {
      int row = r0 + r;
      int b = row / cNCTX;
      int t = row - b * cNCTX;
      float4 q0 = *(const float4*)&kb[r][h * 16 + 0];
      float4 q1 = *(const float4*)&kb[r][h * 16 + 4];
      float4 q2 = *(const float4*)&kb[r][h * 16 + 8];
      float4 q3 = *(const float4*)&kb[r][h * 16 + 12];
      float dash = q0.x * pr[0] + q0.y * pr[1] + q0.z * pr[2] + q0.w * pr[3]
                 + q1.x * pr[4] + q1.y * pr[5] + q1.z * pr[6] + q1.w * pr[7]
                 + q2.x * pr[8] + q2.y * pr[9] + q2.z * pr[10] + q2.w * pr[11]
                 + q3.x * pr[12] + q3.y * pr[13] + q3.z * pr[14] + q3.w * pr[15];
      dash *= 0.5f;
      float ss = q0.x * q0.x + q0.y * q0.y + q0.z * q0.z + q0.w * q0.w
               + q1.x * q1.x + q1.y * q1.y + q1.z * q1.z + q1.w * q1.w
               + q2.x * q2.x + q2.y * q2.y + q2.z * q2.z + q2.w * q2.w
               + q3.x * q3.x + q3.y * q3.y + q3.z * q3.z + q3.w * q3.w;
      float un = cRATIO * expf(dash - 0.125f * ss);
      if (t < cNQ)
        k_un[((size_t)(b * cH + h) * cNQ + t) * cM + m] = un;
      if (t >= cSHIFT)
        k_un[((size_t)((b + cB) * cH + h) * cNQ + (t - cSHIFT)) * cM + m] = un;
      float mx = wmax64(dash);
      if (lane == 0) tmax[(b * cH + h) * cNCTX + t] = mx;
    }
  }
}

// ============ K4b: windowed max (R4 exact) ============
__global__ __launch_bounds__(256) void k4b_mxk(
    const float* __restrict__ tmax, float* __restrict__ mxk) {
  const int bh = blockIdx.x;
  const int tid = threadIdx.x;
  float m0 = -1e30f, m1 = -1e30f;
  for (int t = tid; t < cNCTX; t += 256) {
    float v = tmax[bh * cNCTX + t];
    if (t < cNQ) m0 = fmaxf(m0, v);
    if (t >= cSHIFT) m1 = fmaxf(m1, v);
  }
  __shared__ float s0[256], s1[256];
  s0[tid] = m0; s1[tid] = m1;
  __syncthreads();
  for (int s = 128; s; s >>= 1) {
    if (tid < s) { s0[tid] = fmaxf(s0[tid], s0[tid + s]); s1[tid] = fmaxf(s1[tid], s1[tid + s]); }
    __syncthreads();
  }
  if (tid == 0) { mxk[bh] = s0[0]; mxk[bh + 128] = s1[0]; }
}

// ============ K5a: partial ctx/ksum over 512-token chunks (R4 exact) ============
__global__ __launch_bounds__(256) void k5a_ctx(
    const float* __restrict__ k_un, const float* __restrict__ vbuf,
    const float* __restrict__ mxk,
    float* __restrict__ part_c, float* __restrict__ part_k) {
  const int bbh = blockIdx.x;   // 0..255
  const int ch = blockIdx.y;    // 0..5
  const int bb = bbh >> 3, h = bbh & 7;
  const int b = bb & 15, toff = (bb >> 4) * cSHIFT;
  const float ek = expf(-mxk[bbh]);
  const int tid = threadIdx.x, m = tid & 63, eq = tid >> 6;
  __shared__ float ub[64][64];
  __shared__ float vb[64][16];
  float c0 = 0, c1 = 0, c2 = 0, c3 = 0, ks = 0;
  const int nb = ch * 512;
  for (int n0 = nb; n0 < nb + 512; n0 += 64) {
    for (int i = tid; i < 64 * 64; i += 256)
      ub[i >> 6][i & 63] = k_un[((size_t)bbh * cNQ + n0 + (i >> 6)) * cM + (i & 63)];
    for (int i = tid; i < 64 * 16; i += 256)
      vb[i >> 4][i & 15] = vbuf[((size_t)(b * cNCTX) + toff + n0 + (i >> 4)) * cDP + h * 16 + (i & 15)];
    __syncthreads();
#pragma unroll 4
    for (int nn = 0; nn < 64; ++nn) {
      float kf = ub[nn][m] * ek + cEPST;
      ks += kf;
      float4 vv = *(const float4*)&vb[nn][eq * 4];
      c0 += kf * vv.x; c1 += kf * vv.y; c2 += kf * vv.z; c3 += kf * vv.w;
    }
    __syncthreads();
  }
  size_t po = (size_t)ch * 256 + bbh;
  part_c[po * 1024 + m * 16 + eq * 4 + 0] = c0;
  part_c[po * 1024 + m * 16 + eq * 4 + 1] = c1;
  part_c[po * 1024 + m * 16 + eq * 4 + 2] = c2;
  part_c[po * 1024 + m * 16 + eq * 4 + 3] = c3;
  if (eq == 0) part_k[po * 64 + m] = ks;
}

__global__ __launch_bounds__(256) void k5a2_red(
    const float* __restrict__ part_c, const float* __restrict__ part_k,
    float* __restrict__ ctx2, float* __restrict__ ksum) {
  const int bbh = blockIdx.x;
  const int tid = threadIdx.x;
  for (int i = tid; i < 1024; i += 256) {
    float s = 0;
#pragma unroll
    for (int ch = 0; ch < 6; ++ch) s += part_c[((size_t)ch * 256 + bbh) * 1024 + i];
    ctx2[bbh * 1024 + i] = s;
  }
  if (tid < 64) {
    float s = 0;
#pragma unroll
    for (int ch = 0; ch < 6; ++ch) s += part_k[((size_t)ch * 256 + bbh) * 64 + tid];
    ksum[bbh * cM + tid] = s;
  }
}

// ============ K5b: denom + out = d_inv * qf @ ctx2 (R4 exact) ============
__global__ __launch_bounds__(256) void k5b_out(
    const float* __restrict__ q_un, const float* __restrict__ mxq,
    const float* __restrict__ ctx2, const float* __restrict__ ksum,
    float* __restrict__ attn) {
  const int chunk = blockIdx.x;   // 0..11
  const int bbh = blockIdx.y;     // 0..255
  const int bb = bbh >> 3, h = bbh & 7;
  const int tid = threadIdx.x, lane = tid & 63;
  __shared__ float c2[cM * 16];
  __shared__ float ksl[cM];
  __shared__ float qf[16][cM];
  __shared__ float evs[16], dv[16];
  for (int i = tid; i < cM * 16; i += 256) c2[i] = ctx2[(size_t)bbh * 1024 + i];
  if (tid < cM) ksl[tid] = ksum[bbh * cM + tid];
  __syncthreads();
  for (int it = 0; it < 16; ++it) {
    const int t0 = chunk * 256 + it * 16;
    if (tid < 16) evs[tid] = expf(-mxq[(size_t)bbh * cNQ + t0 + tid]);
    __syncthreads();
#pragma unroll
    for (int j = 0; j < 4; ++j) {
      int i = tid + j * 256;
      int tt = i >> 6, mm = i & 63;
      qf[tt][mm] = q_un[((size_t)bbh * cNQ + t0 + tt) * cM + mm] * evs[tt] + cEPST;
    }
    __syncthreads();
#pragma unroll
    for (int p = 0; p < 4; ++p) {
      int tt = (tid >> 6) * 4 + p;
      float v = qf[tt][lane] * ksl[lane];
      v = wsum64(v);
      if (lane == 0) dv[tt] = 1.0f / v;
    }
    __syncthreads();
    {
      int tt = tid >> 4, e = tid & 15;
      float a = 0.f;
#pragma unroll 8
      for (int mm = 0; mm < cM; ++mm) a += qf[tt][mm] * c2[mm * 16 + e];
      attn[((size_t)(bb * cNQ) + t0 + tt) * cDP + h * 16 + e] = a * dv[tt];
    }
    __syncthreads();
  }
}

// ============ K6: yout = y1 + attn @ wo.T + wo_b, MFMA version ============
__global__ __launch_bounds__(256, 2) void k6_wo(
    const float* __restrict__ attn,
    const unsigned short* __restrict__ woT, const float* __restrict__ wob,
    const float* __restrict__ y1, float* __restrict__ yout) {
  __shared__ unsigned short wos[16384];
  __shared__ unsigned short xb[4096];
  const int tid = threadIdx.x;
  {
    const uint4* s1 = (const uint4*)woT; uint4* d1 = (uint4*)wos;
    for (int i = tid; i < 2048; i += 256) d1[i] = s1[i];
  }
  const int lane = tid & 63, wv = tid >> 6;
  const int lrow = tid >> 3, lsub = tid & 7;
  const int colbase = wv * 32;
  float wb[2];
#pragma unroll
  for (int ct = 0; ct < 2; ++ct) wb[ct] = wob[colbase + ct * 16 + (lane & 15)];
  uint4* xb4 = (uint4*)xb;
  __syncthreads();
  for (int g = blockIdx.x; g < ROWS_Q / 32; g += gridDim.x) {
    const int r0 = g * 32;
    {  // stage attn tile -> bf16 swizzled
      const float* ar = attn + (size_t)(r0 + lrow) * 128 + lsub * 16;
      float v[16];
      *(float4*)&v[0] = *(const float4*)(ar + 0);
      *(float4*)&v[4] = *(const float4*)(ar + 4);
      *(float4*)&v[8] = *(const float4*)(ar + 8);
      *(float4*)&v[12] = *(const float4*)(ar + 12);
      unsigned int us[8];
#pragma unroll
      for (int j = 0; j < 8; ++j)
        us[j] = bf16r(v[2 * j]) | (bf16r(v[2 * j + 1]) << 16);
      int s0 = (lsub * 2) ^ (lrow & 15), s1 = (lsub * 2 + 1) ^ (lrow & 15);
      xb4[lrow * 16 + s0] = make_uint4(us[0], us[1], us[2], us[3]);
      xb4[lrow * 16 + s1] = make_uint4(us[4], us[5], us[6], us[7]);
    }
    __syncthreads();
    {
      f32x4 acc[2][2] = {{{0.f,0.f,0.f,0.f},{0.f,0.f,0.f,0.f}},
                         {{0.f,0.f,0.f,0.f},{0.f,0.f,0.f,0.f}}};
#pragma unroll
      for (int kc = 0; kc < 4; ++kc) {
        short8 af[2], bfv[2];
#pragma unroll
        for (int rt = 0; rt < 2; ++rt) {
          int row = rt * 16 + (lane & 15);
          int slot = ((lane >> 4) + kc * 4) ^ (row & 15);
          af[rt] = *(const short8*)&xb[row * 128 + slot * 8];
        }
#pragma unroll
        for (int ct = 0; ct < 2; ++ct) {
          int col = colbase + ct * 16 + (lane & 15);
          int slot = ((lane >> 4) + kc * 4) ^ (col & 15);
          bfv[ct] = *(const short8*)&wos[col * 128 + slot * 8];
        }
#pragma unroll
        for (int rt = 0; rt < 2; ++rt)
#pragma unroll
          for (int ct = 0; ct < 2; ++ct)
            acc[rt][ct] = MFMA16x16(af[rt], bfv[ct], acc[rt][ct]);
      }
#pragma unroll
      for (int rt = 0; rt < 2; ++rt)
#pragma unroll
        for (int ct = 0; ct < 2; ++ct) {
          int col = colbase + ct * 16 + (lane & 15);
#pragma unroll
          for (int reg = 0; reg < 4; ++reg) {
            int row = rt * 16 + (lane >> 4) * 4 + reg;
            size_t o = (size_t)(r0 + row) * 128 + col;
            yout[o] = acc[rt][ct][reg] + wb[ct] + y1[o];
          }
        }
    }
    __syncthreads();
  }
}

// =============================== launch ===============================
extern "C" void kernel_launch(void* const* d_in, const int* in_sizes, int n_in,
                              void* d_out, int out_size, void* d_ws, size_t ws_size,
                              hipStream_t stream) {
  (void)in_sizes; (void)n_in; (void)out_size; (void)ws_size;
  const float* x = (const float*)d_in[0];
  const float* y = (const float*)d_in[1];
  const float* proj = (const float*)d_in[2];
  const float* ln1w = (const float*)d_in[3];
  const float* ln1b = (const float*)d_in[4];
  const float* ln2w = (const float*)d_in[5];
  const float* ln2b = (const float*)d_in[6];
  const float* ln4w = (const float*)d_in[7];
  const float* ln4b = (const float*)d_in[8];
  const float* fcw = (const float*)d_in[9];
  const float* fcb = (const float*)d_in[10];
  const float* prw = (const float*)d_in[11];
  const float* prb = (const float*)d_in[12];
  const float* wq = (const float*)d_in[13];
  const float* wk = (const float*)d_in[14];
  const float* wv = (const float*)d_in[15];
  const float* wo = (const float*)d_in[16];
  const float* wob = (const float*)d_in[17];

  float* out = (float*)d_out;
  float* q_un = out + 12582912;
  float* k_un = out + 62914560;

  float* ws = (float*)d_ws;
  float* y1 = ws;                          // 12,582,912
  float* kbuf = ws + 12582912;             // 6,553,600 (dead after k4)
  float* vbuf = ws + 19136512;             // 6,553,600 (dead after k5a)
  float* part_c = ws + 12582912;           // 1,572,864 (reuses kbuf region)
  float* part_k = ws + 14155776;           // 98,304
  float* attn = ws + 12582912;             // 12,582,912 (after k5a2)
  float* mxq = ws + 25690112;              // 786,432
  float* tmax = ws + 26476544;             // 409,600
  float* mxk = ws + 26886144;              // 256
  float* ksum = ws + 26886400;             // 16,384
  float* ctx2 = ws + 26902784;             // 262,144
  unsigned short* fcT = (unsigned short*)(ws + 27164928);   // 4 x 16384 ushorts
  unsigned short* prT = fcT + 16384;
  unsigned short* wqT = prT + 16384;
  unsigned short* woT = wqT + 16384;

  k0_prep<<<dim3(4), dim3(256), 0, stream>>>(fcw, prw, wq, wo, fcT, prT, wqT, woT);
  k1_mlp<<<dim3(512), dim3(256), 0, stream>>>(y, ln4w, ln4b, fcT, fcb, prT, prb, y1);
  k2_kv<<<dim3(400), dim3(512), 0, stream>>>(x, ln2w, ln2b, wk, wv, kbuf, vbuf);
  k3_q<<<dim3(512), dim3(256), 0, stream>>>(y1, ln1w, ln1b, wqT, proj, q_un, mxq);
  k4_kun<<<dim3(400), dim3(512), 0, stream>>>(kbuf, proj, k_un, tmax);
  k4b_mxk<<<dim3(128), dim3(256), 0, stream>>>(tmax, mxk);
  k5a_ctx<<<dim3(256, 6), dim3(256), 0, stream>>>(k_un, vbuf, mxk, part_c, part_k);
  k5a2_red<<<dim3(256), dim3(256), 0, stream>>>(part_c, part_k, ctx2, ksum);
  k5b_out<<<dim3(12, 256), dim3(256), 0, stream>>>(q_un, mxq, ctx2, ksum, attn);
  k6_wo<<<dim3(512), dim3(256), 0, stream>>>(attn, woT, wob, y1, out);
}

// Round 10
// 588.310 us; speedup vs baseline: 4.4755x; 1.1135x over previous
//
#include <hip/hip_runtime.h>
#include <math.h>

// ---------------- problem constants ----------------
constexpr int cH = 8;
constexpr int cDP = 128;
constexpr int cM = 64;
constexpr int cB = 16;
constexpr int cNCTX = 3200;
constexpr int cNQ = 3072;
constexpr int cSHIFT = 128;
constexpr int ROWS_Q = 2 * cB * cNQ;    // 98304
constexpr int ROWS_KV = cB * cNCTX;     // 51200
constexpr float cRATIO = 0.125f;
constexpr float cEPST = 0.125e-4f;
constexpr float cLNEPS = 1e-5f;

typedef float f32x4 __attribute__((ext_vector_type(4)));
typedef short short8 __attribute__((ext_vector_type(8)));

#define MFMA16x16(a, b, c) __builtin_amdgcn_mfma_f32_16x16x32_bf16((a), (b), (c), 0, 0, 0)

__device__ __forceinline__ float wmax64(float v) {
#pragma unroll
  for (int o = 32; o; o >>= 1) v = fmaxf(v, __shfl_xor(v, o));
  return v;
}
__device__ __forceinline__ float wsum64(float v) {
#pragma unroll
  for (int o = 32; o; o >>= 1) v += __shfl_xor(v, o);
  return v;
}
__device__ __forceinline__ float gelu_f(float x) {
  return 0.5f * x * (1.0f + tanhf(0.79788456080286536f * (x + 0.044715f * x * x * x)));
}
// fp32 -> bf16 (RTNE), low 16 bits
__device__ __forceinline__ unsigned int bf16r(float f) {
  unsigned int x = __float_as_uint(f);
  return (x + 0x7fffu + ((x >> 16) & 1u)) >> 16;
}
// 8 packed bf16 (uint4) -> 8 floats
__device__ __forceinline__ void cvt8(uint4 u, float f[8]) {
  f[0] = __uint_as_float(u.x << 16);
  f[1] = __uint_as_float(u.x & 0xffff0000u);
  f[2] = __uint_as_float(u.y << 16);
  f[3] = __uint_as_float(u.y & 0xffff0000u);
  f[4] = __uint_as_float(u.z << 16);
  f[5] = __uint_as_float(u.z & 0xffff0000u);
  f[6] = __uint_as_float(u.w << 16);
  f[7] = __uint_as_float(u.w & 0xffff0000u);
}
// swizzled ushort index for element (row, k) in a [*][128] 16-bit tile
__device__ __forceinline__ int swz(int row, int k) {
  return row * 128 + ((((k >> 3) ^ (row & 15)) << 3) | (k & 7));
}

// 4x4 register-tiled VALU GEMM micro-kernel (q path: fp32-fma precision required by exp())
__device__ __forceinline__ void gemm_tile(const uint4* __restrict__ a4,
                                          const uint4* __restrict__ w4,
                                          int cx, int ry, float acc[4][4]) {
#pragma unroll 2
  for (int kg = 0; kg < 16; ++kg) {
    uint4 xv[4], wv[4];
#pragma unroll
    for (int rr = 0; rr < 4; ++rr) {
      int r = ry * 4 + rr;
      xv[rr] = a4[r * 16 + (kg ^ (r & 15))];
    }
#pragma unroll
    for (int cc = 0; cc < 4; ++cc) {
      int c = cx + 32 * cc;
      wv[cc] = w4[c * 16 + (kg ^ (c & 15))];
    }
    float xf[4][8];
#pragma unroll
    for (int rr = 0; rr < 4; ++rr) cvt8(xv[rr], xf[rr]);
#pragma unroll
    for (int cc = 0; cc < 4; ++cc) {
      float wf[8];
      cvt8(wv[cc], wf);
#pragma unroll
      for (int rr = 0; rr < 4; ++rr)
#pragma unroll
        for (int i = 0; i < 8; ++i)
          acc[rr][cc] = fmaf(xf[rr][i], wf[i], acc[rr][cc]);
    }
  }
}

// ============ K0: weight prep -> bf16, [n][k] layout, pre-swizzled ============
__global__ __launch_bounds__(256) void k0_prep(
    const float* __restrict__ fcw, const float* __restrict__ prw,
    const float* __restrict__ wq, const float* __restrict__ wo,
    unsigned short* __restrict__ fcT, unsigned short* __restrict__ prT,
    unsigned short* __restrict__ wqT, unsigned short* __restrict__ woT) {
  const int mat = blockIdx.x;
  const float* src = mat == 0 ? fcw : mat == 1 ? prw : mat == 2 ? wq : wo;
  unsigned short* dst = mat == 0 ? fcT : mat == 1 ? prT : mat == 2 ? wqT : woT;
  const bool tr = (mat < 2);   // fc_w/pr_w are [k][n]; wq/wo are [n][k]
  for (int i = threadIdx.x; i < 16384; i += 256) {
    int n = i >> 7, k = i & 127;
    float f = tr ? src[k * 128 + n] : src[i];
    dst[swz(n, k)] = (unsigned short)bf16r(f);
  }
}

// ============ K1: MLP (LN4 -> fc -> gelu -> pr -> +y), MFMA (R8 exact) ============
__global__ __launch_bounds__(256, 2) void k1_mlp(
    const float* __restrict__ y,
    const float* __restrict__ ln4w, const float* __restrict__ ln4b,
    const unsigned short* __restrict__ fcT, const float* __restrict__ fcb,
    const unsigned short* __restrict__ prT, const float* __restrict__ prb,
    float* __restrict__ y1) {
  __shared__ unsigned short wfc[16384];
  __shared__ unsigned short wpr[16384];
  __shared__ unsigned short xb[4096];
  __shared__ unsigned short hb[4096];
  const int tid = threadIdx.x;
  {
    const uint4* s1 = (const uint4*)fcT; uint4* d1 = (uint4*)wfc;
    const uint4* s2 = (const uint4*)prT; uint4* d2 = (uint4*)wpr;
    for (int i = tid; i < 2048; i += 256) { d1[i] = s1[i]; d2[i] = s2[i]; }
  }
  const int lane = tid & 63, wv = tid >> 6;
  const int lrow = tid >> 3, lsub = tid & 7;
  const int colbase = wv * 32;
  float fb[2], pb[2];
#pragma unroll
  for (int ct = 0; ct < 2; ++ct) {
    int col = colbase + ct * 16 + (lane & 15);
    fb[ct] = fcb[col];
    pb[ct] = prb[col];
  }
  float lw[16], lb[16];
  *(float4*)&lw[0] = *(const float4*)(ln4w + lsub * 16 + 0);
  *(float4*)&lw[4] = *(const float4*)(ln4w + lsub * 16 + 4);
  *(float4*)&lw[8] = *(const float4*)(ln4w + lsub * 16 + 8);
  *(float4*)&lw[12] = *(const float4*)(ln4w + lsub * 16 + 12);
  *(float4*)&lb[0] = *(const float4*)(ln4b + lsub * 16 + 0);
  *(float4*)&lb[4] = *(const float4*)(ln4b + lsub * 16 + 4);
  *(float4*)&lb[8] = *(const float4*)(ln4b + lsub * 16 + 8);
  *(float4*)&lb[12] = *(const float4*)(ln4b + lsub * 16 + 12);
  uint4* xb4 = (uint4*)xb;
  __syncthreads();

  for (int g = blockIdx.x; g < ROWS_Q / 32; g += gridDim.x) {
    const int r0 = g * 32;
    {  // LN4 -> xb (bf16 swizzled)
      const float* yr = y + (size_t)(r0 + lrow) * 128 + lsub * 16;
      float v[16];
      *(float4*)&v[0] = *(const float4*)(yr + 0);
      *(float4*)&v[4] = *(const float4*)(yr + 4);
      *(float4*)&v[8] = *(const float4*)(yr + 8);
      *(float4*)&v[12] = *(const float4*)(yr + 12);
      float s = 0.f, q = 0.f;
#pragma unroll
      for (int j = 0; j < 16; ++j) { s += v[j]; q += v[j] * v[j]; }
#pragma unroll
      for (int o = 1; o <= 4; o <<= 1) { s += __shfl_xor(s, o); q += __shfl_xor(q, o); }
      float mu = s * (1.0f / 128.0f);
      float rs = rsqrtf(q * (1.0f / 128.0f) - mu * mu + cLNEPS);
      unsigned int us[8];
#pragma unroll
      for (int j = 0; j < 8; ++j) {
        float f0 = (v[2 * j] - mu) * rs * lw[2 * j] + lb[2 * j];
        float f1 = (v[2 * j + 1] - mu) * rs * lw[2 * j + 1] + lb[2 * j + 1];
        us[j] = bf16r(f0) | (bf16r(f1) << 16);
      }
      int s0 = (lsub * 2) ^ (lrow & 15), s1 = (lsub * 2 + 1) ^ (lrow & 15);
      xb4[lrow * 16 + s0] = make_uint4(us[0], us[1], us[2], us[3]);
      xb4[lrow * 16 + s1] = make_uint4(us[4], us[5], us[6], us[7]);
    }
    __syncthreads();
    {  // GEMM1 (MFMA) + gelu -> hb
      f32x4 acc[2][2] = {{{0.f,0.f,0.f,0.f},{0.f,0.f,0.f,0.f}},
                         {{0.f,0.f,0.f,0.f},{0.f,0.f,0.f,0.f}}};
#pragma unroll
      for (int kc = 0; kc < 4; ++kc) {
        short8 af[2], bfv[2];
#pragma unroll
        for (int rt = 0; rt < 2; ++rt) {
          int row = rt * 16 + (lane & 15);
          int slot = ((lane >> 4) + kc * 4) ^ (row & 15);
          af[rt] = *(const short8*)&xb[row * 128 + slot * 8];
        }
#pragma unroll
        for (int ct = 0; ct < 2; ++ct) {
          int col = colbase + ct * 16 + (lane & 15);
          int slot = ((lane >> 4) + kc * 4) ^ (col & 15);
          bfv[ct] = *(const short8*)&wfc[col * 128 + slot * 8];
        }
#pragma unroll
        for (int rt = 0; rt < 2; ++rt)
#pragma unroll
          for (int ct = 0; ct < 2; ++ct)
            acc[rt][ct] = MFMA16x16(af[rt], bfv[ct], acc[rt][ct]);
      }
#pragma unroll
      for (int rt = 0; rt < 2; ++rt)
#pragma unroll
        for (int ct = 0; ct < 2; ++ct) {
          int col = colbase + ct * 16 + (lane & 15);
#pragma unroll
          for (int reg = 0; reg < 4; ++reg) {
            int row = rt * 16 + (lane >> 4) * 4 + reg;
            hb[swz(row, col)] = (unsigned short)bf16r(gelu_f(acc[rt][ct][reg] + fb[ct]));
          }
        }
    }
    __syncthreads();
    {  // GEMM2 (MFMA) + bias + residual -> y1
      f32x4 a2[2][2] = {{{0.f,0.f,0.f,0.f},{0.f,0.f,0.f,0.f}},
                        {{0.f,0.f,0.f,0.f},{0.f,0.f,0.f,0.f}}};
#pragma unroll
      for (int kc = 0; kc < 4; ++kc) {
        short8 af[2], bfv[2];
#pragma unroll
        for (int rt = 0; rt < 2; ++rt) {
          int row = rt * 16 + (lane & 15);
          int slot = ((lane >> 4) + kc * 4) ^ (row & 15);
          af[rt] = *(const short8*)&hb[row * 128 + slot * 8];
        }
#pragma unroll
        for (int ct = 0; ct < 2; ++ct) {
          int col = colbase + ct * 16 + (lane & 15);
          int slot = ((lane >> 4) + kc * 4) ^ (col & 15);
          bfv[ct] = *(const short8*)&wpr[col * 128 + slot * 8];
        }
#pragma unroll
        for (int rt = 0; rt < 2; ++rt)
#pragma unroll
          for (int ct = 0; ct < 2; ++ct)
            a2[rt][ct] = MFMA16x16(af[rt], bfv[ct], a2[rt][ct]);
      }
#pragma unroll
      for (int rt = 0; rt < 2; ++rt)
#pragma unroll
        for (int ct = 0; ct < 2; ++ct) {
          int col = colbase + ct * 16 + (lane & 15);
#pragma unroll
          for (int reg = 0; reg < 4; ++reg) {
            int row = rt * 16 + (lane >> 4) * 4 + reg;
            size_t o = (size_t)(r0 + row) * 128 + col;
            y1[o] = a2[rt][ct][reg] + pb[ct] + y[o];
          }
        }
    }
    __syncthreads();
  }
}

// ============ K2: LN2(x) -> k,v projections (R4 exact) ============
__global__ __launch_bounds__(512) void k2_kv(
    const float* __restrict__ x,
    const float* __restrict__ ln2w, const float* __restrict__ ln2b,
    const float* __restrict__ wkw, const float* __restrict__ wvw,
    float* __restrict__ kbuf, float* __restrict__ vbuf) {
  __shared__ float wkT[32 * cDP];
  __shared__ float wvT[32 * cDP];
  __shared__ float xbs[16][32];
  const int tid = threadIdx.x;
  for (int i = tid; i < 32 * cDP; i += 512) {
    int j = i >> 5, d = i & 31;
    wkT[d * cDP + j] = wkw[i];
    wvT[d * cDP + j] = wvw[i];
  }
  const int dl = tid & 31, rl = tid >> 5;
  const int col = tid & 127, rh = tid >> 7;
  const float l2w = ln2w[dl], l2b = ln2b[dl];
  __syncthreads();
  for (int g = blockIdx.x; g < ROWS_KV / 16; g += gridDim.x) {
    const int r0 = g * 16;
    __syncthreads();
    {
      float v = x[(size_t)(r0 + rl) * 32 + dl];
      float s = v, q = v * v;
#pragma unroll
      for (int o = 16; o; o >>= 1) { s += __shfl_xor(s, o); q += __shfl_xor(q, o); }
      float mu = s * (1.0f / 32.0f);
      float var = q * (1.0f / 32.0f) - mu * mu;
      xbs[rl][dl] = (v - mu) * rsqrtf(var + cLNEPS) * l2w + l2b;
    }
    __syncthreads();
    float ak0 = 0, ak1 = 0, ak2 = 0, ak3 = 0, av0 = 0, av1 = 0, av2 = 0, av3 = 0;
    for (int d = 0; d < 32; d += 4) {
      float4 v0 = *(const float4*)&xbs[rh * 4 + 0][d];
      float4 v1 = *(const float4*)&xbs[rh * 4 + 1][d];
      float4 v2 = *(const float4*)&xbs[rh * 4 + 2][d];
      float4 v3 = *(const float4*)&xbs[rh * 4 + 3][d];
      float k0 = wkT[(d + 0) * cDP + col], k1 = wkT[(d + 1) * cDP + col];
      float k2 = wkT[(d + 2) * cDP + col], k3 = wkT[(d + 3) * cDP + col];
      float u0 = wvT[(d + 0) * cDP + col], u1 = wvT[(d + 1) * cDP + col];
      float u2 = wvT[(d + 2) * cDP + col], u3 = wvT[(d + 3) * cDP + col];
      ak0 += v0.x * k0 + v0.y * k1 + v0.z * k2 + v0.w * k3;
      ak1 += v1.x * k0 + v1.y * k1 + v1.z * k2 + v1.w * k3;
      ak2 += v2.x * k0 + v2.y * k1 + v2.z * k2 + v2.w * k3;
      ak3 += v3.x * k0 + v3.y * k1 + v3.z * k2 + v3.w * k3;
      av0 += v0.x * u0 + v0.y * u1 + v0.z * u2 + v0.w * u3;
      av1 += v1.x * u0 + v1.y * u1 + v1.z * u2 + v1.w * u3;
      av2 += v2.x * u0 + v2.y * u1 + v2.z * u2 + v2.w * u3;
      av3 += v3.x * u0 + v3.y * u1 + v3.z * u2 + v3.w * u3;
    }
    kbuf[(size_t)(r0 + rh * 4 + 0) * cDP + col] = ak0;
    kbuf[(size_t)(r0 + rh * 4 + 1) * cDP + col] = ak1;
    kbuf[(size_t)(r0 + rh * 4 + 2) * cDP + col] = ak2;
    kbuf[(size_t)(r0 + rh * 4 + 3) * cDP + col] = ak3;
    vbuf[(size_t)(r0 + rh * 4 + 0) * cDP + col] = av0;
    vbuf[(size_t)(r0 + rh * 4 + 1) * cDP + col] = av1;
    vbuf[(size_t)(r0 + rh * 4 + 2) * cDP + col] = av2;
    vbuf[(size_t)(r0 + rh * 4 + 3) * cDP + col] = av3;
  }
}

// ============ K4: k features + temporal-split windowed writes (R4 exact) ============
__global__ __launch_bounds__(512) void k4_kun(
    const float* __restrict__ kbuf, const float* __restrict__ proj,
    float* __restrict__ k_un, float* __restrict__ tmax) {
  __shared__ float kb[16][cDP];
  const int tid = threadIdx.x;
  const int m = tid & 63, h = tid >> 6, lane = tid & 63;
  float pr[16];
#pragma unroll
  for (int d = 0; d < 16; ++d) pr[d] = proj[m * 16 + d];
  for (int g = blockIdx.x; g < ROWS_KV / 16; g += gridDim.x) {
    const int r0 = g * 16;
    __syncthreads();
    for (int i = tid; i < 16 * cDP; i += 512)
      kb[i >> 7][i & 127] = kbuf[(size_t)(r0 + (i >> 7)) * cDP + (i & 127)];
    __syncthreads();
    for (int r = 0; r < 16; ++r) {
      int row = r0 + r;
      int b = row / cNCTX;
      int t = row - b * cNCTX;
      float4 q0 = *(const float4*)&kb[r][h * 16 + 0];
      float4 q1 = *(const float4*)&kb[r][h * 16 + 4];
      float4 q2 = *(const float4*)&kb[r][h * 16 + 8];
      float4 q3 = *(const float4*)&kb[r][h * 16 + 12];
      float dash = q0.x * pr[0] + q0.y * pr[1] + q0.z * pr[2] + q0.w * pr[3]
                 + q1.x * pr[4] + q1.y * pr[5] + q1.z * pr[6] + q1.w * pr[7]
                 + q2.x * pr[8] + q2.y * pr[9] + q2.z * pr[10] + q2.w * pr[11]
                 + q3.x * pr[12] + q3.y * pr[13] + q3.z * pr[14] + q3.w * pr[15];
      dash *= 0.5f;
      float ss = q0.x * q0.x + q0.y * q0.y + q0.z * q0.z + q0.w * q0.w
               + q1.x * q1.x + q1.y * q1.y + q1.z * q1.z + q1.w * q1.w
               + q2.x * q2.x + q2.y * q2.y + q2.z * q2.z + q2.w * q2.w
               + q3.x * q3.x + q3.y * q3.y + q3.z * q3.z + q3.w * q3.w;
      float un = cRATIO * expf(dash - 0.125f * ss);
      if (t < cNQ)
        k_un[((size_t)(b * cH + h) * cNQ + t) * cM + m] = un;
      if (t >= cSHIFT)
        k_un[((size_t)((b + cB) * cH + h) * cNQ + (t - cSHIFT)) * cM + m] = un;
      float mx = wmax64(dash);
      if (lane == 0) tmax[(b * cH + h) * cNCTX + t] = mx;
    }
  }
}

// ============ K4b: windowed max (R4 exact) ============
__global__ __launch_bounds__(256) void k4b_mxk(
    const float* __restrict__ tmax, float* __restrict__ mxk) {
  const int bh = blockIdx.x;
  const int tid = threadIdx.x;
  float m0 = -1e30f, m1 = -1e30f;
  for (int t = tid; t < cNCTX; t += 256) {
    float v = tmax[bh * cNCTX + t];
    if (t < cNQ) m0 = fmaxf(m0, v);
    if (t >= cSHIFT) m1 = fmaxf(m1, v);
  }
  __shared__ float s0[256], s1[256];
  s0[tid] = m0; s1[tid] = m1;
  __syncthreads();
  for (int s = 128; s; s >>= 1) {
    if (tid < s) { s0[tid] = fmaxf(s0[tid], s0[tid + s]); s1[tid] = fmaxf(s1[tid], s1[tid + s]); }
    __syncthreads();
  }
  if (tid == 0) { mxk[bh] = s0[0]; mxk[bh + 128] = s1[0]; }
}

// ============ K5a: partial ctx/ksum over 512-token chunks (R4 exact) ============
__global__ __launch_bounds__(256) void k5a_ctx(
    const float* __restrict__ k_un, const float* __restrict__ vbuf,
    const float* __restrict__ mxk,
    float* __restrict__ part_c, float* __restrict__ part_k) {
  const int bbh = blockIdx.x;   // 0..255
  const int ch = blockIdx.y;    // 0..5
  const int bb = bbh >> 3, h = bbh & 7;
  const int b = bb & 15, toff = (bb >> 4) * cSHIFT;
  const float ek = expf(-mxk[bbh]);
  const int tid = threadIdx.x, m = tid & 63, eq = tid >> 6;
  __shared__ float ub[64][64];
  __shared__ float vb[64][16];
  float c0 = 0, c1 = 0, c2 = 0, c3 = 0, ks = 0;
  const int nb = ch * 512;
  for (int n0 = nb; n0 < nb + 512; n0 += 64) {
    for (int i = tid; i < 64 * 64; i += 256)
      ub[i >> 6][i & 63] = k_un[((size_t)bbh * cNQ + n0 + (i >> 6)) * cM + (i & 63)];
    for (int i = tid; i < 64 * 16; i += 256)
      vb[i >> 4][i & 15] = vbuf[((size_t)(b * cNCTX) + toff + n0 + (i >> 4)) * cDP + h * 16 + (i & 15)];
    __syncthreads();
#pragma unroll 4
    for (int nn = 0; nn < 64; ++nn) {
      float kf = ub[nn][m] * ek + cEPST;
      ks += kf;
      float4 vv = *(const float4*)&vb[nn][eq * 4];
      c0 += kf * vv.x; c1 += kf * vv.y; c2 += kf * vv.z; c3 += kf * vv.w;
    }
    __syncthreads();
  }
  size_t po = (size_t)ch * 256 + bbh;
  part_c[po * 1024 + m * 16 + eq * 4 + 0] = c0;
  part_c[po * 1024 + m * 16 + eq * 4 + 1] = c1;
  part_c[po * 1024 + m * 16 + eq * 4 + 2] = c2;
  part_c[po * 1024 + m * 16 + eq * 4 + 3] = c3;
  if (eq == 0) part_k[po * 64 + m] = ks;
}

__global__ __launch_bounds__(256) void k5a2_red(
    const float* __restrict__ part_c, const float* __restrict__ part_k,
    float* __restrict__ ctx2, float* __restrict__ ksum) {
  const int bbh = blockIdx.x;
  const int tid = threadIdx.x;
  for (int i = tid; i < 1024; i += 256) {
    float s = 0;
#pragma unroll
    for (int ch = 0; ch < 6; ++ch) s += part_c[((size_t)ch * 256 + bbh) * 1024 + i];
    ctx2[bbh * 1024 + i] = s;
  }
  if (tid < 64) {
    float s = 0;
#pragma unroll
    for (int ch = 0; ch < 6; ++ch) s += part_k[((size_t)ch * 256 + bbh) * 64 + tid];
    ksum[bbh * cM + tid] = s;
  }
}

// ============ KQ2: LN1 -> VALU qGEMM (R8 exact) -> FAVOR (R8 exact) -> qf/denom -> MFMA PV ============
// Composition of R8's k3_q (q_un math byte-identical) and R9's k5b (Output-0-proven MFMA PV).
__global__ __launch_bounds__(256, 2) void kq_fused2(
    const float* __restrict__ y1,
    const float* __restrict__ ln1w, const float* __restrict__ ln1b,
    const unsigned short* __restrict__ wqT, const float* __restrict__ proj,
    const float* __restrict__ ctx2, const float* __restrict__ ksum,
    float* __restrict__ q_un, float* __restrict__ attn) {
  __shared__ unsigned short wqs[128 * 128];   // 32KB
  __shared__ unsigned short xb[32 * 128];     // 8KB
  __shared__ float qb[32][132];               // 16.9KB
  __shared__ unsigned short qfl[8][16][72];   // 18KB bf16 qf [head][row][m]
  __shared__ float dvv[8][16];                // 0.5KB
  const int tid = threadIdx.x;
  const int bb = blockIdx.y;                  // 0..31
  {
    const uint4* s1 = (const uint4*)wqT; uint4* d1 = (uint4*)wqs;
    for (int i = tid; i < 2048; i += 256) d1[i] = s1[i];
  }
  const int lrow = tid >> 3, lsub = tid & 7;
  const int cx = tid & 31, ry = tid >> 5;
  const int lane = tid & 63, wvid = tid >> 6;
  const int m = lane;
  float pr[16];
#pragma unroll
  for (int d = 0; d < 16; ++d) pr[d] = proj[m * 16 + d];
  // ctx2 B-frags + ksum for this wave's two heads (R9 k5b layout, Output-0-proven)
  short8 bfr[2][2];
  float kslr[2];
#pragma unroll
  for (int hh = 0; hh < 2; ++hh) {
    int h = wvid * 2 + hh;
    const float* cp = ctx2 + (size_t)(bb * cH + h) * 1024;
#pragma unroll
    for (int kh = 0; kh < 2; ++kh) {
      short8 bfv;
#pragma unroll
      for (int j = 0; j < 8; ++j) {
        int mm = kh * 32 + (lane >> 4) * 8 + j;
        ((unsigned short*)&bfv)[j] = (unsigned short)bf16r(cp[mm * 16 + (lane & 15)]);
      }
      bfr[hh][kh] = bfv;
    }
    kslr[hh] = ksum[(bb * cH + h) * cM + lane];
  }
  float lw[16], lb[16];
  *(float4*)&lw[0] = *(const float4*)(ln1w + lsub * 16 + 0);
  *(float4*)&lw[4] = *(const float4*)(ln1w + lsub * 16 + 4);
  *(float4*)&lw[8] = *(const float4*)(ln1w + lsub * 16 + 8);
  *(float4*)&lw[12] = *(const float4*)(ln1w + lsub * 16 + 12);
  *(float4*)&lb[0] = *(const float4*)(ln1b + lsub * 16 + 0);
  *(float4*)&lb[4] = *(const float4*)(ln1b + lsub * 16 + 4);
  *(float4*)&lb[8] = *(const float4*)(ln1b + lsub * 16 + 8);
  *(float4*)&lb[12] = *(const float4*)(ln1b + lsub * 16 + 12);
  uint4* xb4 = (uint4*)xb;
  const uint4* wq4 = (const uint4*)wqs;
  __syncthreads();

  for (int tile = blockIdx.x; tile < 96; tile += 16) {
    const int n0 = tile * 32;                   // row within batch bb
    const size_t r0g = (size_t)bb * cNQ + n0;   // global row
    {  // LN1 -> xb (bf16 swizzled) — R8 exact
      const float* yr = y1 + (r0g + lrow) * 128 + lsub * 16;
      float v[16];
      *(float4*)&v[0] = *(const float4*)(yr + 0);
      *(float4*)&v[4] = *(const float4*)(yr + 4);
      *(float4*)&v[8] = *(const float4*)(yr + 8);
      *(float4*)&v[12] = *(const float4*)(yr + 12);
      float s = 0.f, q = 0.f;
#pragma unroll
      for (int j = 0; j < 16; ++j) { s += v[j]; q += v[j] * v[j]; }
#pragma unroll
      for (int o = 1; o <= 4; o <<= 1) { s += __shfl_xor(s, o); q += __shfl_xor(q, o); }
      float mu = s * (1.0f / 128.0f);
      float rs = rsqrtf(q * (1.0f / 128.0f) - mu * mu + cLNEPS);
      unsigned int us[8];
#pragma unroll
      for (int j = 0; j < 8; ++j) {
        float f0 = (v[2 * j] - mu) * rs * lw[2 * j] + lb[2 * j];
        float f1 = (v[2 * j + 1] - mu) * rs * lw[2 * j + 1] + lb[2 * j + 1];
        us[j] = bf16r(f0) | (bf16r(f1) << 16);
      }
      int s0 = (lsub * 2) ^ (lrow & 15), s1 = (lsub * 2 + 1) ^ (lrow & 15);
      xb4[lrow * 16 + s0] = make_uint4(us[0], us[1], us[2], us[3]);
      xb4[lrow * 16 + s1] = make_uint4(us[4], us[5], us[6], us[7]);
    }
    __syncthreads();
    {  // VALU qGEMM — R8 exact
      float acc[4][4] = {};
      gemm_tile(xb4, wq4, cx, ry, acc);
#pragma unroll
      for (int rr = 0; rr < 4; ++rr)
#pragma unroll
        for (int cc = 0; cc < 4; ++cc) qb[ry * 4 + rr][cx + 32 * cc] = acc[rr][cc];
    }
    __syncthreads();
    // FAVOR (R8 exact per (r,hh)) -> qf -> denom -> PV MFMA, two 16-row halves
#pragma unroll
    for (int half = 0; half < 2; ++half) {
      for (int rr = 0; rr < 16; ++rr) {
        int r = half * 16 + rr;
#pragma unroll
        for (int hh = 0; hh < 2; ++hh) {
          int h = wvid * 2 + hh;
          float4 q0 = *(const float4*)&qb[r][h * 16 + 0];
          float4 q1 = *(const float4*)&qb[r][h * 16 + 4];
          float4 q2 = *(const float4*)&qb[r][h * 16 + 8];
          float4 q3 = *(const float4*)&qb[r][h * 16 + 12];
          float dash = q0.x * pr[0] + q0.y * pr[1] + q0.z * pr[2] + q0.w * pr[3]
                     + q1.x * pr[4] + q1.y * pr[5] + q1.z * pr[6] + q1.w * pr[7]
                     + q2.x * pr[8] + q2.y * pr[9] + q2.z * pr[10] + q2.w * pr[11]
                     + q3.x * pr[12] + q3.y * pr[13] + q3.z * pr[14] + q3.w * pr[15];
          dash *= 0.5f;
          float ss = q0.x * q0.x + q0.y * q0.y + q0.z * q0.z + q0.w * q0.w
                   + q1.x * q1.x + q1.y * q1.y + q1.z * q1.z + q1.w * q1.w
                   + q2.x * q2.x + q2.y * q2.y + q2.z * q2.z + q2.w * q2.w
                   + q3.x * q3.x + q3.y * q3.y + q3.z * q3.z + q3.w * q3.w;
          float un = cRATIO * expf(dash - 0.125f * ss);
          size_t base = (size_t)(bb * cH + h) * cNQ + n0 + r;
          q_un[base * cM + m] = un;
          float mx = wmax64(dash);
          float qf = un * expf(-mx) + cEPST;
          qfl[h][rr][lane] = (unsigned short)bf16r(qf);
          float den = wsum64(qf * kslr[hh]);
          if (lane == 0) dvv[h][rr] = 1.0f / den;
        }
      }
      // PV (R9 k5b exact layouts); wave-synchronous: qfl[h]/dvv[h] touched only by this wave
#pragma unroll
      for (int hh = 0; hh < 2; ++hh) {
        int h = wvid * 2 + hh;
        const unsigned short* qp = &qfl[h][0][0];
        int ab = (lane & 15) * 72 + (lane >> 4) * 8;
        short8 a0 = *(const short8*)&qp[ab];
        short8 a1 = *(const short8*)&qp[ab + 32];
        f32x4 c = {0.f, 0.f, 0.f, 0.f};
        c = MFMA16x16(a0, bfr[hh][0], c);
        c = MFMA16x16(a1, bfr[hh][1], c);
#pragma unroll
        for (int reg = 0; reg < 4; ++reg) {
          int rloc = (lane >> 4) * 4 + reg;
          attn[(r0g + half * 16 + rloc) * cDP + h * 16 + (lane & 15)] =
              c[reg] * dvv[h][rloc];
        }
      }
    }
    __syncthreads();
  }
}

// ============ K6: yout = y1 + attn @ wo.T + wo_b, MFMA (R8 exact) ============
__global__ __launch_bounds__(256, 2) void k6_wo(
    const float* __restrict__ attn,
    const unsigned short* __restrict__ woT, const float* __restrict__ wob,
    const float* __restrict__ y1, float* __restrict__ yout) {
  __shared__ unsigned short wos[16384];
  __shared__ unsigned short xb[4096];
  const int tid = threadIdx.x;
  {
    const uint4* s1 = (const uint4*)woT; uint4* d1 = (uint4*)wos;
    for (int i = tid; i < 2048; i += 256) d1[i] = s1[i];
  }
  const int lane = tid & 63, wv = tid >> 6;
  const int lrow = tid >> 3, lsub = tid & 7;
  const int colbase = wv * 32;
  float wb[2];
#pragma unroll
  for (int ct = 0; ct < 2; ++ct) wb[ct] = wob[colbase + ct * 16 + (lane & 15)];
  uint4* xb4 = (uint4*)xb;
  __syncthreads();
  for (int g = blockIdx.x; g < ROWS_Q / 32; g += gridDim.x) {
    const int r0 = g * 32;
    {  // stage attn tile -> bf16 swizzled
      const float* ar = attn + (size_t)(r0 + lrow) * 128 + lsub * 16;
      float v[16];
      *(float4*)&v[0] = *(const float4*)(ar + 0);
      *(float4*)&v[4] = *(const float4*)(ar + 4);
      *(float4*)&v[8] = *(const float4*)(ar + 8);
      *(float4*)&v[12] = *(const float4*)(ar + 12);
      unsigned int us[8];
#pragma unroll
      for (int j = 0; j < 8; ++j)
        us[j] = bf16r(v[2 * j]) | (bf16r(v[2 * j + 1]) << 16);
      int s0 = (lsub * 2) ^ (lrow & 15), s1 = (lsub * 2 + 1) ^ (lrow & 15);
      xb4[lrow * 16 + s0] = make_uint4(us[0], us[1], us[2], us[3]);
      xb4[lrow * 16 + s1] = make_uint4(us[4], us[5], us[6], us[7]);
    }
    __syncthreads();
    {
      f32x4 acc[2][2] = {{{0.f,0.f,0.f,0.f},{0.f,0.f,0.f,0.f}},
                         {{0.f,0.f,0.f,0.f},{0.f,0.f,0.f,0.f}}};
#pragma unroll
      for (int kc = 0; kc < 4; ++kc) {
        short8 af[2], bfv[2];
#pragma unroll
        for (int rt = 0; rt < 2; ++rt) {
          int row = rt * 16 + (lane & 15);
          int slot = ((lane >> 4) + kc * 4) ^ (row & 15);
          af[rt] = *(const short8*)&xb[row * 128 + slot * 8];
        }
#pragma unroll
        for (int ct = 0; ct < 2; ++ct) {
          int col = colbase + ct * 16 + (lane & 15);
          int slot = ((lane >> 4) + kc * 4) ^ (col & 15);
          bfv[ct] = *(const short8*)&wos[col * 128 + slot * 8];
        }
#pragma unroll
        for (int rt = 0; rt < 2; ++rt)
#pragma unroll
          for (int ct = 0; ct < 2; ++ct)
            acc[rt][ct] = MFMA16x16(af[rt], bfv[ct], acc[rt][ct]);
      }
#pragma unroll
      for (int rt = 0; rt < 2; ++rt)
#pragma unroll
        for (int ct = 0; ct < 2; ++ct) {
          int col = colbase + ct * 16 + (lane & 15);
#pragma unroll
          for (int reg = 0; reg < 4; ++reg) {
            int row = rt * 16 + (lane >> 4) * 4 + reg;
            size_t o = (size_t)(r0 + row) * 128 + col;
            yout[o] = acc[rt][ct][reg] + wb[ct] + y1[o];
          }
        }
    }
    __syncthreads();
  }
}

// =============================== launch ===============================
extern "C" void kernel_launch(void* const* d_in, const int* in_sizes, int n_in,
                              void* d_out, int out_size, void* d_ws, size_t ws_size,
                              hipStream_t stream) {
  (void)in_sizes; (void)n_in; (void)out_size; (void)ws_size;
  const float* x = (const float*)d_in[0];
  const float* y = (const float*)d_in[1];
  const float* proj = (const float*)d_in[2];
  const float* ln1w = (const float*)d_in[3];
  const float* ln1b = (const float*)d_in[4];
  const float* ln2w = (const float*)d_in[5];
  const float* ln2b = (const float*)d_in[6];
  const float* ln4w = (const float*)d_in[7];
  const float* ln4b = (const float*)d_in[8];
  const float* fcw = (const float*)d_in[9];
  const float* fcb = (const float*)d_in[10];
  const float* prw = (const float*)d_in[11];
  const float* prb = (const float*)d_in[12];
  const float* wq = (const float*)d_in[13];
  const float* wk = (const float*)d_in[14];
  const float* wv = (const float*)d_in[15];
  const float* wo = (const float*)d_in[16];
  const float* wob = (const float*)d_in[17];

  float* out = (float*)d_out;
  float* q_un = out + 12582912;
  float* k_un = out + 62914560;

  float* ws = (float*)d_ws;
  float* y1 = ws;                          // 12,582,912
  float* kbuf = ws + 12582912;             // 6,553,600 (dead after k4)
  float* vbuf = ws + 19136512;             // 6,553,600 (dead after k5a)
  float* part_c = ws + 12582912;           // 1,572,864 (aliases kbuf; after k4)
  float* part_k = ws + 14155776;           // 98,304
  float* attn = ws + 12582912;             // 12,582,912 (aliases kbuf+vbuf; after k5a2)
  float* tmax = ws + 26476544;             // 409,600
  float* mxk = ws + 26886144;              // 256
  float* ksum = ws + 26886400;             // 16,384
  float* ctx2 = ws + 26902784;             // 262,144
  unsigned short* fcT = (unsigned short*)(ws + 27164928);   // 4 x 16384 ushorts
  unsigned short* prT = fcT + 16384;
  unsigned short* wqT = prT + 16384;
  unsigned short* woT = wqT + 16384;

  // k-side first (ctx2/ksum ready before the fused q-side)
  k0_prep<<<dim3(4), dim3(256), 0, stream>>>(fcw, prw, wq, wo, fcT, prT, wqT, woT);
  k1_mlp<<<dim3(512), dim3(256), 0, stream>>>(y, ln4w, ln4b, fcT, fcb, prT, prb, y1);
  k2_kv<<<dim3(400), dim3(512), 0, stream>>>(x, ln2w, ln2b, wk, wv, kbuf, vbuf);
  k4_kun<<<dim3(400), dim3(512), 0, stream>>>(kbuf, proj, k_un, tmax);
  k4b_mxk<<<dim3(128), dim3(256), 0, stream>>>(tmax, mxk);
  k5a_ctx<<<dim3(256, 6), dim3(256), 0, stream>>>(k_un, vbuf, mxk, part_c, part_k);
  k5a2_red<<<dim3(256), dim3(256), 0, stream>>>(part_c, part_k, ctx2, ksum);
  kq_fused2<<<dim3(16, 32), dim3(256), 0, stream>>>(y1, ln1w, ln1b, wqT, proj,
                                                    ctx2, ksum, q_un, attn);
  k6_wo<<<dim3(512), dim3(256), 0, stream>>>(attn, woT, wob, y1, out);
}

// Round 12
// 516.038 us; speedup vs baseline: 5.1023x; 1.1400x over previous
//
#include <hip/hip_runtime.h>
#include <math.h>

// ---------------- problem constants ----------------
constexpr int cH = 8;
constexpr int cDP = 128;
constexpr int cM = 64;
constexpr int cB = 16;
constexpr int cNCTX = 3200;
constexpr int cNQ = 3072;
constexpr int cSHIFT = 128;
constexpr int ROWS_Q = 2 * cB * cNQ;    // 98304
constexpr int ROWS_KV = cB * cNCTX;     // 51200
constexpr float cRATIO = 0.125f;
constexpr float cEPST = 0.125e-4f;
constexpr float cLNEPS = 1e-5f;

typedef float f32x4 __attribute__((ext_vector_type(4)));
typedef short short8 __attribute__((ext_vector_type(8)));

#define MFMA16x16(a, b, c) __builtin_amdgcn_mfma_f32_16x16x32_bf16((a), (b), (c), 0, 0, 0)

__device__ __forceinline__ float wmax64(float v) {
#pragma unroll
  for (int o = 32; o; o >>= 1) v = fmaxf(v, __shfl_xor(v, o));
  return v;
}
__device__ __forceinline__ float wsum64(float v) {
#pragma unroll
  for (int o = 32; o; o >>= 1) v += __shfl_xor(v, o);
  return v;
}
__device__ __forceinline__ float gelu_f(float x) {
  return 0.5f * x * (1.0f + tanhf(0.79788456080286536f * (x + 0.044715f * x * x * x)));
}
// fp32 -> bf16 (RTNE), low 16 bits
__device__ __forceinline__ unsigned int bf16r(float f) {
  unsigned int x = __float_as_uint(f);
  return (x + 0x7fffu + ((x >> 16) & 1u)) >> 16;
}
// 8 packed bf16 (uint4) -> 8 floats
__device__ __forceinline__ void cvt8(uint4 u, float f[8]) {
  f[0] = __uint_as_float(u.x << 16);
  f[1] = __uint_as_float(u.x & 0xffff0000u);
  f[2] = __uint_as_float(u.y << 16);
  f[3] = __uint_as_float(u.y & 0xffff0000u);
  f[4] = __uint_as_float(u.z << 16);
  f[5] = __uint_as_float(u.z & 0xffff0000u);
  f[6] = __uint_as_float(u.w << 16);
  f[7] = __uint_as_float(u.w & 0xffff0000u);
}
// swizzled ushort index for element (row, k) in a [*][128] 16-bit tile
__device__ __forceinline__ int swz(int row, int k) {
  return row * 128 + ((((k >> 3) ^ (row & 15)) << 3) | (k & 7));
}

// ============ K0: weight prep -> bf16, [n][k] layout, pre-swizzled (R10 exact) ============
__global__ __launch_bounds__(256) void k0_prep(
    const float* __restrict__ fcw, const float* __restrict__ prw,
    const float* __restrict__ wq, const float* __restrict__ wo,
    unsigned short* __restrict__ fcT, unsigned short* __restrict__ prT,
    unsigned short* __restrict__ wqT, unsigned short* __restrict__ woT) {
  const int mat = blockIdx.x;
  const float* src = mat == 0 ? fcw : mat == 1 ? prw : mat == 2 ? wq : wo;
  unsigned short* dst = mat == 0 ? fcT : mat == 1 ? prT : mat == 2 ? wqT : woT;
  const bool tr = (mat < 2);   // fc_w/pr_w are [k][n]; wq/wo are [n][k]
  for (int i = threadIdx.x; i < 16384; i += 256) {
    int n = i >> 7, k = i & 127;
    float f = tr ? src[k * 128 + n] : src[i];
    dst[swz(n, k)] = (unsigned short)bf16r(f);
  }
}

// ============ K1: MLP (LN4 -> fc -> gelu -> pr -> +y), MFMA (R10 exact) ============
__global__ __launch_bounds__(256, 2) void k1_mlp(
    const float* __restrict__ y,
    const float* __restrict__ ln4w, const float* __restrict__ ln4b,
    const unsigned short* __restrict__ fcT, const float* __restrict__ fcb,
    const unsigned short* __restrict__ prT, const float* __restrict__ prb,
    float* __restrict__ y1) {
  __shared__ unsigned short wfc[16384];
  __shared__ unsigned short wpr[16384];
  __shared__ unsigned short xb[4096];
  __shared__ unsigned short hb[4096];
  const int tid = threadIdx.x;
  {
    const uint4* s1 = (const uint4*)fcT; uint4* d1 = (uint4*)wfc;
    const uint4* s2 = (const uint4*)prT; uint4* d2 = (uint4*)wpr;
    for (int i = tid; i < 2048; i += 256) { d1[i] = s1[i]; d2[i] = s2[i]; }
  }
  const int lane = tid & 63, wv = tid >> 6;
  const int lrow = tid >> 3, lsub = tid & 7;
  const int colbase = wv * 32;
  float fb[2], pb[2];
#pragma unroll
  for (int ct = 0; ct < 2; ++ct) {
    int col = colbase + ct * 16 + (lane & 15);
    fb[ct] = fcb[col];
    pb[ct] = prb[col];
  }
  float lw[16], lb[16];
  *(float4*)&lw[0] = *(const float4*)(ln4w + lsub * 16 + 0);
  *(float4*)&lw[4] = *(const float4*)(ln4w + lsub * 16 + 4);
  *(float4*)&lw[8] = *(const float4*)(ln4w + lsub * 16 + 8);
  *(float4*)&lw[12] = *(const float4*)(ln4w + lsub * 16 + 12);
  *(float4*)&lb[0] = *(const float4*)(ln4b + lsub * 16 + 0);
  *(float4*)&lb[4] = *(const float4*)(ln4b + lsub * 16 + 4);
  *(float4*)&lb[8] = *(const float4*)(ln4b + lsub * 16 + 8);
  *(float4*)&lb[12] = *(const float4*)(ln4b + lsub * 16 + 12);
  uint4* xb4 = (uint4*)xb;
  __syncthreads();

  for (int g = blockIdx.x; g < ROWS_Q / 32; g += gridDim.x) {
    const int r0 = g * 32;
    {  // LN4 -> xb (bf16 swizzled)
      const float* yr = y + (size_t)(r0 + lrow) * 128 + lsub * 16;
      float v[16];
      *(float4*)&v[0] = *(const float4*)(yr + 0);
      *(float4*)&v[4] = *(const float4*)(yr + 4);
      *(float4*)&v[8] = *(const float4*)(yr + 8);
      *(float4*)&v[12] = *(const float4*)(yr + 12);
      float s = 0.f, q = 0.f;
#pragma unroll
      for (int j = 0; j < 16; ++j) { s += v[j]; q += v[j] * v[j]; }
#pragma unroll
      for (int o = 1; o <= 4; o <<= 1) { s += __shfl_xor(s, o); q += __shfl_xor(q, o); }
      float mu = s * (1.0f / 128.0f);
      float rs = rsqrtf(q * (1.0f / 128.0f) - mu * mu + cLNEPS);
      unsigned int us[8];
#pragma unroll
      for (int j = 0; j < 8; ++j) {
        float f0 = (v[2 * j] - mu) * rs * lw[2 * j] + lb[2 * j];
        float f1 = (v[2 * j + 1] - mu) * rs * lw[2 * j + 1] + lb[2 * j + 1];
        us[j] = bf16r(f0) | (bf16r(f1) << 16);
      }
      int s0 = (lsub * 2) ^ (lrow & 15), s1 = (lsub * 2 + 1) ^ (lrow & 15);
      xb4[lrow * 16 + s0] = make_uint4(us[0], us[1], us[2], us[3]);
      xb4[lrow * 16 + s1] = make_uint4(us[4], us[5], us[6], us[7]);
    }
    __syncthreads();
    {  // GEMM1 (MFMA) + gelu -> hb
      f32x4 acc[2][2] = {{{0.f,0.f,0.f,0.f},{0.f,0.f,0.f,0.f}},
                         {{0.f,0.f,0.f,0.f},{0.f,0.f,0.f,0.f}}};
#pragma unroll
      for (int kc = 0; kc < 4; ++kc) {
        short8 af[2], bfv[2];
#pragma unroll
        for (int rt = 0; rt < 2; ++rt) {
          int row = rt * 16 + (lane & 15);
          int slot = ((lane >> 4) + kc * 4) ^ (row & 15);
          af[rt] = *(const short8*)&xb[row * 128 + slot * 8];
        }
#pragma unroll
        for (int ct = 0; ct < 2; ++ct) {
          int col = colbase + ct * 16 + (lane & 15);
          int slot = ((lane >> 4) + kc * 4) ^ (col & 15);
          bfv[ct] = *(const short8*)&wfc[col * 128 + slot * 8];
        }
#pragma unroll
        for (int rt = 0; rt < 2; ++rt)
#pragma unroll
          for (int ct = 0; ct < 2; ++ct)
            acc[rt][ct] = MFMA16x16(af[rt], bfv[ct], acc[rt][ct]);
      }
#pragma unroll
      for (int rt = 0; rt < 2; ++rt)
#pragma unroll
        for (int ct = 0; ct < 2; ++ct) {
          int col = colbase + ct * 16 + (lane & 15);
#pragma unroll
          for (int reg = 0; reg < 4; ++reg) {
            int row = rt * 16 + (lane >> 4) * 4 + reg;
            hb[swz(row, col)] = (unsigned short)bf16r(gelu_f(acc[rt][ct][reg] + fb[ct]));
          }
        }
    }
    __syncthreads();
    {  // GEMM2 (MFMA) + bias + residual -> y1
      f32x4 a2[2][2] = {{{0.f,0.f,0.f,0.f},{0.f,0.f,0.f,0.f}},
                        {{0.f,0.f,0.f,0.f},{0.f,0.f,0.f,0.f}}};
#pragma unroll
      for (int kc = 0; kc < 4; ++kc) {
        short8 af[2], bfv[2];
#pragma unroll
        for (int rt = 0; rt < 2; ++rt) {
          int row = rt * 16 + (lane & 15);
          int slot = ((lane >> 4) + kc * 4) ^ (row & 15);
          af[rt] = *(const short8*)&hb[row * 128 + slot * 8];
        }
#pragma unroll
        for (int ct = 0; ct < 2; ++ct) {
          int col = colbase + ct * 16 + (lane & 15);
          int slot = ((lane >> 4) + kc * 4) ^ (col & 15);
          bfv[ct] = *(const short8*)&wpr[col * 128 + slot * 8];
        }
#pragma unroll
        for (int rt = 0; rt < 2; ++rt)
#pragma unroll
          for (int ct = 0; ct < 2; ++ct)
            a2[rt][ct] = MFMA16x16(af[rt], bfv[ct], a2[rt][ct]);
      }
#pragma unroll
      for (int rt = 0; rt < 2; ++rt)
#pragma unroll
        for (int ct = 0; ct < 2; ++ct) {
          int col = colbase + ct * 16 + (lane & 15);
#pragma unroll
          for (int reg = 0; reg < 4; ++reg) {
            int row = rt * 16 + (lane >> 4) * 4 + reg;
            size_t o = (size_t)(r0 + row) * 128 + col;
            y1[o] = a2[rt][ct][reg] + pb[ct] + y[o];
          }
        }
    }
    __syncthreads();
  }
}

// ============ K2: LN2(x) -> k,v projections (R10 exact) ============
__global__ __launch_bounds__(512) void k2_kv(
    const float* __restrict__ x,
    const float* __restrict__ ln2w, const float* __restrict__ ln2b,
    const float* __restrict__ wkw, const float* __restrict__ wvw,
    float* __restrict__ kbuf, float* __restrict__ vbuf) {
  __shared__ float wkT[32 * cDP];
  __shared__ float wvT[32 * cDP];
  __shared__ float xbs[16][32];
  const int tid = threadIdx.x;
  for (int i = tid; i < 32 * cDP; i += 512) {
    int j = i >> 5, d = i & 31;
    wkT[d * cDP + j] = wkw[i];
    wvT[d * cDP + j] = wvw[i];
  }
  const int dl = tid & 31, rl = tid >> 5;
  const int col = tid & 127, rh = tid >> 7;
  const float l2w = ln2w[dl], l2b = ln2b[dl];
  __syncthreads();
  for (int g = blockIdx.x; g < ROWS_KV / 16; g += gridDim.x) {
    const int r0 = g * 16;
    __syncthreads();
    {
      float v = x[(size_t)(r0 + rl) * 32 + dl];
      float s = v, q = v * v;
#pragma unroll
      for (int o = 16; o; o >>= 1) { s += __shfl_xor(s, o); q += __shfl_xor(q, o); }
      float mu = s * (1.0f / 32.0f);
      float var = q * (1.0f / 32.0f) - mu * mu;
      xbs[rl][dl] = (v - mu) * rsqrtf(var + cLNEPS) * l2w + l2b;
    }
    __syncthreads();
    float ak0 = 0, ak1 = 0, ak2 = 0, ak3 = 0, av0 = 0, av1 = 0, av2 = 0, av3 = 0;
    for (int d = 0; d < 32; d += 4) {
      float4 v0 = *(const float4*)&xbs[rh * 4 + 0][d];
      float4 v1 = *(const float4*)&xbs[rh * 4 + 1][d];
      float4 v2 = *(const float4*)&xbs[rh * 4 + 2][d];
      float4 v3 = *(const float4*)&xbs[rh * 4 + 3][d];
      float k0 = wkT[(d + 0) * cDP + col], k1 = wkT[(d + 1) * cDP + col];
      float k2 = wkT[(d + 2) * cDP + col], k3 = wkT[(d + 3) * cDP + col];
      float u0 = wvT[(d + 0) * cDP + col], u1 = wvT[(d + 1) * cDP + col];
      float u2 = wvT[(d + 2) * cDP + col], u3 = wvT[(d + 3) * cDP + col];
      ak0 += v0.x * k0 + v0.y * k1 + v0.z * k2 + v0.w * k3;
      ak1 += v1.x * k0 + v1.y * k1 + v1.z * k2 + v1.w * k3;
      ak2 += v2.x * k0 + v2.y * k1 + v2.z * k2 + v2.w * k3;
      ak3 += v3.x * k0 + v3.y * k1 + v3.z * k2 + v3.w * k3;
      av0 += v0.x * u0 + v0.y * u1 + v0.z * u2 + v0.w * u3;
      av1 += v1.x * u0 + v1.y * u1 + v1.z * u2 + v1.w * u3;
      av2 += v2.x * u0 + v2.y * u1 + v2.z * u2 + v2.w * u3;
      av3 += v3.x * u0 + v3.y * u1 + v3.z * u2 + v3.w * u3;
    }
    kbuf[(size_t)(r0 + rh * 4 + 0) * cDP + col] = ak0;
    kbuf[(size_t)(r0 + rh * 4 + 1) * cDP + col] = ak1;
    kbuf[(size_t)(r0 + rh * 4 + 2) * cDP + col] = ak2;
    kbuf[(size_t)(r0 + rh * 4 + 3) * cDP + col] = ak3;
    vbuf[(size_t)(r0 + rh * 4 + 0) * cDP + col] = av0;
    vbuf[(size_t)(r0 + rh * 4 + 1) * cDP + col] = av1;
    vbuf[(size_t)(r0 + rh * 4 + 2) * cDP + col] = av2;
    vbuf[(size_t)(r0 + rh * 4 + 3) * cDP + col] = av3;
  }
}

// ============ K4: k features + temporal-split windowed writes (R10 exact) ============
__global__ __launch_bounds__(512) void k4_kun(
    const float* __restrict__ kbuf, const float* __restrict__ proj,
    float* __restrict__ k_un, float* __restrict__ tmax) {
  __shared__ float kb[16][cDP];
  const int tid = threadIdx.x;
  const int m = tid & 63, h = tid >> 6, lane = tid & 63;
  float pr[16];
#pragma unroll
  for (int d = 0; d < 16; ++d) pr[d] = proj[m * 16 + d];
  for (int g = blockIdx.x; g < ROWS_KV / 16; g += gridDim.x) {
    const int r0 = g * 16;
    __syncthreads();
    for (int i = tid; i < 16 * cDP; i += 512)
      kb[i >> 7][i & 127] = kbuf[(size_t)(r0 + (i >> 7)) * cDP + (i & 127)];
    __syncthreads();
    for (int r = 0; r < 16; ++r) {
      int row = r0 + r;
      int b = row / cNCTX;
      int t = row - b * cNCTX;
      float4 q0 = *(const float4*)&kb[r][h * 16 + 0];
      float4 q1 = *(const float4*)&kb[r][h * 16 + 4];
      float4 q2 = *(const float4*)&kb[r][h * 16 + 8];
      float4 q3 = *(const float4*)&kb[r][h * 16 + 12];
      float dash = q0.x * pr[0] + q0.y * pr[1] + q0.z * pr[2] + q0.w * pr[3]
                 + q1.x * pr[4] + q1.y * pr[5] + q1.z * pr[6] + q1.w * pr[7]
                 + q2.x * pr[8] + q2.y * pr[9] + q2.z * pr[10] + q2.w * pr[11]
                 + q3.x * pr[12] + q3.y * pr[13] + q3.z * pr[14] + q3.w * pr[15];
      dash *= 0.5f;
      float ss = q0.x * q0.x + q0.y * q0.y + q0.z * q0.z + q0.w * q0.w
               + q1.x * q1.x + q1.y * q1.y + q1.z * q1.z + q1.w * q1.w
               + q2.x * q2.x + q2.y * q2.y + q2.z * q2.z + q2.w * q2.w
               + q3.x * q3.x + q3.y * q3.y + q3.z * q3.z + q3.w * q3.w;
      float un = cRATIO * expf(dash - 0.125f * ss);
      if (t < cNQ)
        k_un[((size_t)(b * cH + h) * cNQ + t) * cM + m] = un;
      if (t >= cSHIFT)
        k_un[((size_t)((b + cB) * cH + h) * cNQ + (t - cSHIFT)) * cM + m] = un;
      float mx = wmax64(dash);
      if (lane == 0) tmax[(b * cH + h) * cNCTX + t] = mx;
    }
  }
}

// ============ K4b: windowed max (R10 exact) ============
__global__ __launch_bounds__(256) void k4b_mxk(
    const float* __restrict__ tmax, float* __restrict__ mxk) {
  const int bh = blockIdx.x;
  const int tid = threadIdx.x;
  float m0 = -1e30f, m1 = -1e30f;
  for (int t = tid; t < cNCTX; t += 256) {
    float v = tmax[bh * cNCTX + t];
    if (t < cNQ) m0 = fmaxf(m0, v);
    if (t >= cSHIFT) m1 = fmaxf(m1, v);
  }
  __shared__ float s0[256], s1[256];
  s0[tid] = m0; s1[tid] = m1;
  __syncthreads();
  for (int s = 128; s; s >>= 1) {
    if (tid < s) { s0[tid] = fmaxf(s0[tid], s0[tid + s]); s1[tid] = fmaxf(s1[tid], s1[tid + s]); }
    __syncthreads();
  }
  if (tid == 0) { mxk[bh] = s0[0]; mxk[bh + 128] = s1[0]; }
}

// ============ K5a: partial ctx/ksum over 512-token chunks (R10 exact) ============
__global__ __launch_bounds__(256) void k5a_ctx(
    const float* __restrict__ k_un, const float* __restrict__ vbuf,
    const float* __restrict__ mxk,
    float* __restrict__ part_c, float* __restrict__ part_k) {
  const int bbh = blockIdx.x;   // 0..255
  const int ch = blockIdx.y;    // 0..5
  const int bb = bbh >> 3, h = bbh & 7;
  const int b = bb & 15, toff = (bb >> 4) * cSHIFT;
  const float ek = expf(-mxk[bbh]);
  const int tid = threadIdx.x, m = tid & 63, eq = tid >> 6;
  __shared__ float ub[64][64];
  __shared__ float vb[64][16];
  float c0 = 0, c1 = 0, c2 = 0, c3 = 0, ks = 0;
  const int nb = ch * 512;
  for (int n0 = nb; n0 < nb + 512; n0 += 64) {
    for (int i = tid; i < 64 * 64; i += 256)
      ub[i >> 6][i & 63] = k_un[((size_t)bbh * cNQ + n0 + (i >> 6)) * cM + (i & 63)];
    for (int i = tid; i < 64 * 16; i += 256)
      vb[i >> 4][i & 15] = vbuf[((size_t)(b * cNCTX) + toff + n0 + (i >> 4)) * cDP + h * 16 + (i & 15)];
    __syncthreads();
#pragma unroll 4
    for (int nn = 0; nn < 64; ++nn) {
      float kf = ub[nn][m] * ek + cEPST;
      ks += kf;
      float4 vv = *(const float4*)&vb[nn][eq * 4];
      c0 += kf * vv.x; c1 += kf * vv.y; c2 += kf * vv.z; c3 += kf * vv.w;
    }
    __syncthreads();
  }
  size_t po = (size_t)ch * 256 + bbh;
  part_c[po * 1024 + m * 16 + eq * 4 + 0] = c0;
  part_c[po * 1024 + m * 16 + eq * 4 + 1] = c1;
  part_c[po * 1024 + m * 16 + eq * 4 + 2] = c2;
  part_c[po * 1024 + m * 16 + eq * 4 + 3] = c3;
  if (eq == 0) part_k[po * 64 + m] = ks;
}

__global__ __launch_bounds__(256) void k5a2_red(
    const float* __restrict__ part_c, const float* __restrict__ part_k,
    float* __restrict__ ctx2, float* __restrict__ ksum) {
  const int bbh = blockIdx.x;
  const int tid = threadIdx.x;
  for (int i = tid; i < 1024; i += 256) {
    float s = 0;
#pragma unroll
    for (int ch = 0; ch < 6; ++ch) s += part_c[((size_t)ch * 256 + bbh) * 1024 + i];
    ctx2[bbh * 1024 + i] = s;
  }
  if (tid < 64) {
    float s = 0;
#pragma unroll
    for (int ch = 0; ch < 6; ++ch) s += part_k[((size_t)ch * 256 + bbh) * 64 + tid];
    ksum[bbh * cM + tid] = s;
  }
}

// ============ KQ2 (512 threads): LN1 -> VALU fp32 qGEMM -> FAVOR -> denom -> MFMA PV ============
// Math bit-identical to passing R10; 8 waves (1 head each), 2x4 micro-tile, 2 blocks/CU.
__global__ __launch_bounds__(512, 4) void kq_fused2(
    const float* __restrict__ y1,
    const float* __restrict__ ln1w, const float* __restrict__ ln1b,
    const unsigned short* __restrict__ wqT, const float* __restrict__ proj,
    const float* __restrict__ ctx2, const float* __restrict__ ksum,
    float* __restrict__ q_un, float* __restrict__ attn) {
  __shared__ unsigned short wqs[128 * 128];   // 32KB bf16
  __shared__ unsigned short xb[32 * 128];     // 8KB bf16
  __shared__ float qb[32][132];               // 16.9KB
  __shared__ unsigned short qfl[8][16][72];   // 18KB bf16 qf [wave][row][m]
  __shared__ float dvv[8][16];                // 0.5KB
  const int tid = threadIdx.x;
  const int bb = blockIdx.y;                  // 0..31
  {
    const uint4* s1 = (const uint4*)wqT; uint4* d1 = (uint4*)wqs;
    for (int i = tid; i < 2048; i += 512) d1[i] = s1[i];
  }
  const int lane = tid & 63, wvid = tid >> 6;   // 8 waves
  const int lrow = tid >> 4, c8 = tid & 15;     // LN: 32 rows x 16 chunks of 8
  const int cx = tid & 31, ry2 = tid >> 5;      // GEMM: rows ry2*2..+1, cols cx+32*cc
  const int m = lane;
  const int h = wvid;                           // head per wave
  float pr[16];
#pragma unroll
  for (int d = 0; d < 16; ++d) pr[d] = proj[m * 16 + d];
  // ctx2 B-frags + ksum for this wave's head (layout proven R9/R10 via Output 0)
  short8 bfr[2];
  {
    const float* cp = ctx2 + (size_t)(bb * cH + h) * 1024;
#pragma unroll
    for (int kh = 0; kh < 2; ++kh) {
      short8 bfv;
#pragma unroll
      for (int j = 0; j < 8; ++j) {
        int mm = kh * 32 + (lane >> 4) * 8 + j;
        ((unsigned short*)&bfv)[j] = (unsigned short)bf16r(cp[mm * 16 + (lane & 15)]);
      }
      bfr[kh] = bfv;
    }
  }
  const float kslr = ksum[(bb * cH + h) * cM + lane];
  float lw[8], lb[8];
  *(float4*)&lw[0] = *(const float4*)(ln1w + c8 * 8 + 0);
  *(float4*)&lw[4] = *(const float4*)(ln1w + c8 * 8 + 4);
  *(float4*)&lb[0] = *(const float4*)(ln1b + c8 * 8 + 0);
  *(float4*)&lb[4] = *(const float4*)(ln1b + c8 * 8 + 4);
  uint4* xb4 = (uint4*)xb;
  const uint4* wq4 = (const uint4*)wqs;
  __syncthreads();

  for (int tile = blockIdx.x; tile < 96; tile += 16) {
    const int n0 = tile * 32;
    const size_t r0g = (size_t)bb * cNQ + n0;
    {  // LN1 -> xb (bf16 swizzled); row lrow, cols c8*8..+7
      const float* yr = y1 + (r0g + lrow) * 128 + c8 * 8;
      float v[8];
      *(float4*)&v[0] = *(const float4*)(yr + 0);
      *(float4*)&v[4] = *(const float4*)(yr + 4);
      float s = 0.f, q = 0.f;
#pragma unroll
      for (int j = 0; j < 8; ++j) { s += v[j]; q += v[j] * v[j]; }
#pragma unroll
      for (int o = 1; o <= 8; o <<= 1) { s += __shfl_xor(s, o); q += __shfl_xor(q, o); }
      float mu = s * (1.0f / 128.0f);
      float rs = rsqrtf(q * (1.0f / 128.0f) - mu * mu + cLNEPS);
      unsigned int us[4];
#pragma unroll
      for (int j = 0; j < 4; ++j) {
        float f0 = (v[2 * j] - mu) * rs * lw[2 * j] + lb[2 * j];
        float f1 = (v[2 * j + 1] - mu) * rs * lw[2 * j + 1] + lb[2 * j + 1];
        us[j] = bf16r(f0) | (bf16r(f1) << 16);
      }
      xb4[lrow * 16 + (c8 ^ (lrow & 15))] = make_uint4(us[0], us[1], us[2], us[3]);
    }
    __syncthreads();
    {  // VALU fp32 qGEMM (same fmaf order per output as R10): rows ry2*2..+1, cols cx+32*cc
      float acc[2][4] = {};
#pragma unroll 2
      for (int kg = 0; kg < 16; ++kg) {
        uint4 xv[2], wv[4];
#pragma unroll
        for (int rr = 0; rr < 2; ++rr) {
          int r = ry2 * 2 + rr;
          xv[rr] = xb4[r * 16 + (kg ^ (r & 15))];
        }
#pragma unroll
        for (int cc = 0; cc < 4; ++cc) {
          int c = cx + 32 * cc;
          wv[cc] = wq4[c * 16 + (kg ^ (c & 15))];
        }
        float xf[2][8];
#pragma unroll
        for (int rr = 0; rr < 2; ++rr) cvt8(xv[rr], xf[rr]);
#pragma unroll
        for (int cc = 0; cc < 4; ++cc) {
          float wf[8];
          cvt8(wv[cc], wf);
#pragma unroll
          for (int rr = 0; rr < 2; ++rr)
#pragma unroll
            for (int i = 0; i < 8; ++i)
              acc[rr][cc] = fmaf(xf[rr][i], wf[i], acc[rr][cc]);
        }
      }
#pragma unroll
      for (int rr = 0; rr < 2; ++rr)
#pragma unroll
        for (int cc = 0; cc < 4; ++cc)
          qb[ry2 * 2 + rr][cx + 32 * cc] = acc[rr][cc];
    }
    __syncthreads();
    // FAVOR (R10-exact math, head h per wave) -> qf -> denom -> PV MFMA, two halves
#pragma unroll
    for (int half = 0; half < 2; ++half) {
      for (int rr = 0; rr < 16; ++rr) {
        int r = half * 16 + rr;
        float4 q0 = *(const float4*)&qb[r][h * 16 + 0];
        float4 q1 = *(const float4*)&qb[r][h * 16 + 4];
        float4 q2 = *(const float4*)&qb[r][h * 16 + 8];
        float4 q3 = *(const float4*)&qb[r][h * 16 + 12];
        float dash = q0.x * pr[0] + q0.y * pr[1] + q0.z * pr[2] + q0.w * pr[3]
                   + q1.x * pr[4] + q1.y * pr[5] + q1.z * pr[6] + q1.w * pr[7]
                   + q2.x * pr[8] + q2.y * pr[9] + q2.z * pr[10] + q2.w * pr[11]
                   + q3.x * pr[12] + q3.y * pr[13] + q3.z * pr[14] + q3.w * pr[15];
        dash *= 0.5f;
        float ss = q0.x * q0.x + q0.y * q0.y + q0.z * q0.z + q0.w * q0.w
                 + q1.x * q1.x + q1.y * q1.y + q1.z * q1.z + q1.w * q1.w
                 + q2.x * q2.x + q2.y * q2.y + q2.z * q2.z + q2.w * q2.w
                 + q3.x * q3.x + q3.y * q3.y + q3.z * q3.z + q3.w * q3.w;
        float un = cRATIO * expf(dash - 0.125f * ss);
        size_t base = (size_t)(bb * cH + h) * cNQ + n0 + r;
        q_un[base * cM + m] = un;
        float mx = wmax64(dash);
        float qf = un * expf(-mx) + cEPST;
        qfl[wvid][rr][lane] = (unsigned short)bf16r(qf);
        float den = wsum64(qf * kslr);
        if (lane == 0) dvv[wvid][rr] = 1.0f / den;
      }
      // PV (proven layouts); wave-synchronous: qfl[wvid]/dvv[wvid] touched only by this wave
      {
        const unsigned short* qp = &qfl[wvid][0][0];
        int ab = (lane & 15) * 72 + (lane >> 4) * 8;
        short8 a0 = *(const short8*)&qp[ab];
        short8 a1 = *(const short8*)&qp[ab + 32];
        f32x4 c = {0.f, 0.f, 0.f, 0.f};
        c = MFMA16x16(a0, bfr[0], c);
        c = MFMA16x16(a1, bfr[1], c);
#pragma unroll
        for (int reg = 0; reg < 4; ++reg) {
          int rloc = (lane >> 4) * 4 + reg;
          attn[(r0g + half * 16 + rloc) * cDP + h * 16 + (lane & 15)] =
              c[reg] * dvv[wvid][rloc];
        }
      }
    }
    __syncthreads();
  }
}

// ============ K6: yout = y1 + attn @ wo.T + wo_b, MFMA (R10 exact) ============
__global__ __launch_bounds__(256, 2) void k6_wo(
    const float* __restrict__ attn,
    const unsigned short* __restrict__ woT, const float* __restrict__ wob,
    const float* __restrict__ y1, float* __restrict__ yout) {
  __shared__ unsigned short wos[16384];
  __shared__ unsigned short xb[4096];
  const int tid = threadIdx.x;
  {
    const uint4* s1 = (const uint4*)woT; uint4* d1 = (uint4*)wos;
    for (int i = tid; i < 2048; i += 256) d1[i] = s1[i];
  }
  const int lane = tid & 63, wv = tid >> 6;
  const int lrow = tid >> 3, lsub = tid & 7;
  const int colbase = wv * 32;
  float wb[2];
#pragma unroll
  for (int ct = 0; ct < 2; ++ct) wb[ct] = wob[colbase + ct * 16 + (lane & 15)];
  uint4* xb4 = (uint4*)xb;
  __syncthreads();
  for (int g = blockIdx.x; g < ROWS_Q / 32; g += gridDim.x) {
    const int r0 = g * 32;
    {  // stage attn tile -> bf16 swizzled
      const float* ar = attn + (size_t)(r0 + lrow) * 128 + lsub * 16;
      float v[16];
      *(float4*)&v[0] = *(const float4*)(ar + 0);
      *(float4*)&v[4] = *(const float4*)(ar + 4);
      *(float4*)&v[8] = *(const float4*)(ar + 8);
      *(float4*)&v[12] = *(const float4*)(ar + 12);
      unsigned int us[8];
#pragma unroll
      for (int j = 0; j < 8; ++j)
        us[j] = bf16r(v[2 * j]) | (bf16r(v[2 * j + 1]) << 16);
      int s0 = (lsub * 2) ^ (lrow & 15), s1 = (lsub * 2 + 1) ^ (lrow & 15);
      xb4[lrow * 16 + s0] = make_uint4(us[0], us[1], us[2], us[3]);
      xb4[lrow * 16 + s1] = make_uint4(us[4], us[5], us[6], us[7]);
    }
    __syncthreads();
    {
      f32x4 acc[2][2] = {{{0.f,0.f,0.f,0.f},{0.f,0.f,0.f,0.f}},
                         {{0.f,0.f,0.f,0.f},{0.f,0.f,0.f,0.f}}};
#pragma unroll
      for (int kc = 0; kc < 4; ++kc) {
        short8 af[2], bfv[2];
#pragma unroll
        for (int rt = 0; rt < 2; ++rt) {
          int row = rt * 16 + (lane & 15);
          int slot = ((lane >> 4) + kc * 4) ^ (row & 15);
          af[rt] = *(const short8*)&xb[row * 128 + slot * 8];
        }
#pragma unroll
        for (int ct = 0; ct < 2; ++ct) {
          int col = colbase + ct * 16 + (lane & 15);
          int slot = ((lane >> 4) + kc * 4) ^ (col & 15);
          bfv[ct] = *(const short8*)&wos[col * 128 + slot * 8];
        }
#pragma unroll
        for (int rt = 0; rt < 2; ++rt)
#pragma unroll
          for (int ct = 0; ct < 2; ++ct)
            acc[rt][ct] = MFMA16x16(af[rt], bfv[ct], acc[rt][ct]);
      }
#pragma unroll
      for (int rt = 0; rt < 2; ++rt)
#pragma unroll
        for (int ct = 0; ct < 2; ++ct) {
          int col = colbase + ct * 16 + (lane & 15);
#pragma unroll
          for (int reg = 0; reg < 4; ++reg) {
            int row = rt * 16 + (lane >> 4) * 4 + reg;
            size_t o = (size_t)(r0 + row) * 128 + col;
            yout[o] = acc[rt][ct][reg] + wb[ct] + y1[o];
          }
        }
    }
    __syncthreads();
  }
}

// =============================== launch ===============================
extern "C" void kernel_launch(void* const* d_in, const int* in_sizes, int n_in,
                              void* d_out, int out_size, void* d_ws, size_t ws_size,
                              hipStream_t stream) {
  (void)in_sizes; (void)n_in; (void)out_size; (void)ws_size;
  const float* x = (const float*)d_in[0];
  const float* y = (const float*)d_in[1];
  const float* proj = (const float*)d_in[2];
  const float* ln1w = (const float*)d_in[3];
  const float* ln1b = (const float*)d_in[4];
  const float* ln2w = (const float*)d_in[5];
  const float* ln2b = (const float*)d_in[6];
  const float* ln4w = (const float*)d_in[7];
  const float* ln4b = (const float*)d_in[8];
  const float* fcw = (const float*)d_in[9];
  const float* fcb = (const float*)d_in[10];
  const float* prw = (const float*)d_in[11];
  const float* prb = (const float*)d_in[12];
  const float* wq = (const float*)d_in[13];
  const float* wk = (const float*)d_in[14];
  const float* wv = (const float*)d_in[15];
  const float* wo = (const float*)d_in[16];
  const float* wob = (const float*)d_in[17];

  float* out = (float*)d_out;
  float* q_un = out + 12582912;
  float* k_un = out + 62914560;

  float* ws = (float*)d_ws;
  float* y1 = ws;                          // 12,582,912
  float* kbuf = ws + 12582912;             // 6,553,600 (dead after k4)
  float* vbuf = ws + 19136512;             // 6,553,600 (dead after k5a)
  float* part_c = ws + 12582912;           // 1,572,864 (aliases kbuf; after k4)
  float* part_k = ws + 14155776;           // 98,304
  float* attn = ws + 12582912;             // 12,582,912 (aliases kbuf+vbuf; after k5a2)
  float* tmax = ws + 26476544;             // 409,600
  float* mxk = ws + 26886144;              // 256
  float* ksum = ws + 26886400;             // 16,384
  float* ctx2 = ws + 26902784;             // 262,144
  unsigned short* fcT = (unsigned short*)(ws + 27164928);   // 4 x 16384 ushorts
  unsigned short* prT = fcT + 16384;
  unsigned short* wqT = prT + 16384;
  unsigned short* woT = wqT + 16384;

  k0_prep<<<dim3(4), dim3(256), 0, stream>>>(fcw, prw, wq, wo, fcT, prT, wqT, woT);
  k1_mlp<<<dim3(512), dim3(256), 0, stream>>>(y, ln4w, ln4b, fcT, fcb, prT, prb, y1);
  k2_kv<<<dim3(400), dim3(512), 0, stream>>>(x, ln2w, ln2b, wk, wv, kbuf, vbuf);
  k4_kun<<<dim3(400), dim3(512), 0, stream>>>(kbuf, proj, k_un, tmax);
  k4b_mxk<<<dim3(128), dim3(256), 0, stream>>>(tmax, mxk);
  k5a_ctx<<<dim3(256, 6), dim3(256), 0, stream>>>(k_un, vbuf, mxk, part_c, part_k);
  k5a2_red<<<dim3(256), dim3(256), 0, stream>>>(part_c, part_k, ctx2, ksum);
  kq_fused2<<<dim3(16, 32), dim3(512), 0, stream>>>(y1, ln1w, ln1b, wqT, proj,
                                                    ctx2, ksum, q_un, attn);
  k6_wo<<<dim3(512), dim3(256), 0, stream>>>(attn, woT, wob, y1, out);
}

// Round 13
// 496.221 us; speedup vs baseline: 5.3061x; 1.0399x over previous
//
#include <hip/hip_runtime.h>
#include <math.h>

// ---------------- problem constants ----------------
constexpr int cH = 8;
constexpr int cDP = 128;
constexpr int cM = 64;
constexpr int cB = 16;
constexpr int cNCTX = 3200;
constexpr int cNQ = 3072;
constexpr int cSHIFT = 128;
constexpr int ROWS_Q = 2 * cB * cNQ;    // 98304
constexpr int ROWS_KV = cB * cNCTX;     // 51200
constexpr float cRATIO = 0.125f;
constexpr float cEPST = 0.125e-4f;
constexpr float cLNEPS = 1e-5f;

typedef float f32x4 __attribute__((ext_vector_type(4)));
typedef short short8 __attribute__((ext_vector_type(8)));

#define MFMA16x16(a, b, c) __builtin_amdgcn_mfma_f32_16x16x32_bf16((a), (b), (c), 0, 0, 0)

__device__ __forceinline__ float wmax64(float v) {
#pragma unroll
  for (int o = 32; o; o >>= 1) v = fmaxf(v, __shfl_xor(v, o));
  return v;
}
__device__ __forceinline__ float wsum64(float v) {
#pragma unroll
  for (int o = 32; o; o >>= 1) v += __shfl_xor(v, o);
  return v;
}
__device__ __forceinline__ float gelu_f(float x) {
  return 0.5f * x * (1.0f + tanhf(0.79788456080286536f * (x + 0.044715f * x * x * x)));
}
// fp32 -> bf16 (RTNE), low 16 bits
__device__ __forceinline__ unsigned int bf16r(float f) {
  unsigned int x = __float_as_uint(f);
  return (x + 0x7fffu + ((x >> 16) & 1u)) >> 16;
}
// 8 packed bf16 (uint4) -> 8 floats
__device__ __forceinline__ void cvt8(uint4 u, float f[8]) {
  f[0] = __uint_as_float(u.x << 16);
  f[1] = __uint_as_float(u.x & 0xffff0000u);
  f[2] = __uint_as_float(u.y << 16);
  f[3] = __uint_as_float(u.y & 0xffff0000u);
  f[4] = __uint_as_float(u.z << 16);
  f[5] = __uint_as_float(u.z & 0xffff0000u);
  f[6] = __uint_as_float(u.w << 16);
  f[7] = __uint_as_float(u.w & 0xffff0000u);
}
// swizzled ushort index for element (row, k) in a [*][128] 16-bit tile
__device__ __forceinline__ int swz(int row, int k) {
  return row * 128 + ((((k >> 3) ^ (row & 15)) << 3) | (k & 7));
}

// ============ K0: weight prep -> bf16, [n][k] layout, pre-swizzled (R12 exact) ============
__global__ __launch_bounds__(256) void k0_prep(
    const float* __restrict__ fcw, const float* __restrict__ prw,
    const float* __restrict__ wq, const float* __restrict__ wo,
    unsigned short* __restrict__ fcT, unsigned short* __restrict__ prT,
    unsigned short* __restrict__ wqT, unsigned short* __restrict__ woT) {
  const int mat = blockIdx.x;
  const float* src = mat == 0 ? fcw : mat == 1 ? prw : mat == 2 ? wq : wo;
  unsigned short* dst = mat == 0 ? fcT : mat == 1 ? prT : mat == 2 ? wqT : woT;
  const bool tr = (mat < 2);   // fc_w/pr_w are [k][n]; wq/wo are [n][k]
  for (int i = threadIdx.x; i < 16384; i += 256) {
    int n = i >> 7, k = i & 127;
    float f = tr ? src[k * 128 + n] : src[i];
    dst[swz(n, k)] = (unsigned short)bf16r(f);
  }
}

// ============ K1: MLP (LN4 -> fc -> gelu -> pr -> +y), MFMA (R12 exact) ============
__global__ __launch_bounds__(256, 2) void k1_mlp(
    const float* __restrict__ y,
    const float* __restrict__ ln4w, const float* __restrict__ ln4b,
    const unsigned short* __restrict__ fcT, const float* __restrict__ fcb,
    const unsigned short* __restrict__ prT, const float* __restrict__ prb,
    float* __restrict__ y1) {
  __shared__ unsigned short wfc[16384];
  __shared__ unsigned short wpr[16384];
  __shared__ unsigned short xb[4096];
  __shared__ unsigned short hb[4096];
  const int tid = threadIdx.x;
  {
    const uint4* s1 = (const uint4*)fcT; uint4* d1 = (uint4*)wfc;
    const uint4* s2 = (const uint4*)prT; uint4* d2 = (uint4*)wpr;
    for (int i = tid; i < 2048; i += 256) { d1[i] = s1[i]; d2[i] = s2[i]; }
  }
  const int lane = tid & 63, wv = tid >> 6;
  const int lrow = tid >> 3, lsub = tid & 7;
  const int colbase = wv * 32;
  float fb[2], pb[2];
#pragma unroll
  for (int ct = 0; ct < 2; ++ct) {
    int col = colbase + ct * 16 + (lane & 15);
    fb[ct] = fcb[col];
    pb[ct] = prb[col];
  }
  float lw[16], lb[16];
  *(float4*)&lw[0] = *(const float4*)(ln4w + lsub * 16 + 0);
  *(float4*)&lw[4] = *(const float4*)(ln4w + lsub * 16 + 4);
  *(float4*)&lw[8] = *(const float4*)(ln4w + lsub * 16 + 8);
  *(float4*)&lw[12] = *(const float4*)(ln4w + lsub * 16 + 12);
  *(float4*)&lb[0] = *(const float4*)(ln4b + lsub * 16 + 0);
  *(float4*)&lb[4] = *(const float4*)(ln4b + lsub * 16 + 4);
  *(float4*)&lb[8] = *(const float4*)(ln4b + lsub * 16 + 8);
  *(float4*)&lb[12] = *(const float4*)(ln4b + lsub * 16 + 12);
  uint4* xb4 = (uint4*)xb;
  __syncthreads();

  for (int g = blockIdx.x; g < ROWS_Q / 32; g += gridDim.x) {
    const int r0 = g * 32;
    {  // LN4 -> xb (bf16 swizzled)
      const float* yr = y + (size_t)(r0 + lrow) * 128 + lsub * 16;
      float v[16];
      *(float4*)&v[0] = *(const float4*)(yr + 0);
      *(float4*)&v[4] = *(const float4*)(yr + 4);
      *(float4*)&v[8] = *(const float4*)(yr + 8);
      *(float4*)&v[12] = *(const float4*)(yr + 12);
      float s = 0.f, q = 0.f;
#pragma unroll
      for (int j = 0; j < 16; ++j) { s += v[j]; q += v[j] * v[j]; }
#pragma unroll
      for (int o = 1; o <= 4; o <<= 1) { s += __shfl_xor(s, o); q += __shfl_xor(q, o); }
      float mu = s * (1.0f / 128.0f);
      float rs = rsqrtf(q * (1.0f / 128.0f) - mu * mu + cLNEPS);
      unsigned int us[8];
#pragma unroll
      for (int j = 0; j < 8; ++j) {
        float f0 = (v[2 * j] - mu) * rs * lw[2 * j] + lb[2 * j];
        float f1 = (v[2 * j + 1] - mu) * rs * lw[2 * j + 1] + lb[2 * j + 1];
        us[j] = bf16r(f0) | (bf16r(f1) << 16);
      }
      int s0 = (lsub * 2) ^ (lrow & 15), s1 = (lsub * 2 + 1) ^ (lrow & 15);
      xb4[lrow * 16 + s0] = make_uint4(us[0], us[1], us[2], us[3]);
      xb4[lrow * 16 + s1] = make_uint4(us[4], us[5], us[6], us[7]);
    }
    __syncthreads();
    {  // GEMM1 (MFMA) + gelu -> hb
      f32x4 acc[2][2] = {{{0.f,0.f,0.f,0.f},{0.f,0.f,0.f,0.f}},
                         {{0.f,0.f,0.f,0.f},{0.f,0.f,0.f,0.f}}};
#pragma unroll
      for (int kc = 0; kc < 4; ++kc) {
        short8 af[2], bfv[2];
#pragma unroll
        for (int rt = 0; rt < 2; ++rt) {
          int row = rt * 16 + (lane & 15);
          int slot = ((lane >> 4) + kc * 4) ^ (row & 15);
          af[rt] = *(const short8*)&xb[row * 128 + slot * 8];
        }
#pragma unroll
        for (int ct = 0; ct < 2; ++ct) {
          int col = colbase + ct * 16 + (lane & 15);
          int slot = ((lane >> 4) + kc * 4) ^ (col & 15);
          bfv[ct] = *(const short8*)&wfc[col * 128 + slot * 8];
        }
#pragma unroll
        for (int rt = 0; rt < 2; ++rt)
#pragma unroll
          for (int ct = 0; ct < 2; ++ct)
            acc[rt][ct] = MFMA16x16(af[rt], bfv[ct], acc[rt][ct]);
      }
#pragma unroll
      for (int rt = 0; rt < 2; ++rt)
#pragma unroll
        for (int ct = 0; ct < 2; ++ct) {
          int col = colbase + ct * 16 + (lane & 15);
#pragma unroll
          for (int reg = 0; reg < 4; ++reg) {
            int row = rt * 16 + (lane >> 4) * 4 + reg;
            hb[swz(row, col)] = (unsigned short)bf16r(gelu_f(acc[rt][ct][reg] + fb[ct]));
          }
        }
    }
    __syncthreads();
    {  // GEMM2 (MFMA) + bias + residual -> y1
      f32x4 a2[2][2] = {{{0.f,0.f,0.f,0.f},{0.f,0.f,0.f,0.f}},
                        {{0.f,0.f,0.f,0.f},{0.f,0.f,0.f,0.f}}};
#pragma unroll
      for (int kc = 0; kc < 4; ++kc) {
        short8 af[2], bfv[2];
#pragma unroll
        for (int rt = 0; rt < 2; ++rt) {
          int row = rt * 16 + (lane & 15);
          int slot = ((lane >> 4) + kc * 4) ^ (row & 15);
          af[rt] = *(const short8*)&hb[row * 128 + slot * 8];
        }
#pragma unroll
        for (int ct = 0; ct < 2; ++ct) {
          int col = colbase + ct * 16 + (lane & 15);
          int slot = ((lane >> 4) + kc * 4) ^ (col & 15);
          bfv[ct] = *(const short8*)&wpr[col * 128 + slot * 8];
        }
#pragma unroll
        for (int rt = 0; rt < 2; ++rt)
#pragma unroll
          for (int ct = 0; ct < 2; ++ct)
            a2[rt][ct] = MFMA16x16(af[rt], bfv[ct], a2[rt][ct]);
      }
#pragma unroll
      for (int rt = 0; rt < 2; ++rt)
#pragma unroll
        for (int ct = 0; ct < 2; ++ct) {
          int col = colbase + ct * 16 + (lane & 15);
#pragma unroll
          for (int reg = 0; reg < 4; ++reg) {
            int row = rt * 16 + (lane >> 4) * 4 + reg;
            size_t o = (size_t)(r0 + row) * 128 + col;
            y1[o] = a2[rt][ct][reg] + pb[ct] + y[o];
          }
        }
    }
    __syncthreads();
  }
}

// ============ K2: LN2(x) -> k,v projections (R12 exact) ============
__global__ __launch_bounds__(512) void k2_kv(
    const float* __restrict__ x,
    const float* __restrict__ ln2w, const float* __restrict__ ln2b,
    const float* __restrict__ wkw, const float* __restrict__ wvw,
    float* __restrict__ kbuf, float* __restrict__ vbuf) {
  __shared__ float wkT[32 * cDP];
  __shared__ float wvT[32 * cDP];
  __shared__ float xbs[16][32];
  const int tid = threadIdx.x;
  for (int i = tid; i < 32 * cDP; i += 512) {
    int j = i >> 5, d = i & 31;
    wkT[d * cDP + j] = wkw[i];
    wvT[d * cDP + j] = wvw[i];
  }
  const int dl = tid & 31, rl = tid >> 5;
  const int col = tid & 127, rh = tid >> 7;
  const float l2w = ln2w[dl], l2b = ln2b[dl];
  __syncthreads();
  for (int g = blockIdx.x; g < ROWS_KV / 16; g += gridDim.x) {
    const int r0 = g * 16;
    __syncthreads();
    {
      float v = x[(size_t)(r0 + rl) * 32 + dl];
      float s = v, q = v * v;
#pragma unroll
      for (int o = 16; o; o >>= 1) { s += __shfl_xor(s, o); q += __shfl_xor(q, o); }
      float mu = s * (1.0f / 32.0f);
      float var = q * (1.0f / 32.0f) - mu * mu;
      xbs[rl][dl] = (v - mu) * rsqrtf(var + cLNEPS) * l2w + l2b;
    }
    __syncthreads();
    float ak0 = 0, ak1 = 0, ak2 = 0, ak3 = 0, av0 = 0, av1 = 0, av2 = 0, av3 = 0;
    for (int d = 0; d < 32; d += 4) {
      float4 v0 = *(const float4*)&xbs[rh * 4 + 0][d];
      float4 v1 = *(const float4*)&xbs[rh * 4 + 1][d];
      float4 v2 = *(const float4*)&xbs[rh * 4 + 2][d];
      float4 v3 = *(const float4*)&xbs[rh * 4 + 3][d];
      float k0 = wkT[(d + 0) * cDP + col], k1 = wkT[(d + 1) * cDP + col];
      float k2 = wkT[(d + 2) * cDP + col], k3 = wkT[(d + 3) * cDP + col];
      float u0 = wvT[(d + 0) * cDP + col], u1 = wvT[(d + 1) * cDP + col];
      float u2 = wvT[(d + 2) * cDP + col], u3 = wvT[(d + 3) * cDP + col];
      ak0 += v0.x * k0 + v0.y * k1 + v0.z * k2 + v0.w * k3;
      ak1 += v1.x * k0 + v1.y * k1 + v1.z * k2 + v1.w * k3;
      ak2 += v2.x * k0 + v2.y * k1 + v2.z * k2 + v2.w * k3;
      ak3 += v3.x * k0 + v3.y * k1 + v3.z * k2 + v3.w * k3;
      av0 += v0.x * u0 + v0.y * u1 + v0.z * u2 + v0.w * u3;
      av1 += v1.x * u0 + v1.y * u1 + v1.z * u2 + v1.w * u3;
      av2 += v2.x * u0 + v2.y * u1 + v2.z * u2 + v2.w * u3;
      av3 += v3.x * u0 + v3.y * u1 + v3.z * u2 + v3.w * u3;
    }
    kbuf[(size_t)(r0 + rh * 4 + 0) * cDP + col] = ak0;
    kbuf[(size_t)(r0 + rh * 4 + 1) * cDP + col] = ak1;
    kbuf[(size_t)(r0 + rh * 4 + 2) * cDP + col] = ak2;
    kbuf[(size_t)(r0 + rh * 4 + 3) * cDP + col] = ak3;
    vbuf[(size_t)(r0 + rh * 4 + 0) * cDP + col] = av0;
    vbuf[(size_t)(r0 + rh * 4 + 1) * cDP + col] = av1;
    vbuf[(size_t)(r0 + rh * 4 + 2) * cDP + col] = av2;
    vbuf[(size_t)(r0 + rh * 4 + 3) * cDP + col] = av3;
  }
}

// ============ K4: k features + temporal-split windowed writes (__expf) ============
__global__ __launch_bounds__(512) void k4_kun(
    const float* __restrict__ kbuf, const float* __restrict__ proj,
    float* __restrict__ k_un, float* __restrict__ tmax) {
  __shared__ float kb[16][cDP];
  const int tid = threadIdx.x;
  const int m = tid & 63, h = tid >> 6, lane = tid & 63;
  float pr[16];
#pragma unroll
  for (int d = 0; d < 16; ++d) pr[d] = proj[m * 16 + d];
  for (int g = blockIdx.x; g < ROWS_KV / 16; g += gridDim.x) {
    const int r0 = g * 16;
    __syncthreads();
    for (int i = tid; i < 16 * cDP; i += 512)
      kb[i >> 7][i & 127] = kbuf[(size_t)(r0 + (i >> 7)) * cDP + (i & 127)];
    __syncthreads();
    for (int r = 0; r < 16; ++r) {
      int row = r0 + r;
      int b = row / cNCTX;
      int t = row - b * cNCTX;
      float4 q0 = *(const float4*)&kb[r][h * 16 + 0];
      float4 q1 = *(const float4*)&kb[r][h * 16 + 4];
      float4 q2 = *(const float4*)&kb[r][h * 16 + 8];
      float4 q3 = *(const float4*)&kb[r][h * 16 + 12];
      float dash = q0.x * pr[0] + q0.y * pr[1] + q0.z * pr[2] + q0.w * pr[3]
                 + q1.x * pr[4] + q1.y * pr[5] + q1.z * pr[6] + q1.w * pr[7]
                 + q2.x * pr[8] + q2.y * pr[9] + q2.z * pr[10] + q2.w * pr[11]
                 + q3.x * pr[12] + q3.y * pr[13] + q3.z * pr[14] + q3.w * pr[15];
      dash *= 0.5f;
      float ss = q0.x * q0.x + q0.y * q0.y + q0.z * q0.z + q0.w * q0.w
               + q1.x * q1.x + q1.y * q1.y + q1.z * q1.z + q1.w * q1.w
               + q2.x * q2.x + q2.y * q2.y + q2.z * q2.z + q2.w * q2.w
               + q3.x * q3.x + q3.y * q3.y + q3.z * q3.z + q3.w * q3.w;
      float un = cRATIO * __expf(dash - 0.125f * ss);
      if (t < cNQ)
        k_un[((size_t)(b * cH + h) * cNQ + t) * cM + m] = un;
      if (t >= cSHIFT)
        k_un[((size_t)((b + cB) * cH + h) * cNQ + (t - cSHIFT)) * cM + m] = un;
      float mx = wmax64(dash);
      if (lane == 0) tmax[(b * cH + h) * cNCTX + t] = mx;
    }
  }
}

// ============ K4b: windowed max (R12 exact) ============
__global__ __launch_bounds__(256) void k4b_mxk(
    const float* __restrict__ tmax, float* __restrict__ mxk) {
  const int bh = blockIdx.x;
  const int tid = threadIdx.x;
  float m0 = -1e30f, m1 = -1e30f;
  for (int t = tid; t < cNCTX; t += 256) {
    float v = tmax[bh * cNCTX + t];
    if (t < cNQ) m0 = fmaxf(m0, v);
    if (t >= cSHIFT) m1 = fmaxf(m1, v);
  }
  __shared__ float s0[256], s1[256];
  s0[tid] = m0; s1[tid] = m1;
  __syncthreads();
  for (int s = 128; s; s >>= 1) {
    if (tid < s) { s0[tid] = fmaxf(s0[tid], s0[tid + s]); s1[tid] = fmaxf(s1[tid], s1[tid + s]); }
    __syncthreads();
  }
  if (tid == 0) { mxk[bh] = s0[0]; mxk[bh + 128] = s1[0]; }
}

// ============ K5a: partial ctx/ksum over 512-token chunks (R12 exact) ============
__global__ __launch_bounds__(256) void k5a_ctx(
    const float* __restrict__ k_un, const float* __restrict__ vbuf,
    const float* __restrict__ mxk,
    float* __restrict__ part_c, float* __restrict__ part_k) {
  const int bbh = blockIdx.x;   // 0..255
  const int ch = blockIdx.y;    // 0..5
  const int bb = bbh >> 3, h = bbh & 7;
  const int b = bb & 15, toff = (bb >> 4) * cSHIFT;
  const float ek = expf(-mxk[bbh]);
  const int tid = threadIdx.x, m = tid & 63, eq = tid >> 6;
  __shared__ float ub[64][64];
  __shared__ float vb[64][16];
  float c0 = 0, c1 = 0, c2 = 0, c3 = 0, ks = 0;
  const int nb = ch * 512;
  for (int n0 = nb; n0 < nb + 512; n0 += 64) {
    for (int i = tid; i < 64 * 64; i += 256)
      ub[i >> 6][i & 63] = k_un[((size_t)bbh * cNQ + n0 + (i >> 6)) * cM + (i & 63)];
    for (int i = tid; i < 64 * 16; i += 256)
      vb[i >> 4][i & 15] = vbuf[((size_t)(b * cNCTX) + toff + n0 + (i >> 4)) * cDP + h * 16 + (i & 15)];
    __syncthreads();
#pragma unroll 4
    for (int nn = 0; nn < 64; ++nn) {
      float kf = ub[nn][m] * ek + cEPST;
      ks += kf;
      float4 vv = *(const float4*)&vb[nn][eq * 4];
      c0 += kf * vv.x; c1 += kf * vv.y; c2 += kf * vv.z; c3 += kf * vv.w;
    }
    __syncthreads();
  }
  size_t po = (size_t)ch * 256 + bbh;
  part_c[po * 1024 + m * 16 + eq * 4 + 0] = c0;
  part_c[po * 1024 + m * 16 + eq * 4 + 1] = c1;
  part_c[po * 1024 + m * 16 + eq * 4 + 2] = c2;
  part_c[po * 1024 + m * 16 + eq * 4 + 3] = c3;
  if (eq == 0) part_k[po * 64 + m] = ks;
}

__global__ __launch_bounds__(256) void k5a2_red(
    const float* __restrict__ part_c, const float* __restrict__ part_k,
    float* __restrict__ ctx2, float* __restrict__ ksum) {
  const int bbh = blockIdx.x;
  const int tid = threadIdx.x;
  for (int i = tid; i < 1024; i += 256) {
    float s = 0;
#pragma unroll
    for (int ch = 0; ch < 6; ++ch) s += part_c[((size_t)ch * 256 + bbh) * 1024 + i];
    ctx2[bbh * 1024 + i] = s;
  }
  if (tid < 64) {
    float s = 0;
#pragma unroll
    for (int ch = 0; ch < 6; ++ch) s += part_k[((size_t)ch * 256 + bbh) * 64 + tid];
    ksum[bbh * cM + tid] = s;
  }
}

// ============ KQ2 (512 threads): LN1 -> VALU fp32 qGEMM -> FAVOR(__expf) -> denom -> MFMA PV ============
__global__ __launch_bounds__(512, 4) void kq_fused2(
    const float* __restrict__ y1,
    const float* __restrict__ ln1w, const float* __restrict__ ln1b,
    const unsigned short* __restrict__ wqT, const float* __restrict__ proj,
    const float* __restrict__ ctx2, const float* __restrict__ ksum,
    float* __restrict__ q_un, float* __restrict__ attn) {
  __shared__ unsigned short wqs[128 * 128];   // 32KB bf16
  __shared__ unsigned short xb[32 * 128];     // 8KB bf16
  __shared__ float qb[32][132];               // 16.9KB
  __shared__ unsigned short qfl[8][16][72];   // 18KB bf16 qf [wave][row][m]
  __shared__ float dvv[8][16];                // 0.5KB
  const int tid = threadIdx.x;
  const int bb = blockIdx.y;                  // 0..31
  {
    const uint4* s1 = (const uint4*)wqT; uint4* d1 = (uint4*)wqs;
    for (int i = tid; i < 2048; i += 512) d1[i] = s1[i];
  }
  const int lane = tid & 63, wvid = tid >> 6;   // 8 waves
  const int lrow = tid >> 4, c8 = tid & 15;     // LN: 32 rows x 16 chunks of 8
  const int cx = tid & 31, ry2 = tid >> 5;      // GEMM: rows ry2*2..+1, cols cx+32*cc
  const int m = lane;
  const int h = wvid;                           // head per wave
  float pr[16];
#pragma unroll
  for (int d = 0; d < 16; ++d) pr[d] = proj[m * 16 + d];
  short8 bfr[2];
  {
    const float* cp = ctx2 + (size_t)(bb * cH + h) * 1024;
#pragma unroll
    for (int kh = 0; kh < 2; ++kh) {
      short8 bfv;
#pragma unroll
      for (int j = 0; j < 8; ++j) {
        int mm = kh * 32 + (lane >> 4) * 8 + j;
        ((unsigned short*)&bfv)[j] = (unsigned short)bf16r(cp[mm * 16 + (lane & 15)]);
      }
      bfr[kh] = bfv;
    }
  }
  const float kslr = ksum[(bb * cH + h) * cM + lane];
  float lw[8], lb[8];
  *(float4*)&lw[0] = *(const float4*)(ln1w + c8 * 8 + 0);
  *(float4*)&lw[4] = *(const float4*)(ln1w + c8 * 8 + 4);
  *(float4*)&lb[0] = *(const float4*)(ln1b + c8 * 8 + 0);
  *(float4*)&lb[4] = *(const float4*)(ln1b + c8 * 8 + 4);
  uint4* xb4 = (uint4*)xb;
  const uint4* wq4 = (const uint4*)wqs;
  __syncthreads();

  for (int tile = blockIdx.x; tile < 96; tile += 16) {
    const int n0 = tile * 32;
    const size_t r0g = (size_t)bb * cNQ + n0;
    {  // LN1 -> xb (bf16 swizzled); row lrow, cols c8*8..+7
      const float* yr = y1 + (r0g + lrow) * 128 + c8 * 8;
      float v[8];
      *(float4*)&v[0] = *(const float4*)(yr + 0);
      *(float4*)&v[4] = *(const float4*)(yr + 4);
      float s = 0.f, q = 0.f;
#pragma unroll
      for (int j = 0; j < 8; ++j) { s += v[j]; q += v[j] * v[j]; }
#pragma unroll
      for (int o = 1; o <= 8; o <<= 1) { s += __shfl_xor(s, o); q += __shfl_xor(q, o); }
      float mu = s * (1.0f / 128.0f);
      float rs = rsqrtf(q * (1.0f / 128.0f) - mu * mu + cLNEPS);
      unsigned int us[4];
#pragma unroll
      for (int j = 0; j < 4; ++j) {
        float f0 = (v[2 * j] - mu) * rs * lw[2 * j] + lb[2 * j];
        float f1 = (v[2 * j + 1] - mu) * rs * lw[2 * j + 1] + lb[2 * j + 1];
        us[j] = bf16r(f0) | (bf16r(f1) << 16);
      }
      xb4[lrow * 16 + (c8 ^ (lrow & 15))] = make_uint4(us[0], us[1], us[2], us[3]);
    }
    __syncthreads();
    {  // VALU fp32 qGEMM: rows ry2*2..+1, cols cx+32*cc
      float acc[2][4] = {};
#pragma unroll 2
      for (int kg = 0; kg < 16; ++kg) {
        uint4 xv[2], wv[4];
#pragma unroll
        for (int rr = 0; rr < 2; ++rr) {
          int r = ry2 * 2 + rr;
          xv[rr] = xb4[r * 16 + (kg ^ (r & 15))];
        }
#pragma unroll
        for (int cc = 0; cc < 4; ++cc) {
          int c = cx + 32 * cc;
          wv[cc] = wq4[c * 16 + (kg ^ (c & 15))];
        }
        float xf[2][8];
#pragma unroll
        for (int rr = 0; rr < 2; ++rr) cvt8(xv[rr], xf[rr]);
#pragma unroll
        for (int cc = 0; cc < 4; ++cc) {
          float wf[8];
          cvt8(wv[cc], wf);
#pragma unroll
          for (int rr = 0; rr < 2; ++rr)
#pragma unroll
            for (int i = 0; i < 8; ++i)
              acc[rr][cc] = fmaf(xf[rr][i], wf[i], acc[rr][cc]);
        }
      }
#pragma unroll
      for (int rr = 0; rr < 2; ++rr)
#pragma unroll
        for (int cc = 0; cc < 4; ++cc)
          qb[ry2 * 2 + rr][cx + 32 * cc] = acc[rr][cc];
    }
    __syncthreads();
    // FAVOR (__expf) -> qf -> denom -> PV MFMA, two halves
#pragma unroll
    for (int half = 0; half < 2; ++half) {
      for (int rr = 0; rr < 16; ++rr) {
        int r = half * 16 + rr;
        float4 q0 = *(const float4*)&qb[r][h * 16 + 0];
        float4 q1 = *(const float4*)&qb[r][h * 16 + 4];
        float4 q2 = *(const float4*)&qb[r][h * 16 + 8];
        float4 q3 = *(const float4*)&qb[r][h * 16 + 12];
        float dash = q0.x * pr[0] + q0.y * pr[1] + q0.z * pr[2] + q0.w * pr[3]
                   + q1.x * pr[4] + q1.y * pr[5] + q1.z * pr[6] + q1.w * pr[7]
                   + q2.x * pr[8] + q2.y * pr[9] + q2.z * pr[10] + q2.w * pr[11]
                   + q3.x * pr[12] + q3.y * pr[13] + q3.z * pr[14] + q3.w * pr[15];
        dash *= 0.5f;
        float ss = q0.x * q0.x + q0.y * q0.y + q0.z * q0.z + q0.w * q0.w
                 + q1.x * q1.x + q1.y * q1.y + q1.z * q1.z + q1.w * q1.w
                 + q2.x * q2.x + q2.y * q2.y + q2.z * q2.z + q2.w * q2.w
                 + q3.x * q3.x + q3.y * q3.y + q3.z * q3.z + q3.w * q3.w;
        float un = cRATIO * __expf(dash - 0.125f * ss);
        size_t base = (size_t)(bb * cH + h) * cNQ + n0 + r;
        q_un[base * cM + m] = un;
        float mx = wmax64(dash);
        float qf = un * __expf(-mx) + cEPST;
        qfl[wvid][rr][lane] = (unsigned short)bf16r(qf);
        float den = wsum64(qf * kslr);
        if (lane == 0) dvv[wvid][rr] = 1.0f / den;
      }
      // PV (proven layouts); wave-synchronous
      {
        const unsigned short* qp = &qfl[wvid][0][0];
        int ab = (lane & 15) * 72 + (lane >> 4) * 8;
        short8 a0 = *(const short8*)&qp[ab];
        short8 a1 = *(const short8*)&qp[ab + 32];
        f32x4 c = {0.f, 0.f, 0.f, 0.f};
        c = MFMA16x16(a0, bfr[0], c);
        c = MFMA16x16(a1, bfr[1], c);
#pragma unroll
        for (int reg = 0; reg < 4; ++reg) {
          int rloc = (lane >> 4) * 4 + reg;
          attn[(r0g + half * 16 + rloc) * cDP + h * 16 + (lane & 15)] =
              c[reg] * dvv[wvid][rloc];
        }
      }
    }
    __syncthreads();
  }
}

// ============ K6: yout = y1 + attn @ wo.T + wo_b, MFMA (R12 exact) ============
__global__ __launch_bounds__(256, 2) void k6_wo(
    const float* __restrict__ attn,
    const unsigned short* __restrict__ woT, const float* __restrict__ wob,
    const float* __restrict__ y1, float* __restrict__ yout) {
  __shared__ unsigned short wos[16384];
  __shared__ unsigned short xb[4096];
  const int tid = threadIdx.x;
  {
    const uint4* s1 = (const uint4*)woT; uint4* d1 = (uint4*)wos;
    for (int i = tid; i < 2048; i += 256) d1[i] = s1[i];
  }
  const int lane = tid & 63, wv = tid >> 6;
  const int lrow = tid >> 3, lsub = tid & 7;
  const int colbase = wv * 32;
  float wb[2];
#pragma unroll
  for (int ct = 0; ct < 2; ++ct) wb[ct] = wob[colbase + ct * 16 + (lane & 15)];
  uint4* xb4 = (uint4*)xb;
  __syncthreads();
  for (int g = blockIdx.x; g < ROWS_Q / 32; g += gridDim.x) {
    const int r0 = g * 32;
    {  // stage attn tile -> bf16 swizzled
      const float* ar = attn + (size_t)(r0 + lrow) * 128 + lsub * 16;
      float v[16];
      *(float4*)&v[0] = *(const float4*)(ar + 0);
      *(float4*)&v[4] = *(const float4*)(ar + 4);
      *(float4*)&v[8] = *(const float4*)(ar + 8);
      *(float4*)&v[12] = *(const float4*)(ar + 12);
      unsigned int us[8];
#pragma unroll
      for (int j = 0; j < 8; ++j)
        us[j] = bf16r(v[2 * j]) | (bf16r(v[2 * j + 1]) << 16);
      int s0 = (lsub * 2) ^ (lrow & 15), s1 = (lsub * 2 + 1) ^ (lrow & 15);
      xb4[lrow * 16 + s0] = make_uint4(us[0], us[1], us[2], us[3]);
      xb4[lrow * 16 + s1] = make_uint4(us[4], us[5], us[6], us[7]);
    }
    __syncthreads();
    {
      f32x4 acc[2][2] = {{{0.f,0.f,0.f,0.f},{0.f,0.f,0.f,0.f}},
                         {{0.f,0.f,0.f,0.f},{0.f,0.f,0.f,0.f}}};
#pragma unroll
      for (int kc = 0; kc < 4; ++kc) {
        short8 af[2], bfv[2];
#pragma unroll
        for (int rt = 0; rt < 2; ++rt) {
          int row = rt * 16 + (lane & 15);
          int slot = ((lane >> 4) + kc * 4) ^ (row & 15);
          af[rt] = *(const short8*)&xb[row * 128 + slot * 8];
        }
#pragma unroll
        for (int ct = 0; ct < 2; ++ct) {
          int col = colbase + ct * 16 + (lane & 15);
          int slot = ((lane >> 4) + kc * 4) ^ (col & 15);
          bfv[ct] = *(const short8*)&wos[col * 128 + slot * 8];
        }
#pragma unroll
        for (int rt = 0; rt < 2; ++rt)
#pragma unroll
          for (int ct = 0; ct < 2; ++ct)
            acc[rt][ct] = MFMA16x16(af[rt], bfv[ct], acc[rt][ct]);
      }
#pragma unroll
      for (int rt = 0; rt < 2; ++rt)
#pragma unroll
        for (int ct = 0; ct < 2; ++ct) {
          int col = colbase + ct * 16 + (lane & 15);
#pragma unroll
          for (int reg = 0; reg < 4; ++reg) {
            int row = rt * 16 + (lane >> 4) * 4 + reg;
            size_t o = (size_t)(r0 + row) * 128 + col;
            yout[o] = acc[rt][ct][reg] + wb[ct] + y1[o];
          }
        }
    }
    __syncthreads();
  }
}

// =============================== launch ===============================
extern "C" void kernel_launch(void* const* d_in, const int* in_sizes, int n_in,
                              void* d_out, int out_size, void* d_ws, size_t ws_size,
                              hipStream_t stream) {
  (void)in_sizes; (void)n_in; (void)out_size; (void)ws_size;
  const float* x = (const float*)d_in[0];
  const float* y = (const float*)d_in[1];
  const float* proj = (const float*)d_in[2];
  const float* ln1w = (const float*)d_in[3];
  const float* ln1b = (const float*)d_in[4];
  const float* ln2w = (const float*)d_in[5];
  const float* ln2b = (const float*)d_in[6];
  const float* ln4w = (const float*)d_in[7];
  const float* ln4b = (const float*)d_in[8];
  const float* fcw = (const float*)d_in[9];
  const float* fcb = (const float*)d_in[10];
  const float* prw = (const float*)d_in[11];
  const float* prb = (const float*)d_in[12];
  const float* wq = (const float*)d_in[13];
  const float* wk = (const float*)d_in[14];
  const float* wv = (const float*)d_in[15];
  const float* wo = (const float*)d_in[16];
  const float* wob = (const float*)d_in[17];

  float* out = (float*)d_out;
  float* q_un = out + 12582912;
  float* k_un = out + 62914560;

  float* ws = (float*)d_ws;
  float* y1 = ws;                          // 12,582,912
  float* kbuf = ws + 12582912;             // 6,553,600 (dead after k4)
  float* vbuf = ws + 19136512;             // 6,553,600 (dead after k5a)
  float* part_c = ws + 12582912;           // 1,572,864 (aliases kbuf; after k4)
  float* part_k = ws + 14155776;           // 98,304
  float* attn = ws + 12582912;             // 12,582,912 (aliases kbuf+vbuf; after k5a2)
  float* tmax = ws + 26476544;             // 409,600
  float* mxk = ws + 26886144;              // 256
  float* ksum = ws + 26886400;             // 16,384
  float* ctx2 = ws + 26902784;             // 262,144
  unsigned short* fcT = (unsigned short*)(ws + 27164928);   // 4 x 16384 ushorts
  unsigned short* prT = fcT + 16384;
  unsigned short* wqT = prT + 16384;
  unsigned short* woT = wqT + 16384;

  k0_prep<<<dim3(4), dim3(256), 0, stream>>>(fcw, prw, wq, wo, fcT, prT, wqT, woT);
  k1_mlp<<<dim3(512), dim3(256), 0, stream>>>(y, ln4w, ln4b, fcT, fcb, prT, prb, y1);
  k2_kv<<<dim3(400), dim3(512), 0, stream>>>(x, ln2w, ln2b, wk, wv, kbuf, vbuf);
  k4_kun<<<dim3(400), dim3(512), 0, stream>>>(kbuf, proj, k_un, tmax);
  k4b_mxk<<<dim3(128), dim3(256), 0, stream>>>(tmax, mxk);
  k5a_ctx<<<dim3(256, 6), dim3(256), 0, stream>>>(k_un, vbuf, mxk, part_c, part_k);
  k5a2_red<<<dim3(256), dim3(256), 0, stream>>>(part_c, part_k, ctx2, ksum);
  kq_fused2<<<dim3(16, 32), dim3(512), 0, stream>>>(y1, ln1w, ln1b, wqT, proj,
                                                    ctx2, ksum, q_un, attn);
  k6_wo<<<dim3(512), dim3(256), 0, stream>>>(attn, woT, wob, y1, out);
}